// Round 1
// baseline (469.460 us; speedup 1.0000x reference)
//
#include <hip/hip_runtime.h>
#include <hip/hip_bf16.h>

constexpr int LS = 1024;   // sequence length
constexpr int DM = 768;    // model dim
constexpr int NH = 12;     // heads
constexpr int HD = 64;     // head dim
constexpr float EPSF = 1e-5f;
constexpr float ALPHAF = 0.01f;

// ---------------------------------------------------------------------------
// K1: causal conv  xt[l, head*64+c] = sum_{s<=l} filters[l-s, c] * x[s, head*64+c]
// grid (LS/4, NH), block 256 = 4 l-values x 64 channels
__global__ void conv_kernel(const float* __restrict__ x, const float* __restrict__ f,
                            float* __restrict__ xt) {
  const int li = threadIdx.x >> 6;
  const int c  = threadIdx.x & 63;
  const int l  = blockIdx.x * 4 + li;
  const int head = blockIdx.y;
  const float* xp = x + head * HD + c;
  float a0 = 0.f, a1 = 0.f;
  int s = 0;
  for (; s + 1 <= l; s += 2) {
    a0 = fmaf(f[(l - s) * HD + c],     xp[s * DM],       a0);
    a1 = fmaf(f[(l - s - 1) * HD + c], xp[(s + 1) * DM], a1);
  }
  for (; s <= l; ++s) a0 = fmaf(f[(l - s) * HD + c], xp[s * DM], a0);
  xt[l * DM + head * HD + c] = a0 + a1;
}

// ---------------------------------------------------------------------------
// K2: q/k/v = xt @ W + b, written head-major [NH][LS][HD]
// grid (DM/64=12, LS/64=16, 3), block 256
__global__ void qkv_gemm(const float* __restrict__ xt,
                         const float* __restrict__ wq, const float* __restrict__ bq,
                         const float* __restrict__ wk, const float* __restrict__ bk,
                         const float* __restrict__ wv, const float* __restrict__ bv,
                         float* __restrict__ qo, float* __restrict__ ko, float* __restrict__ vo) {
  const float* w; const float* bias; float* out;
  if (blockIdx.z == 0)      { w = wq; bias = bq; out = qo; }
  else if (blockIdx.z == 1) { w = wk; bias = bk; out = ko; }
  else                      { w = wv; bias = bv; out = vo; }
  __shared__ float As[64][17];
  __shared__ float Bs[16][64];
  const int tid = threadIdx.x;
  const int tx = tid & 15, ty = tid >> 4;
  const int rowbase = blockIdx.y * 64, colbase = blockIdx.x * 64;
  const int lr = tid >> 2, lc = (tid & 3) * 4;
  const int lk = tid >> 4, lcc = (tid & 15) * 4;
  float acc[4][4] = {};
  for (int k0 = 0; k0 < DM; k0 += 16) {
    float4 av = *(const float4*)(xt + (rowbase + lr) * DM + k0 + lc);
    As[lr][lc + 0] = av.x; As[lr][lc + 1] = av.y; As[lr][lc + 2] = av.z; As[lr][lc + 3] = av.w;
    *(float4*)&Bs[lk][lcc] = *(const float4*)(w + (k0 + lk) * DM + colbase + lcc);
    __syncthreads();
#pragma unroll
    for (int kk = 0; kk < 16; ++kk) {
      float ra[4], rb[4];
#pragma unroll
      for (int i = 0; i < 4; ++i) ra[i] = As[ty * 4 + i][kk];
#pragma unroll
      for (int j = 0; j < 4; ++j) rb[j] = Bs[kk][tx * 4 + j];
#pragma unroll
      for (int i = 0; i < 4; ++i)
#pragma unroll
        for (int j = 0; j < 4; ++j)
          acc[i][j] = fmaf(ra[i], rb[j], acc[i][j]);
    }
    __syncthreads();
  }
  const int head = blockIdx.x;  // 64-wide column tiles align with heads
#pragma unroll
  for (int i = 0; i < 4; ++i) {
    const int row = rowbase + ty * 4 + i;
#pragma unroll
    for (int j = 0; j < 4; ++j) {
      const int cc = tx * 4 + j;
      out[((size_t)head * LS + row) * HD + cc] = acc[i][j] + bias[colbase + cc];
    }
  }
}

// ---------------------------------------------------------------------------
// K6: y = lerp @ wo + b, row-major output [LS][DM]
// grid (12, 16), block 256
__global__ void out_gemm(const float* __restrict__ A, const float* __restrict__ w,
                         const float* __restrict__ bias, float* __restrict__ out) {
  __shared__ float As[64][17];
  __shared__ float Bs[16][64];
  const int tid = threadIdx.x;
  const int tx = tid & 15, ty = tid >> 4;
  const int rowbase = blockIdx.y * 64, colbase = blockIdx.x * 64;
  const int lr = tid >> 2, lc = (tid & 3) * 4;
  const int lk = tid >> 4, lcc = (tid & 15) * 4;
  float acc[4][4] = {};
  for (int k0 = 0; k0 < DM; k0 += 16) {
    float4 av = *(const float4*)(A + (rowbase + lr) * DM + k0 + lc);
    As[lr][lc + 0] = av.x; As[lr][lc + 1] = av.y; As[lr][lc + 2] = av.z; As[lr][lc + 3] = av.w;
    *(float4*)&Bs[lk][lcc] = *(const float4*)(w + (k0 + lk) * DM + colbase + lcc);
    __syncthreads();
#pragma unroll
    for (int kk = 0; kk < 16; ++kk) {
      float ra[4], rb[4];
#pragma unroll
      for (int i = 0; i < 4; ++i) ra[i] = As[ty * 4 + i][kk];
#pragma unroll
      for (int j = 0; j < 4; ++j) rb[j] = Bs[kk][tx * 4 + j];
#pragma unroll
      for (int i = 0; i < 4; ++i)
#pragma unroll
        for (int j = 0; j < 4; ++j)
          acc[i][j] = fmaf(ra[i], rb[j], acc[i][j]);
    }
    __syncthreads();
  }
#pragma unroll
  for (int i = 0; i < 4; ++i) {
    const int row = rowbase + ty * 4 + i;
#pragma unroll
    for (int j = 0; j < 4; ++j) {
      const int cc = colbase + tx * 4 + j;
      out[(size_t)row * DM + cc] = acc[i][j] + bias[cc];
    }
  }
}

// ---------------------------------------------------------------------------
// K3: in-place l2norm of q,k,v + sim + gates.  One wave per (head, l).
// grid (LS/4, NH), block 256
__global__ void norm_sim_gate(float* __restrict__ q, float* __restrict__ k, float* __restrict__ v,
                              const float* __restrict__ wg, const float* __restrict__ wgb,
                              const float* __restrict__ qk_scale, const float* __restrict__ kv_scale,
                              float* __restrict__ sim, float* __restrict__ gates) {
  const int w = threadIdx.x >> 6, lane = threadIdx.x & 63;
  const int l = blockIdx.x * 4 + w;
  const int head = blockIdx.y;
  const size_t idx = ((size_t)head * LS + l) * HD + lane;
  float qv = q[idx], kv = k[idx], vv = v[idx];

  auto red = [](float x) {
#pragma unroll
    for (int o = 32; o; o >>= 1) x += __shfl_xor(x, o);
    return x;
  };
  const float qn = fmaxf(sqrtf(red(qv * qv)), 1e-12f);
  const float kn = fmaxf(sqrtf(red(kv * kv)), 1e-12f);
  const float vn = fmaxf(sqrtf(red(vv * vv)), 1e-12f);
  qv /= qn; kv /= kn; vv /= vn;
  q[idx] = qv; k[idx] = kv; v[idx] = vv;

  const float s = red(qv * kv) * qk_scale[head];

  __shared__ float vs[4][64];
  vs[w][lane] = vv;
  __syncthreads();
  float t = 0.f;
#pragma unroll 8
  for (int p = 0; p < 64; ++p) t = fmaf(vs[w][p], wg[p * 64 + lane], t);
  float gl = red(t * kv) * kv_scale[head] + wgb[0];
  gl = gl > 0.f ? gl : ALPHAF * gl;
  const float g = gl * gl + EPSF;
  if (lane == 0) {
    sim[head * LS + l] = s;
    gates[head * LS + l] = g;
  }
}

// ---------------------------------------------------------------------------
// K4: per-head scalar prefix scans: cummax(sim), cumsum(exp(sim)), cumsum(gates)
// grid (NH), block 1024 (Hillis-Steele in LDS)
__global__ void scan_kernel(const float* __restrict__ sim, const float* __restrict__ gates,
                            float* __restrict__ m_s, float* __restrict__ Sraw,
                            float* __restrict__ g_s) {
  const int head = blockIdx.x, t = threadIdx.x;
  __shared__ float bm[1024], bs[1024], bg[1024];
  const float sv = sim[head * LS + t];
  float m = sv, S = expf(sv), g = gates[head * LS + t];
  bm[t] = m; bs[t] = S; bg[t] = g;
  __syncthreads();
  for (int off = 1; off < 1024; off <<= 1) {
    float om = -1e30f, os = 0.f, og = 0.f;
    if (t >= off) { om = bm[t - off]; os = bs[t - off]; og = bg[t - off]; }
    __syncthreads();
    m = fmaxf(m, om); S += os; g += og;
    bm[t] = m; bs[t] = S; bg[t] = g;
    __syncthreads();
  }
  m_s[head * LS + t] = m;
  Sraw[head * LS + t] = S;
  g_s[head * LS + t] = g;
}

// ---------------------------------------------------------------------------
// K5: fused causal attention + linear-attn numerator + lerp.
// Per (head, t-tile of 64): O[t,n] = sum_{s<=t} gates[s]*(q[t].v[s])*k[s,n]
//                           N[t,c] = sum_{s<=t} exp(sim[s])*v[s,c]
// then combine with scan scalars into lerp[t, head*64+c].
// grid (LS/64=16, NH), block 256
__global__ void attn_kernel(const float* __restrict__ q, const float* __restrict__ k,
                            const float* __restrict__ v, const float* __restrict__ sim,
                            const float* __restrict__ gates, const float* __restrict__ m_s,
                            const float* __restrict__ Sraw, const float* __restrict__ g_s,
                            const float* __restrict__ kv_scale, float* __restrict__ lerp) {
  const int ti = blockIdx.x, head = blockIdx.y;
  const int tid = threadIdx.x, tx = tid & 15, ty = tid >> 4;
  __shared__ float Qs[64][65], Vs[64][65], Ks[64][64], Ag[64][65];
  __shared__ float Es[64], Gs[64], nv[64];
  const float* qh = q + (size_t)head * LS * HD;
  const float* kh = k + (size_t)head * LS * HD;
  const float* vh = v + (size_t)head * LS * HD;
  const int tbase = ti * 64;

#pragma unroll
  for (int rep = 0; rep < 4; ++rep) {
    const int lin = rep * 1024 + tid * 4;
    const int r = lin >> 6, c = lin & 63;
    float4 t4 = *(const float4*)(qh + (tbase + r) * HD + c);
    Qs[r][c] = t4.x; Qs[r][c + 1] = t4.y; Qs[r][c + 2] = t4.z; Qs[r][c + 3] = t4.w;
  }

  float O[4][4] = {}, N[4][4] = {};
  for (int si = 0; si <= ti; ++si) {
    const int sbase = si * 64;
#pragma unroll
    for (int rep = 0; rep < 4; ++rep) {
      const int lin = rep * 1024 + tid * 4;
      const int r = lin >> 6, c = lin & 63;
      float4 t4 = *(const float4*)(vh + (sbase + r) * HD + c);
      Vs[r][c] = t4.x; Vs[r][c + 1] = t4.y; Vs[r][c + 2] = t4.z; Vs[r][c + 3] = t4.w;
      float4 u4 = *(const float4*)(kh + (sbase + r) * HD + c);
      Ks[r][c] = u4.x; Ks[r][c + 1] = u4.y; Ks[r][c + 2] = u4.z; Ks[r][c + 3] = u4.w;
    }
    if (tid < 64) {
      Es[tid] = expf(sim[head * LS + sbase + tid]);
      Gs[tid] = gates[head * LS + sbase + tid];
    }
    __syncthreads();

    // phase A: A[t,s] = q[t].v[s]
    float a[4][4] = {};
    for (int p = 0; p < 64; ++p) {
      float ra[4], rb[4];
#pragma unroll
      for (int i = 0; i < 4; ++i) ra[i] = Qs[ty * 4 + i][p];
#pragma unroll
      for (int j = 0; j < 4; ++j) rb[j] = Vs[tx * 4 + j][p];
#pragma unroll
      for (int i = 0; i < 4; ++i)
#pragma unroll
        for (int j = 0; j < 4; ++j)
          a[i][j] = fmaf(ra[i], rb[j], a[i][j]);
    }
    const bool diag = (si == ti);
#pragma unroll
    for (int i = 0; i < 4; ++i)
#pragma unroll
      for (int j = 0; j < 4; ++j) {
        const int tl = ty * 4 + i, sl = tx * 4 + j;
        float val = a[i][j] * Gs[sl];
        if (diag && sl > tl) val = 0.f;
        Ag[tl][sl] = val;
      }
    if (!diag && tid < 64) {
      float acc = 0.f;
      for (int s = 0; s < 64; ++s) acc = fmaf(Es[s], Vs[s][tid], acc);
      nv[tid] = acc;
    }
    __syncthreads();

    // phase B: O += (A*gates) @ K ; N += masked E-weighted V
    for (int s = 0; s < 64; ++s) {
      float rb[4];
#pragma unroll
      for (int j = 0; j < 4; ++j) rb[j] = Ks[s][tx * 4 + j];
#pragma unroll
      for (int i = 0; i < 4; ++i) {
        const float av = Ag[ty * 4 + i][s];
#pragma unroll
        for (int j = 0; j < 4; ++j) O[i][j] = fmaf(av, rb[j], O[i][j]);
      }
    }
    if (diag) {
      for (int s = 0; s < 64; ++s) {
        const float e = Es[s];
        float rv[4];
#pragma unroll
        for (int j = 0; j < 4; ++j) rv[j] = Vs[s][tx * 4 + j];
#pragma unroll
        for (int i = 0; i < 4; ++i)
          if (ty * 4 + i >= s)
#pragma unroll
            for (int j = 0; j < 4; ++j) N[i][j] = fmaf(e, rv[j], N[i][j]);
      }
    } else {
#pragma unroll
      for (int i = 0; i < 4; ++i)
#pragma unroll
        for (int j = 0; j < 4; ++j) N[i][j] += nv[tx * 4 + j];
    }
    __syncthreads();
  }

  const float kvs = kv_scale[head];
#pragma unroll
  for (int i = 0; i < 4; ++i) {
    const int t = tbase + ty * 4 + i;
    const float m  = m_s[head * LS + t];
    const float em = expf(-m);
    const float ss = Sraw[head * LS + t] * em;
    const float inv = 1.f / (ss + EPSF);
    const float sw  = expf(sim[head * LS + t] - m) * inv;
    const float gi  = kvs / (g_s[head * LS + t] + EPSF);
#pragma unroll
    for (int j = 0; j < 4; ++j) {
      const float la = N[i][j] * em * inv;
      const float cx = O[i][j] * gi;
      lerp[(size_t)t * DM + head * HD + tx * 4 + j] = cx + (la - cx) * sw;
    }
  }
}

// ---------------------------------------------------------------------------
extern "C" void kernel_launch(void* const* d_in, const int* in_sizes, int n_in,
                              void* d_out, int out_size, void* d_ws, size_t ws_size,
                              hipStream_t stream) {
  (void)in_sizes; (void)n_in; (void)out_size; (void)ws_size;
  const float* x        = (const float*)d_in[0];
  const float* filters  = (const float*)d_in[1];
  const float* wq_w     = (const float*)d_in[2];
  const float* wq_b     = (const float*)d_in[3];
  const float* wk_w     = (const float*)d_in[4];
  const float* wk_b     = (const float*)d_in[5];
  const float* wv_w     = (const float*)d_in[6];
  const float* wv_b     = (const float*)d_in[7];
  const float* wo_w     = (const float*)d_in[8];
  const float* wo_b     = (const float*)d_in[9];
  const float* wg_w     = (const float*)d_in[10];
  const float* wg_b     = (const float*)d_in[11];
  const float* qk_scale = (const float*)d_in[12];
  const float* kv_scale = (const float*)d_in[13];

  float* ws = (float*)d_ws;
  const size_t NT = (size_t)LS * DM;  // 786432
  float* xt    = ws;
  float* q     = ws + NT;
  float* k     = ws + 2 * NT;
  float* v     = ws + 3 * NT;
  float* lerp  = ws + 4 * NT;
  float* sim   = ws + 5 * NT;
  float* gates = sim + NH * LS;
  float* m_s   = gates + NH * LS;
  float* Sraw  = m_s + NH * LS;
  float* g_s   = Sraw + NH * LS;

  conv_kernel<<<dim3(LS / 4, NH), 256, 0, stream>>>(x, filters, xt);
  qkv_gemm<<<dim3(DM / 64, LS / 64, 3), 256, 0, stream>>>(
      xt, wq_w, wq_b, wk_w, wk_b, wv_w, wv_b, q, k, v);
  norm_sim_gate<<<dim3(LS / 4, NH), 256, 0, stream>>>(
      q, k, v, wg_w, wg_b, qk_scale, kv_scale, sim, gates);
  scan_kernel<<<dim3(NH), 1024, 0, stream>>>(sim, gates, m_s, Sraw, g_s);
  attn_kernel<<<dim3(LS / 64, NH), 256, 0, stream>>>(
      q, k, v, sim, gates, m_s, Sraw, g_s, kv_scale, lerp);
  out_gemm<<<dim3(DM / 64, LS / 64), 256, 0, stream>>>(lerp, wo_w, wo_b, (float*)d_out);
}

// Round 3
// 316.546 us; speedup vs baseline: 1.4831x; 1.4831x over previous
//
#include <hip/hip_runtime.h>
#include <hip/hip_bf16.h>

constexpr int LS = 1024;   // sequence length
constexpr int DM = 768;    // model dim
constexpr int NH = 12;     // heads
constexpr int HD = 64;     // head dim
constexpr float EPSF = 1e-5f;
constexpr float ALPHAF = 0.01f;

// ---------------------------------------------------------------------------
// K1: causal conv  xt[l, head*64+c] = sum_{s<=l} filters[l-s, c] * x[s, head*64+c]
// Tiled banded-stencil form. grid (16 l-tiles, 12 heads, 2 j-parities), block 256.
// Output is split into two partial buffers (parity of the s-tile index j);
// qkv_gemm sums them while staging A. This halves the triangular critical path.
__global__ __launch_bounds__(256) void conv_kernel(const float* __restrict__ x,
                                                   const float* __restrict__ f,
                                                   float* __restrict__ xt_base) {
  const int i    = blockIdx.x;     // l-tile
  const int head = blockIdx.y;
  const int par  = blockIdx.z;     // j parity
  const int tid  = threadIdx.x;
  const int c    = tid & 63;
  const int sg   = tid >> 6;       // wave id 0..3
  const int tbase = i * 64;
  const int l0w   = tbase + sg * 16;
  float* __restrict__ xt_p = xt_base + (size_t)par * LS * DM;

  // r_pad = (l - d - sbase) + 16 in [0,111] -> groups 0..27 (data groups 4..19)
  __shared__ float4 Xs2[28][64];
  // filter band rows dd = d - b0 in [0,127] -> groups 0..31
  __shared__ float4 Fg[32][64];

  // zero the pad groups (0..3 and 20..27) once
  {
    const float4 z4 = make_float4(0.f, 0.f, 0.f, 0.f);
#pragma unroll
    for (int k = 0; k < 3; ++k) {
      const int lin = k * 256 + tid;           // 0..767
      const int g   = lin >> 6;                // 0..11
      const int cc  = lin & 63;
      const int grp = (g < 4) ? g : (16 + g);  // 0..3, 20..27
      Xs2[grp][cc] = z4;
    }
  }

  float acc[16];
#pragma unroll
  for (int t = 0; t < 16; ++t) acc[t] = 0.f;

  const float* xg = x + head * HD + c;
  const float* fg = f + c;

  for (int j = par; j <= i; j += 2) {
    const int sbase = j * 64;
    const int b0 = (j < i) ? (tbase - sbase - 64) : 0;  // band base, mult of 16, >= 0
    // stage X tile: rows r = 0..63 -> groups 4..19
#pragma unroll
    for (int k = 0; k < 4; ++k) {
      const int m  = sg + 4 * k;   // 0..15
      const int ss = 4 * m;
      float4 v4;
      v4.x = xg[(sbase + ss + 0) * DM];
      v4.y = xg[(sbase + ss + 1) * DM];
      v4.z = xg[(sbase + ss + 2) * DM];
      v4.w = xg[(sbase + ss + 3) * DM];
      Xs2[4 + m][c] = v4;
    }
    // stage F band: groups 0..31, f rows b0 + 4m + e (always within [0,1023])
#pragma unroll
    for (int k = 0; k < 8; ++k) {
      const int m  = sg + 4 * k;   // 0..31
      const int d4 = b0 + 4 * m;
      float4 v4;
      v4.x = fg[(d4 + 0) * HD];
      v4.y = fg[(d4 + 1) * HD];
      v4.z = fg[(d4 + 2) * HD];
      v4.w = fg[(d4 + 3) * HD];
      Fg[m][c] = v4;
    }
    __syncthreads();

    // per-wave d-range, 16-aligned start; exact 80-cover for j<i, (sg+1)*16 for j==i
    const int dstart = (j < i) ? (b0 + sg * 16) : 0;
    const int nsteps = (j < i) ? 5 : (sg + 1);
    for (int k = 0; k < nsteps; ++k) {
      const int d0    = dstart + 16 * k;
      const int rbase = l0w - d0 - sbase;      // multiple of 16, in [0,64]
      float fr[16];
      const int fgb = (d0 - b0) >> 2;
#pragma unroll
      for (int m = 0; m < 4; ++m) {
        const float4 v4 = Fg[fgb + m][c];
        fr[4 * m + 0] = v4.x; fr[4 * m + 1] = v4.y;
        fr[4 * m + 2] = v4.z; fr[4 * m + 3] = v4.w;
      }
      float xw[32];                            // r_pad window [rbase, rbase+31]
      const int xgb = rbase >> 2;
#pragma unroll
      for (int m = 0; m < 8; ++m) {
        const float4 v4 = Xs2[xgb + m][c];
        xw[4 * m + 0] = v4.x; xw[4 * m + 1] = v4.y;
        xw[4 * m + 2] = v4.z; xw[4 * m + 3] = v4.w;
      }
#pragma unroll
      for (int li = 0; li < 16; ++li)
#pragma unroll
        for (int dd = 0; dd < 16; ++dd)
          acc[li] = fmaf(fr[dd], xw[li - dd + 16], acc[li]);
    }
    __syncthreads();  // before next j's staging (uniform across waves)
  }

#pragma unroll
  for (int li = 0; li < 16; ++li)
    xt_p[(size_t)(l0w + li) * DM + head * HD + c] = acc[li];
}

// ---------------------------------------------------------------------------
// K2: q/k/v = (xt_a + xt_b) @ W + b, written head-major [NH][LS][HD]
// grid (DM/64=12, LS/64=16, 3), block 256
__global__ void qkv_gemm(const float* __restrict__ xa, const float* __restrict__ xb,
                         const float* __restrict__ wq, const float* __restrict__ bq,
                         const float* __restrict__ wk, const float* __restrict__ bk,
                         const float* __restrict__ wv, const float* __restrict__ bv,
                         float* __restrict__ qo, float* __restrict__ ko, float* __restrict__ vo) {
  const float* w; const float* bias; float* out;
  if (blockIdx.z == 0)      { w = wq; bias = bq; out = qo; }
  else if (blockIdx.z == 1) { w = wk; bias = bk; out = ko; }
  else                      { w = wv; bias = bv; out = vo; }
  __shared__ float As[64][17];
  __shared__ float Bs[16][64];
  const int tid = threadIdx.x;
  const int tx = tid & 15, ty = tid >> 4;
  const int rowbase = blockIdx.y * 64, colbase = blockIdx.x * 64;
  const int lr = tid >> 2, lc = (tid & 3) * 4;
  const int lk = tid >> 4, lcc = (tid & 15) * 4;
  float acc[4][4] = {};
  for (int k0 = 0; k0 < DM; k0 += 16) {
    float4 av = *(const float4*)(xa + (rowbase + lr) * DM + k0 + lc);
    float4 bv2 = *(const float4*)(xb + (rowbase + lr) * DM + k0 + lc);
    As[lr][lc + 0] = av.x + bv2.x; As[lr][lc + 1] = av.y + bv2.y;
    As[lr][lc + 2] = av.z + bv2.z; As[lr][lc + 3] = av.w + bv2.w;
    *(float4*)&Bs[lk][lcc] = *(const float4*)(w + (k0 + lk) * DM + colbase + lcc);
    __syncthreads();
#pragma unroll
    for (int kk = 0; kk < 16; ++kk) {
      float ra[4], rb[4];
#pragma unroll
      for (int i = 0; i < 4; ++i) ra[i] = As[ty * 4 + i][kk];
#pragma unroll
      for (int j = 0; j < 4; ++j) rb[j] = Bs[kk][tx * 4 + j];
#pragma unroll
      for (int i = 0; i < 4; ++i)
#pragma unroll
        for (int j = 0; j < 4; ++j)
          acc[i][j] = fmaf(ra[i], rb[j], acc[i][j]);
    }
    __syncthreads();
  }
  const int head = blockIdx.x;  // 64-wide column tiles align with heads
#pragma unroll
  for (int i = 0; i < 4; ++i) {
    const int row = rowbase + ty * 4 + i;
#pragma unroll
    for (int j = 0; j < 4; ++j) {
      const int cc = tx * 4 + j;
      out[((size_t)head * LS + row) * HD + cc] = acc[i][j] + bias[colbase + cc];
    }
  }
}

// ---------------------------------------------------------------------------
// K6: y = lerp @ wo + b, row-major output [LS][DM]
// grid (12, 16), block 256
__global__ void out_gemm(const float* __restrict__ A, const float* __restrict__ w,
                         const float* __restrict__ bias, float* __restrict__ out) {
  __shared__ float As[64][17];
  __shared__ float Bs[16][64];
  const int tid = threadIdx.x;
  const int tx = tid & 15, ty = tid >> 4;
  const int rowbase = blockIdx.y * 64, colbase = blockIdx.x * 64;
  const int lr = tid >> 2, lc = (tid & 3) * 4;
  const int lk = tid >> 4, lcc = (tid & 15) * 4;
  float acc[4][4] = {};
  for (int k0 = 0; k0 < DM; k0 += 16) {
    float4 av = *(const float4*)(A + (rowbase + lr) * DM + k0 + lc);
    As[lr][lc + 0] = av.x; As[lr][lc + 1] = av.y; As[lr][lc + 2] = av.z; As[lr][lc + 3] = av.w;
    *(float4*)&Bs[lk][lcc] = *(const float4*)(w + (k0 + lk) * DM + colbase + lcc);
    __syncthreads();
#pragma unroll
    for (int kk = 0; kk < 16; ++kk) {
      float ra[4], rb[4];
#pragma unroll
      for (int i = 0; i < 4; ++i) ra[i] = As[ty * 4 + i][kk];
#pragma unroll
      for (int j = 0; j < 4; ++j) rb[j] = Bs[kk][tx * 4 + j];
#pragma unroll
      for (int i = 0; i < 4; ++i)
#pragma unroll
        for (int j = 0; j < 4; ++j)
          acc[i][j] = fmaf(ra[i], rb[j], acc[i][j]);
    }
    __syncthreads();
  }
#pragma unroll
  for (int i = 0; i < 4; ++i) {
    const int row = rowbase + ty * 4 + i;
#pragma unroll
    for (int j = 0; j < 4; ++j) {
      const int cc = colbase + tx * 4 + j;
      out[(size_t)row * DM + cc] = acc[i][j] + bias[cc];
    }
  }
}

// ---------------------------------------------------------------------------
// K3: in-place l2norm of q,k,v + sim + gates.  One wave per (head, l).
// grid (LS/4, NH), block 256
__global__ void norm_sim_gate(float* __restrict__ q, float* __restrict__ k, float* __restrict__ v,
                              const float* __restrict__ wg, const float* __restrict__ wgb,
                              const float* __restrict__ qk_scale, const float* __restrict__ kv_scale,
                              float* __restrict__ sim, float* __restrict__ gates) {
  const int w = threadIdx.x >> 6, lane = threadIdx.x & 63;
  const int l = blockIdx.x * 4 + w;
  const int head = blockIdx.y;
  const size_t idx = ((size_t)head * LS + l) * HD + lane;
  float qv = q[idx], kv = k[idx], vv = v[idx];

  auto red = [](float x) {
#pragma unroll
    for (int o = 32; o; o >>= 1) x += __shfl_xor(x, o);
    return x;
  };
  const float qn = fmaxf(sqrtf(red(qv * qv)), 1e-12f);
  const float kn = fmaxf(sqrtf(red(kv * kv)), 1e-12f);
  const float vn = fmaxf(sqrtf(red(vv * vv)), 1e-12f);
  qv /= qn; kv /= kn; vv /= vn;
  q[idx] = qv; k[idx] = kv; v[idx] = vv;

  const float s = red(qv * kv) * qk_scale[head];

  __shared__ float vs[4][64];
  vs[w][lane] = vv;
  __syncthreads();
  float t = 0.f;
#pragma unroll 8
  for (int p = 0; p < 64; ++p) t = fmaf(vs[w][p], wg[p * 64 + lane], t);
  float gl = red(t * kv) * kv_scale[head] + wgb[0];
  gl = gl > 0.f ? gl : ALPHAF * gl;
  const float g = gl * gl + EPSF;
  if (lane == 0) {
    sim[head * LS + l] = s;
    gates[head * LS + l] = g;
  }
}

// ---------------------------------------------------------------------------
// K4: per-head scalar prefix scans: cummax(sim), cumsum(exp(sim)), cumsum(gates)
// grid (NH), block 1024 (Hillis-Steele in LDS)
__global__ void scan_kernel(const float* __restrict__ sim, const float* __restrict__ gates,
                            float* __restrict__ m_s, float* __restrict__ Sraw,
                            float* __restrict__ g_s) {
  const int head = blockIdx.x, t = threadIdx.x;
  __shared__ float bm[1024], bs[1024], bg[1024];
  const float sv = sim[head * LS + t];
  float m = sv, S = expf(sv), g = gates[head * LS + t];
  bm[t] = m; bs[t] = S; bg[t] = g;
  __syncthreads();
  for (int off = 1; off < 1024; off <<= 1) {
    float om = -1e30f, os = 0.f, og = 0.f;
    if (t >= off) { om = bm[t - off]; os = bs[t - off]; og = bg[t - off]; }
    __syncthreads();
    m = fmaxf(m, om); S += os; g += og;
    bm[t] = m; bs[t] = S; bg[t] = g;
    __syncthreads();
  }
  m_s[head * LS + t] = m;
  Sraw[head * LS + t] = S;
  g_s[head * LS + t] = g;
}

// ---------------------------------------------------------------------------
// K5: fused causal attention + linear-attn numerator + lerp.
// grid (LS/64=16, NH), block 256
__global__ void attn_kernel(const float* __restrict__ q, const float* __restrict__ k,
                            const float* __restrict__ v, const float* __restrict__ sim,
                            const float* __restrict__ gates, const float* __restrict__ m_s,
                            const float* __restrict__ Sraw, const float* __restrict__ g_s,
                            const float* __restrict__ kv_scale, float* __restrict__ lerp) {
  const int ti = blockIdx.x, head = blockIdx.y;
  const int tid = threadIdx.x, tx = tid & 15, ty = tid >> 4;
  __shared__ float Qs[64][65], Vs[64][65], Ks[64][64], Ag[64][65];
  __shared__ float Es[64], Gs[64], nv[64];
  const float* qh = q + (size_t)head * LS * HD;
  const float* kh = k + (size_t)head * LS * HD;
  const float* vh = v + (size_t)head * LS * HD;
  const int tbase = ti * 64;

#pragma unroll
  for (int rep = 0; rep < 4; ++rep) {
    const int lin = rep * 1024 + tid * 4;
    const int r = lin >> 6, c = lin & 63;
    float4 t4 = *(const float4*)(qh + (tbase + r) * HD + c);
    Qs[r][c] = t4.x; Qs[r][c + 1] = t4.y; Qs[r][c + 2] = t4.z; Qs[r][c + 3] = t4.w;
  }

  float O[4][4] = {}, N[4][4] = {};
  for (int si = 0; si <= ti; ++si) {
    const int sbase = si * 64;
#pragma unroll
    for (int rep = 0; rep < 4; ++rep) {
      const int lin = rep * 1024 + tid * 4;
      const int r = lin >> 6, c = lin & 63;
      float4 t4 = *(const float4*)(vh + (sbase + r) * HD + c);
      Vs[r][c] = t4.x; Vs[r][c + 1] = t4.y; Vs[r][c + 2] = t4.z; Vs[r][c + 3] = t4.w;
      float4 u4 = *(const float4*)(kh + (sbase + r) * HD + c);
      Ks[r][c] = u4.x; Ks[r][c + 1] = u4.y; Ks[r][c + 2] = u4.z; Ks[r][c + 3] = u4.w;
    }
    if (tid < 64) {
      Es[tid] = expf(sim[head * LS + sbase + tid]);
      Gs[tid] = gates[head * LS + sbase + tid];
    }
    __syncthreads();

    float a[4][4] = {};
    for (int p = 0; p < 64; ++p) {
      float ra[4], rb[4];
#pragma unroll
      for (int i = 0; i < 4; ++i) ra[i] = Qs[ty * 4 + i][p];
#pragma unroll
      for (int j = 0; j < 4; ++j) rb[j] = Vs[tx * 4 + j][p];
#pragma unroll
      for (int i = 0; i < 4; ++i)
#pragma unroll
        for (int j = 0; j < 4; ++j)
          a[i][j] = fmaf(ra[i], rb[j], a[i][j]);
    }
    const bool diag = (si == ti);
#pragma unroll
    for (int i = 0; i < 4; ++i)
#pragma unroll
      for (int j = 0; j < 4; ++j) {
        const int tl = ty * 4 + i, sl = tx * 4 + j;
        float val = a[i][j] * Gs[sl];
        if (diag && sl > tl) val = 0.f;
        Ag[tl][sl] = val;
      }
    if (!diag && tid < 64) {
      float acc = 0.f;
      for (int s = 0; s < 64; ++s) acc = fmaf(Es[s], Vs[s][tid], acc);
      nv[tid] = acc;
    }
    __syncthreads();

    for (int s = 0; s < 64; ++s) {
      float rb[4];
#pragma unroll
      for (int j = 0; j < 4; ++j) rb[j] = Ks[s][tx * 4 + j];
#pragma unroll
      for (int i = 0; i < 4; ++i) {
        const float av = Ag[ty * 4 + i][s];
#pragma unroll
        for (int j = 0; j < 4; ++j) O[i][j] = fmaf(av, rb[j], O[i][j]);
      }
    }
    if (diag) {
      for (int s = 0; s < 64; ++s) {
        const float e = Es[s];
        float rv[4];
#pragma unroll
        for (int j = 0; j < 4; ++j) rv[j] = Vs[s][tx * 4 + j];
#pragma unroll
        for (int i = 0; i < 4; ++i)
          if (ty * 4 + i >= s)
#pragma unroll
            for (int j = 0; j < 4; ++j) N[i][j] = fmaf(e, rv[j], N[i][j]);
      }
    } else {
#pragma unroll
      for (int i = 0; i < 4; ++i)
#pragma unroll
        for (int j = 0; j < 4; ++j) N[i][j] += nv[tx * 4 + j];
    }
    __syncthreads();
  }

  const float kvs = kv_scale[head];
#pragma unroll
  for (int i = 0; i < 4; ++i) {
    const int t = tbase + ty * 4 + i;
    const float m  = m_s[head * LS + t];
    const float em = expf(-m);
    const float ss = Sraw[head * LS + t] * em;
    const float inv = 1.f / (ss + EPSF);
    const float sw  = expf(sim[head * LS + t] - m) * inv;
    const float gi  = kvs / (g_s[head * LS + t] + EPSF);
#pragma unroll
    for (int j = 0; j < 4; ++j) {
      const float la = N[i][j] * em * inv;
      const float cx = O[i][j] * gi;
      lerp[(size_t)t * DM + head * HD + tx * 4 + j] = cx + (la - cx) * sw;
    }
  }
}

// ---------------------------------------------------------------------------
extern "C" void kernel_launch(void* const* d_in, const int* in_sizes, int n_in,
                              void* d_out, int out_size, void* d_ws, size_t ws_size,
                              hipStream_t stream) {
  (void)in_sizes; (void)n_in; (void)out_size; (void)ws_size;
  const float* x        = (const float*)d_in[0];
  const float* filters  = (const float*)d_in[1];
  const float* wq_w     = (const float*)d_in[2];
  const float* wq_b     = (const float*)d_in[3];
  const float* wk_w     = (const float*)d_in[4];
  const float* wk_b     = (const float*)d_in[5];
  const float* wv_w     = (const float*)d_in[6];
  const float* wv_b     = (const float*)d_in[7];
  const float* wo_w     = (const float*)d_in[8];
  const float* wo_b     = (const float*)d_in[9];
  const float* wg_w     = (const float*)d_in[10];
  const float* wg_b     = (const float*)d_in[11];
  const float* qk_scale = (const float*)d_in[12];
  const float* kv_scale = (const float*)d_in[13];

  float* ws = (float*)d_ws;
  const size_t NT = (size_t)LS * DM;  // 786432
  float* xt_a  = ws;                  // conv partial parity 0; later reused as lerp
  float* xt_b  = ws + NT;             // conv partial parity 1 (= xt_a + NT)
  float* q     = ws + 2 * NT;
  float* k     = ws + 3 * NT;
  float* v     = ws + 4 * NT;
  float* lerp  = xt_a;                // alias: xt consumed before attn writes
  float* sim   = ws + 5 * NT;
  float* gates = sim + NH * LS;
  float* m_s   = gates + NH * LS;
  float* Sraw  = m_s + NH * LS;
  float* g_s   = Sraw + NH * LS;

  conv_kernel<<<dim3(LS / 64, NH, 2), 256, 0, stream>>>(x, filters, xt_a);
  qkv_gemm<<<dim3(DM / 64, LS / 64, 3), 256, 0, stream>>>(
      xt_a, xt_b, wq_w, wq_b, wk_w, wk_b, wv_w, wv_b, q, k, v);
  norm_sim_gate<<<dim3(LS / 4, NH), 256, 0, stream>>>(
      q, k, v, wg_w, wg_b, qk_scale, kv_scale, sim, gates);
  scan_kernel<<<dim3(NH), 1024, 0, stream>>>(sim, gates, m_s, Sraw, g_s);
  attn_kernel<<<dim3(LS / 64, NH), 256, 0, stream>>>(
      q, k, v, sim, gates, m_s, Sraw, g_s, kv_scale, lerp);
  out_gemm<<<dim3(DM / 64, LS / 64), 256, 0, stream>>>(lerp, wo_w, wo_b, (float*)d_out);
}

// Round 4
// 207.638 us; speedup vs baseline: 2.2610x; 1.5245x over previous
//
#include <hip/hip_runtime.h>
#include <hip/hip_bf16.h>

constexpr int LS = 1024;   // sequence length
constexpr int DM = 768;    // model dim
constexpr int NH = 12;     // heads
constexpr int HD = 64;     // head dim
constexpr float EPSF = 1e-5f;
constexpr float ALPHAF = 0.01f;

constexpr int SG = 16;             // state granularity (rows per tile)
constexpr int NTL = LS / SG;       // 64 tiles per head

// ---------------------------------------------------------------------------
// K1: causal conv (banded stencil, parity-split partials). Unchanged (passing).
__global__ __launch_bounds__(256) void conv_kernel(const float* __restrict__ x,
                                                   const float* __restrict__ f,
                                                   float* __restrict__ xt_base) {
  const int i    = blockIdx.x;
  const int head = blockIdx.y;
  const int par  = blockIdx.z;
  const int tid  = threadIdx.x;
  const int c    = tid & 63;
  const int sg   = tid >> 6;
  const int tbase = i * 64;
  const int l0w   = tbase + sg * 16;
  float* __restrict__ xt_p = xt_base + (size_t)par * LS * DM;

  __shared__ float4 Xs2[28][64];
  __shared__ float4 Fg[32][64];

  {
    const float4 z4 = make_float4(0.f, 0.f, 0.f, 0.f);
#pragma unroll
    for (int k = 0; k < 3; ++k) {
      const int lin = k * 256 + tid;
      const int g   = lin >> 6;
      const int cc  = lin & 63;
      const int grp = (g < 4) ? g : (16 + g);
      Xs2[grp][cc] = z4;
    }
  }

  float acc[16];
#pragma unroll
  for (int t = 0; t < 16; ++t) acc[t] = 0.f;

  const float* xg = x + head * HD + c;
  const float* fg = f + c;

  for (int j = par; j <= i; j += 2) {
    const int sbase = j * 64;
    const int b0 = (j < i) ? (tbase - sbase - 64) : 0;
#pragma unroll
    for (int k = 0; k < 4; ++k) {
      const int m  = sg + 4 * k;
      const int ss = 4 * m;
      float4 v4;
      v4.x = xg[(sbase + ss + 0) * DM];
      v4.y = xg[(sbase + ss + 1) * DM];
      v4.z = xg[(sbase + ss + 2) * DM];
      v4.w = xg[(sbase + ss + 3) * DM];
      Xs2[4 + m][c] = v4;
    }
#pragma unroll
    for (int k = 0; k < 8; ++k) {
      const int m  = sg + 4 * k;
      const int d4 = b0 + 4 * m;
      float4 v4;
      v4.x = fg[(d4 + 0) * HD];
      v4.y = fg[(d4 + 1) * HD];
      v4.z = fg[(d4 + 2) * HD];
      v4.w = fg[(d4 + 3) * HD];
      Fg[m][c] = v4;
    }
    __syncthreads();

    const int dstart = (j < i) ? (b0 + sg * 16) : 0;
    const int nsteps = (j < i) ? 5 : (sg + 1);
    for (int k = 0; k < nsteps; ++k) {
      const int d0    = dstart + 16 * k;
      const int rbase = l0w - d0 - sbase;
      float fr[16];
      const int fgb = (d0 - b0) >> 2;
#pragma unroll
      for (int m = 0; m < 4; ++m) {
        const float4 v4 = Fg[fgb + m][c];
        fr[4 * m + 0] = v4.x; fr[4 * m + 1] = v4.y;
        fr[4 * m + 2] = v4.z; fr[4 * m + 3] = v4.w;
      }
      float xw[32];
      const int xgb = rbase >> 2;
#pragma unroll
      for (int m = 0; m < 8; ++m) {
        const float4 v4 = Xs2[xgb + m][c];
        xw[4 * m + 0] = v4.x; xw[4 * m + 1] = v4.y;
        xw[4 * m + 2] = v4.z; xw[4 * m + 3] = v4.w;
      }
#pragma unroll
      for (int li = 0; li < 16; ++li)
#pragma unroll
        for (int dd = 0; dd < 16; ++dd)
          acc[li] = fmaf(fr[dd], xw[li - dd + 16], acc[li]);
    }
    __syncthreads();
  }

#pragma unroll
  for (int li = 0; li < 16; ++li)
    xt_p[(size_t)(l0w + li) * DM + head * HD + c] = acc[li];
}

// ---------------------------------------------------------------------------
// K2: q/k/v = (xt_a + xt_b) @ W + b, head-major outputs. Unchanged (passing).
__global__ void qkv_gemm(const float* __restrict__ xa, const float* __restrict__ xb,
                         const float* __restrict__ wq, const float* __restrict__ bq,
                         const float* __restrict__ wk, const float* __restrict__ bk,
                         const float* __restrict__ wv, const float* __restrict__ bv,
                         float* __restrict__ qo, float* __restrict__ ko, float* __restrict__ vo) {
  const float* w; const float* bias; float* out;
  if (blockIdx.z == 0)      { w = wq; bias = bq; out = qo; }
  else if (blockIdx.z == 1) { w = wk; bias = bk; out = ko; }
  else                      { w = wv; bias = bv; out = vo; }
  __shared__ float As[64][17];
  __shared__ float Bs[16][64];
  const int tid = threadIdx.x;
  const int tx = tid & 15, ty = tid >> 4;
  const int rowbase = blockIdx.y * 64, colbase = blockIdx.x * 64;
  const int lr = tid >> 2, lc = (tid & 3) * 4;
  const int lk = tid >> 4, lcc = (tid & 15) * 4;
  float acc[4][4] = {};
  for (int k0 = 0; k0 < DM; k0 += 16) {
    float4 av = *(const float4*)(xa + (rowbase + lr) * DM + k0 + lc);
    float4 bv2 = *(const float4*)(xb + (rowbase + lr) * DM + k0 + lc);
    As[lr][lc + 0] = av.x + bv2.x; As[lr][lc + 1] = av.y + bv2.y;
    As[lr][lc + 2] = av.z + bv2.z; As[lr][lc + 3] = av.w + bv2.w;
    *(float4*)&Bs[lk][lcc] = *(const float4*)(w + (k0 + lk) * DM + colbase + lcc);
    __syncthreads();
#pragma unroll
    for (int kk = 0; kk < 16; ++kk) {
      float ra[4], rb[4];
#pragma unroll
      for (int i = 0; i < 4; ++i) ra[i] = As[ty * 4 + i][kk];
#pragma unroll
      for (int j = 0; j < 4; ++j) rb[j] = Bs[kk][tx * 4 + j];
#pragma unroll
      for (int i = 0; i < 4; ++i)
#pragma unroll
        for (int j = 0; j < 4; ++j)
          acc[i][j] = fmaf(ra[i], rb[j], acc[i][j]);
    }
    __syncthreads();
  }
  const int head = blockIdx.x;
#pragma unroll
  for (int i = 0; i < 4; ++i) {
    const int row = rowbase + ty * 4 + i;
#pragma unroll
    for (int j = 0; j < 4; ++j) {
      const int cc = tx * 4 + j;
      out[((size_t)head * LS + row) * HD + cc] = acc[i][j] + bias[colbase + cc];
    }
  }
}

// ---------------------------------------------------------------------------
// K6: y = lerp @ wo + b. Unchanged (passing).
__global__ void out_gemm(const float* __restrict__ A, const float* __restrict__ w,
                         const float* __restrict__ bias, float* __restrict__ out) {
  __shared__ float As[64][17];
  __shared__ float Bs[16][64];
  const int tid = threadIdx.x;
  const int tx = tid & 15, ty = tid >> 4;
  const int rowbase = blockIdx.y * 64, colbase = blockIdx.x * 64;
  const int lr = tid >> 2, lc = (tid & 3) * 4;
  const int lk = tid >> 4, lcc = (tid & 15) * 4;
  float acc[4][4] = {};
  for (int k0 = 0; k0 < DM; k0 += 16) {
    float4 av = *(const float4*)(A + (rowbase + lr) * DM + k0 + lc);
    As[lr][lc + 0] = av.x; As[lr][lc + 1] = av.y; As[lr][lc + 2] = av.z; As[lr][lc + 3] = av.w;
    *(float4*)&Bs[lk][lcc] = *(const float4*)(w + (k0 + lk) * DM + colbase + lcc);
    __syncthreads();
#pragma unroll
    for (int kk = 0; kk < 16; ++kk) {
      float ra[4], rb[4];
#pragma unroll
      for (int i = 0; i < 4; ++i) ra[i] = As[ty * 4 + i][kk];
#pragma unroll
      for (int j = 0; j < 4; ++j) rb[j] = Bs[kk][tx * 4 + j];
#pragma unroll
      for (int i = 0; i < 4; ++i)
#pragma unroll
        for (int j = 0; j < 4; ++j)
          acc[i][j] = fmaf(ra[i], rb[j], acc[i][j]);
    }
    __syncthreads();
  }
#pragma unroll
  for (int i = 0; i < 4; ++i) {
    const int row = rowbase + ty * 4 + i;
#pragma unroll
    for (int j = 0; j < 4; ++j) {
      const int cc = colbase + tx * 4 + j;
      out[(size_t)row * DM + cc] = acc[i][j] + bias[cc];
    }
  }
}

// ---------------------------------------------------------------------------
// K3: l2norm + sim + gates. Unchanged (passing).
__global__ void norm_sim_gate(float* __restrict__ q, float* __restrict__ k, float* __restrict__ v,
                              const float* __restrict__ wg, const float* __restrict__ wgb,
                              const float* __restrict__ qk_scale, const float* __restrict__ kv_scale,
                              float* __restrict__ sim, float* __restrict__ gates) {
  const int w = threadIdx.x >> 6, lane = threadIdx.x & 63;
  const int l = blockIdx.x * 4 + w;
  const int head = blockIdx.y;
  const size_t idx = ((size_t)head * LS + l) * HD + lane;
  float qv = q[idx], kv = k[idx], vv = v[idx];

  auto red = [](float x) {
#pragma unroll
    for (int o = 32; o; o >>= 1) x += __shfl_xor(x, o);
    return x;
  };
  const float qn = fmaxf(sqrtf(red(qv * qv)), 1e-12f);
  const float kn = fmaxf(sqrtf(red(kv * kv)), 1e-12f);
  const float vn = fmaxf(sqrtf(red(vv * vv)), 1e-12f);
  qv /= qn; kv /= kn; vv /= vn;
  q[idx] = qv; k[idx] = kv; v[idx] = vv;

  const float s = red(qv * kv) * qk_scale[head];

  __shared__ float vs[4][64];
  vs[w][lane] = vv;
  __syncthreads();
  float t = 0.f;
#pragma unroll 8
  for (int p = 0; p < 64; ++p) t = fmaf(vs[w][p], wg[p * 64 + lane], t);
  float gl = red(t * kv) * kv_scale[head] + wgb[0];
  gl = gl > 0.f ? gl : ALPHAF * gl;
  const float g = gl * gl + EPSF;
  if (lane == 0) {
    sim[head * LS + l] = s;
    gates[head * LS + l] = g;
  }
}

// ---------------------------------------------------------------------------
// K4: per-head scalar prefix scans. Unchanged (passing).
__global__ void scan_kernel(const float* __restrict__ sim, const float* __restrict__ gates,
                            float* __restrict__ m_s, float* __restrict__ Sraw,
                            float* __restrict__ g_s) {
  const int head = blockIdx.x, t = threadIdx.x;
  __shared__ float bm[1024], bs[1024], bg[1024];
  const float sv = sim[head * LS + t];
  float m = sv, S = expf(sv), g = gates[head * LS + t];
  bm[t] = m; bs[t] = S; bg[t] = g;
  __syncthreads();
  for (int off = 1; off < 1024; off <<= 1) {
    float om = -1e30f, os = 0.f, og = 0.f;
    if (t >= off) { om = bm[t - off]; os = bs[t - off]; og = bg[t - off]; }
    __syncthreads();
    m = fmaxf(m, om); S += os; g += og;
    bm[t] = m; bs[t] = S; bg[t] = g;
    __syncthreads();
  }
  m_s[head * LS + t] = m;
  Sraw[head * LS + t] = S;
  g_s[head * LS + t] = g;
}

// ---------------------------------------------------------------------------
// K5a: per-tile states. S_j[p,n] = sum_{s in tile} g[s] v[s,p] k[s,n];
//      NE_j[c] = sum e[s] v[s,c].  grid (NTL=64, NH), block 256.
__global__ __launch_bounds__(256) void state_kernel(const float* __restrict__ k,
                                                    const float* __restrict__ v,
                                                    const float* __restrict__ sim,
                                                    const float* __restrict__ gates,
                                                    float* __restrict__ states,
                                                    float* __restrict__ nes) {
  const int j = blockIdx.x, head = blockIdx.y;
  const int s0 = j * SG;
  const int tid = threadIdx.x;
  __shared__ alignas(16) float Vs[SG][68];
  __shared__ alignas(16) float Kg[SG][68];
  __shared__ float Es[SG];

  const int r = tid >> 4, c = (tid & 15) * 4;
  const float* kh = k + ((size_t)head * LS + s0) * HD;
  const float* vh = v + ((size_t)head * LS + s0) * HD;
  const float g = gates[head * LS + s0 + r];
  *(float4*)&Vs[r][c] = *(const float4*)(vh + r * HD + c);
  float4 k4 = *(const float4*)(kh + r * HD + c);
  k4.x *= g; k4.y *= g; k4.z *= g; k4.w *= g;
  *(float4*)&Kg[r][c] = k4;
  if (tid < SG) Es[tid] = expf(sim[head * LS + s0 + tid]);
  __syncthreads();

  const int p0 = (tid >> 4) * 4, n0 = (tid & 15) * 4;
  float acc[4][4] = {};
  for (int s = 0; s < SG; ++s) {
    const float4 ra = *(const float4*)&Vs[s][p0];
    const float4 rb = *(const float4*)&Kg[s][n0];
    const float av[4] = {ra.x, ra.y, ra.z, ra.w};
    const float bv[4] = {rb.x, rb.y, rb.z, rb.w};
#pragma unroll
    for (int i = 0; i < 4; ++i)
#pragma unroll
      for (int jj = 0; jj < 4; ++jj)
        acc[i][jj] = fmaf(av[i], bv[jj], acc[i][jj]);
  }
  float* Sout = states + (size_t)(head * NTL + j) * 4096;
#pragma unroll
  for (int i = 0; i < 4; ++i)
    *(float4*)&Sout[(p0 + i) * 64 + n0] =
        make_float4(acc[i][0], acc[i][1], acc[i][2], acc[i][3]);

  if (tid < HD) {
    float ne = 0.f;
    for (int s = 0; s < SG; ++s) ne = fmaf(Es[s], Vs[s][tid], ne);
    nes[(size_t)(head * NTL + j) * HD + tid] = ne;
  }
}

// ---------------------------------------------------------------------------
// K5b: in-place exclusive prefix over the NTL tile-states (and NE vectors).
// grid (NH, 4 chunks), block 256; each thread owns 4 state elements.
__global__ __launch_bounds__(256) void prefix_kernel(float* __restrict__ states,
                                                     float* __restrict__ nes) {
  const int head = blockIdx.x, chunk = blockIdx.y;
  const int tid = threadIdx.x;
  const int off = chunk * 1024 + tid * 4;
  float4 acc = make_float4(0.f, 0.f, 0.f, 0.f);
  float* base = states + (size_t)head * NTL * 4096 + off;
#pragma unroll 4
  for (int j = 0; j < NTL; ++j) {
    float4* p = (float4*)(base + (size_t)j * 4096);
    const float4 sv = *p;
    *p = acc;
    acc.x += sv.x; acc.y += sv.y; acc.z += sv.z; acc.w += sv.w;
  }
  if (chunk == 0 && tid < HD) {
    float a = 0.f;
    float* nb = nes + (size_t)head * NTL * HD + tid;
#pragma unroll 4
    for (int j = 0; j < NTL; ++j) {
      float* p = nb + (size_t)j * HD;
      const float t = *p;
      *p = a;
      a += t;
    }
  }
}

// ---------------------------------------------------------------------------
// K5c: apply. O[t] = q[t] @ (P_tile + in-tile triangular), N likewise; epilogue.
// grid (NTL=64, NH), block 256.
__global__ __launch_bounds__(256) void apply_kernel(const float* __restrict__ q,
                                                    const float* __restrict__ k,
                                                    const float* __restrict__ v,
                                                    const float* __restrict__ sim,
                                                    const float* __restrict__ gates,
                                                    const float* __restrict__ m_s,
                                                    const float* __restrict__ Sraw,
                                                    const float* __restrict__ g_s,
                                                    const float* __restrict__ states,
                                                    const float* __restrict__ nes,
                                                    const float* __restrict__ kv_scale,
                                                    float* __restrict__ lerp) {
  const int bt = blockIdx.x, head = blockIdx.y;
  const int t0 = bt * SG;
  const int tid = threadIdx.x;
  __shared__ alignas(16) float Ps[64][68];
  __shared__ alignas(16) float Qs[SG][68];
  __shared__ alignas(16) float Vs[SG][68];
  __shared__ alignas(16) float Ks[SG][68];
  __shared__ alignas(16) float NEp[64];
  __shared__ float Ag[SG][SG + 1];
  __shared__ float Es[SG], Gs[SG];

  // stage prefix state (4096 floats)
  const float* Pg = states + (size_t)(head * NTL + bt) * 4096;
#pragma unroll
  for (int rep = 0; rep < 4; ++rep) {
    const int lin = rep * 1024 + tid * 4;
    *(float4*)&Ps[lin >> 6][lin & 63] = *(const float4*)(Pg + lin);
  }
  // stage q/k/v rows
  {
    const int r = tid >> 4, c = (tid & 15) * 4;
    const size_t rowbase = ((size_t)head * LS + t0 + r) * HD;
    *(float4*)&Qs[r][c] = *(const float4*)(q + rowbase + c);
    *(float4*)&Ks[r][c] = *(const float4*)(k + rowbase + c);
    *(float4*)&Vs[r][c] = *(const float4*)(v + rowbase + c);
  }
  if (tid < SG) {
    Es[tid] = expf(sim[head * LS + t0 + tid]);
    Gs[tid] = gates[head * LS + t0 + tid];
  }
  if (tid < HD) NEp[tid] = nes[(size_t)(head * NTL + bt) * HD + tid];
  __syncthreads();

  // in-tile A: Ag[t][s] = g[s] * (q_t . v_s) for s <= t
  {
    const int t = tid >> 4, s = tid & 15;
    float a = 0.f;
    if (s <= t) {
#pragma unroll
      for (int p = 0; p < 64; p += 4) {
        const float4 q4 = *(const float4*)&Qs[t][p];
        const float4 v4 = *(const float4*)&Vs[s][p];
        a = fmaf(q4.x, v4.x, a); a = fmaf(q4.y, v4.y, a);
        a = fmaf(q4.z, v4.z, a); a = fmaf(q4.w, v4.w, a);
      }
      a *= Gs[s];
    }
    Ag[t][s] = a;
  }
  __syncthreads();

  // output: thread -> row r, cols c0..c0+3
  const int r = tid >> 4, c0 = (tid & 15) * 4;
  float4 O = make_float4(0.f, 0.f, 0.f, 0.f);
#pragma unroll 8
  for (int p = 0; p < 64; ++p) {
    const float qv = Qs[r][p];
    const float4 p4 = *(const float4*)&Ps[p][c0];
    O.x = fmaf(qv, p4.x, O.x); O.y = fmaf(qv, p4.y, O.y);
    O.z = fmaf(qv, p4.z, O.z); O.w = fmaf(qv, p4.w, O.w);
  }
  float4 Nn = *(const float4*)&NEp[c0];
  for (int s = 0; s <= r; ++s) {
    const float ag = Ag[r][s];
    const float es = Es[s];
    const float4 k4 = *(const float4*)&Ks[s][c0];
    const float4 v4 = *(const float4*)&Vs[s][c0];
    O.x = fmaf(ag, k4.x, O.x); O.y = fmaf(ag, k4.y, O.y);
    O.z = fmaf(ag, k4.z, O.z); O.w = fmaf(ag, k4.w, O.w);
    Nn.x = fmaf(es, v4.x, Nn.x); Nn.y = fmaf(es, v4.y, Nn.y);
    Nn.z = fmaf(es, v4.z, Nn.z); Nn.w = fmaf(es, v4.w, Nn.w);
  }

  // epilogue
  const int t = t0 + r;
  const float m  = m_s[head * LS + t];
  const float em = expf(-m);
  const float ss = Sraw[head * LS + t] * em;
  const float inv = 1.f / (ss + EPSF);
  const float sw  = expf(sim[head * LS + t] - m) * inv;
  const float gi  = kv_scale[head] / (g_s[head * LS + t] + EPSF);
  const float ei  = em * inv;
  float4 res;
  {
    const float cx = O.x * gi, la = Nn.x * ei; res.x = cx + (la - cx) * sw;
  }
  { const float cx = O.y * gi, la = Nn.y * ei; res.y = cx + (la - cx) * sw; }
  { const float cx = O.z * gi, la = Nn.z * ei; res.z = cx + (la - cx) * sw; }
  { const float cx = O.w * gi, la = Nn.w * ei; res.w = cx + (la - cx) * sw; }
  *(float4*)&lerp[(size_t)t * DM + head * HD + c0] = res;
}

// ---------------------------------------------------------------------------
extern "C" void kernel_launch(void* const* d_in, const int* in_sizes, int n_in,
                              void* d_out, int out_size, void* d_ws, size_t ws_size,
                              hipStream_t stream) {
  (void)in_sizes; (void)n_in; (void)out_size; (void)ws_size;
  const float* x        = (const float*)d_in[0];
  const float* filters  = (const float*)d_in[1];
  const float* wq_w     = (const float*)d_in[2];
  const float* wq_b     = (const float*)d_in[3];
  const float* wk_w     = (const float*)d_in[4];
  const float* wk_b     = (const float*)d_in[5];
  const float* wv_w     = (const float*)d_in[6];
  const float* wv_b     = (const float*)d_in[7];
  const float* wo_w     = (const float*)d_in[8];
  const float* wo_b     = (const float*)d_in[9];
  const float* wg_w     = (const float*)d_in[10];
  const float* wg_b     = (const float*)d_in[11];
  const float* qk_scale = (const float*)d_in[12];
  const float* kv_scale = (const float*)d_in[13];

  float* ws = (float*)d_ws;
  const size_t NT = (size_t)LS * DM;  // 786432
  float* xt_a  = ws;
  float* xt_b  = ws + NT;
  float* q     = ws + 2 * NT;
  float* k     = ws + 3 * NT;
  float* v     = ws + 4 * NT;
  float* lerp  = xt_a;                // alias: xt consumed before apply writes
  float* sim   = ws + 5 * NT;
  float* gates = sim + NH * LS;
  float* m_s   = gates + NH * LS;
  float* Sraw  = m_s + NH * LS;
  float* g_s   = Sraw + NH * LS;
  float* states = g_s + NH * LS;              // 12*64*4096 = 3.1M floats
  float* nes    = states + (size_t)NH * NTL * 4096;  // 12*64*64

  conv_kernel<<<dim3(LS / 64, NH, 2), 256, 0, stream>>>(x, filters, xt_a);
  qkv_gemm<<<dim3(DM / 64, LS / 64, 3), 256, 0, stream>>>(
      xt_a, xt_b, wq_w, wq_b, wk_w, wk_b, wv_w, wv_b, q, k, v);
  norm_sim_gate<<<dim3(LS / 4, NH), 256, 0, stream>>>(
      q, k, v, wg_w, wg_b, qk_scale, kv_scale, sim, gates);
  scan_kernel<<<dim3(NH), 1024, 0, stream>>>(sim, gates, m_s, Sraw, g_s);
  state_kernel<<<dim3(NTL, NH), 256, 0, stream>>>(k, v, sim, gates, states, nes);
  prefix_kernel<<<dim3(NH, 4), 256, 0, stream>>>(states, nes);
  apply_kernel<<<dim3(NTL, NH), 256, 0, stream>>>(
      q, k, v, sim, gates, m_s, Sraw, g_s, states, nes, kv_scale, lerp);
  out_gemm<<<dim3(DM / 64, LS / 64), 256, 0, stream>>>(lerp, wo_w, wo_b, (float*)d_out);
}

// Round 5
// 155.617 us; speedup vs baseline: 3.0168x; 1.3343x over previous
//
#include <hip/hip_runtime.h>
#include <hip/hip_bf16.h>

constexpr int LS = 1024;   // sequence length
constexpr int DM = 768;    // model dim
constexpr int NH = 12;     // heads
constexpr int HD = 64;     // head dim
constexpr float EPSF = 1e-5f;
constexpr float ALPHAF = 0.01f;

constexpr int SG = 16;             // state granularity (rows per tile)
constexpr int NTL = LS / SG;       // 64 tiles per head
constexpr int WSZ = DM * DM;       // 589824 elements per weight matrix

typedef unsigned short u16;
typedef __attribute__((ext_vector_type(8))) short bf16x8;
typedef __attribute__((ext_vector_type(8))) unsigned short u16x8;
typedef __attribute__((ext_vector_type(4))) float f32x4;

__device__ __forceinline__ u16 f2b(float f) {
  unsigned u = __float_as_uint(f);
  u += 0x7FFFu + ((u >> 16) & 1u);   // round-to-nearest-even
  return (u16)(u >> 16);
}

// ---------------------------------------------------------------------------
// K0: transpose + bf16-convert the 4 weight matrices: wT[z][n][k] = bf16(w[k][n])
// grid (12, 12, 4), block 256
__global__ __launch_bounds__(256) void txw_kernel(const float* __restrict__ wq,
                                                  const float* __restrict__ wk,
                                                  const float* __restrict__ wv,
                                                  const float* __restrict__ wo,
                                                  u16* __restrict__ wT) {
  const int z = blockIdx.z;
  const float* src = (z == 0) ? wq : (z == 1) ? wk : (z == 2) ? wv : wo;
  u16* dst = wT + (size_t)z * WSZ;
  const int kb = blockIdx.x * 64, nb = blockIdx.y * 64;
  const int t = threadIdx.x;
  __shared__ float T[64][65];
#pragma unroll
  for (int rep = 0; rep < 4; ++rep) {
    const int r = rep * 16 + (t >> 4);
    const int c4 = (t & 15) * 4;
    const float4 v4 = *(const float4*)(src + (size_t)(kb + r) * DM + nb + c4);
    T[r][c4] = v4.x; T[r][c4 + 1] = v4.y; T[r][c4 + 2] = v4.z; T[r][c4 + 3] = v4.w;
  }
  __syncthreads();
#pragma unroll
  for (int rep = 0; rep < 4; ++rep) {
    const int n = rep * 16 + (t >> 4);
    const int k4 = (t & 15) * 4;
    ushort4 o;
    o.x = f2b(T[k4 + 0][n]); o.y = f2b(T[k4 + 1][n]);
    o.z = f2b(T[k4 + 2][n]); o.w = f2b(T[k4 + 3][n]);
    *(ushort4*)(dst + (size_t)(nb + n) * DM + kb + k4) = o;
  }
}

// ---------------------------------------------------------------------------
// K1: causal conv (banded stencil, parity-split partials). Unchanged (passing).
__global__ __launch_bounds__(256) void conv_kernel(const float* __restrict__ x,
                                                   const float* __restrict__ f,
                                                   float* __restrict__ xt_base) {
  const int i    = blockIdx.x;
  const int head = blockIdx.y;
  const int par  = blockIdx.z;
  const int tid  = threadIdx.x;
  const int c    = tid & 63;
  const int sg   = tid >> 6;
  const int tbase = i * 64;
  const int l0w   = tbase + sg * 16;
  float* __restrict__ xt_p = xt_base + (size_t)par * LS * DM;

  __shared__ float4 Xs2[28][64];
  __shared__ float4 Fg[32][64];

  {
    const float4 z4 = make_float4(0.f, 0.f, 0.f, 0.f);
#pragma unroll
    for (int k = 0; k < 3; ++k) {
      const int lin = k * 256 + tid;
      const int g   = lin >> 6;
      const int cc  = lin & 63;
      const int grp = (g < 4) ? g : (16 + g);
      Xs2[grp][cc] = z4;
    }
  }

  float acc[16];
#pragma unroll
  for (int t = 0; t < 16; ++t) acc[t] = 0.f;

  const float* xg = x + head * HD + c;
  const float* fg = f + c;

  for (int j = par; j <= i; j += 2) {
    const int sbase = j * 64;
    const int b0 = (j < i) ? (tbase - sbase - 64) : 0;
#pragma unroll
    for (int k = 0; k < 4; ++k) {
      const int m  = sg + 4 * k;
      const int ss = 4 * m;
      float4 v4;
      v4.x = xg[(sbase + ss + 0) * DM];
      v4.y = xg[(sbase + ss + 1) * DM];
      v4.z = xg[(sbase + ss + 2) * DM];
      v4.w = xg[(sbase + ss + 3) * DM];
      Xs2[4 + m][c] = v4;
    }
#pragma unroll
    for (int k = 0; k < 8; ++k) {
      const int m  = sg + 4 * k;
      const int d4 = b0 + 4 * m;
      float4 v4;
      v4.x = fg[(d4 + 0) * HD];
      v4.y = fg[(d4 + 1) * HD];
      v4.z = fg[(d4 + 2) * HD];
      v4.w = fg[(d4 + 3) * HD];
      Fg[m][c] = v4;
    }
    __syncthreads();

    const int dstart = (j < i) ? (b0 + sg * 16) : 0;
    const int nsteps = (j < i) ? 5 : (sg + 1);
    for (int k = 0; k < nsteps; ++k) {
      const int d0    = dstart + 16 * k;
      const int rbase = l0w - d0 - sbase;
      float fr[16];
      const int fgb = (d0 - b0) >> 2;
#pragma unroll
      for (int m = 0; m < 4; ++m) {
        const float4 v4 = Fg[fgb + m][c];
        fr[4 * m + 0] = v4.x; fr[4 * m + 1] = v4.y;
        fr[4 * m + 2] = v4.z; fr[4 * m + 3] = v4.w;
      }
      float xw[32];
      const int xgb = rbase >> 2;
#pragma unroll
      for (int m = 0; m < 8; ++m) {
        const float4 v4 = Xs2[xgb + m][c];
        xw[4 * m + 0] = v4.x; xw[4 * m + 1] = v4.y;
        xw[4 * m + 2] = v4.z; xw[4 * m + 3] = v4.w;
      }
#pragma unroll
      for (int li = 0; li < 16; ++li)
#pragma unroll
        for (int dd = 0; dd < 16; ++dd)
          acc[li] = fmaf(fr[dd], xw[li - dd + 16], acc[li]);
    }
    __syncthreads();
  }

#pragma unroll
  for (int li = 0; li < 16; ++li)
    xt_p[(size_t)(l0w + li) * DM + head * HD + c] = acc[li];
}

// ---------------------------------------------------------------------------
// K1b: xtb[l][k] = bf16(xa + xb). grid 384, block 256 (8 elems/thread).
__global__ __launch_bounds__(256) void pack_xt(const float* __restrict__ xa,
                                               const float* __restrict__ xb,
                                               u16* __restrict__ xtb) {
  const size_t i = ((size_t)blockIdx.x * 256 + threadIdx.x) * 8;
  const float4 a0 = *(const float4*)(xa + i);
  const float4 a1 = *(const float4*)(xa + i + 4);
  const float4 b0 = *(const float4*)(xb + i);
  const float4 b1 = *(const float4*)(xb + i + 4);
  u16x8 o;
  o[0] = f2b(a0.x + b0.x); o[1] = f2b(a0.y + b0.y);
  o[2] = f2b(a0.z + b0.z); o[3] = f2b(a0.w + b0.w);
  o[4] = f2b(a1.x + b1.x); o[5] = f2b(a1.y + b1.y);
  o[6] = f2b(a1.z + b1.z); o[7] = f2b(a1.w + b1.w);
  *(u16x8*)(xtb + i) = o;
}

// ---------------------------------------------------------------------------
// K2: q/k/v = xtb @ W + b via bf16 MFMA, direct-global fragments (no LDS).
// grid (12 heads, 16 row-tiles, 3), block 256 (4 waves; wave = 16 rows x 64 cols)
__global__ __launch_bounds__(256) void qkv_mfma(const u16* __restrict__ xtb,
                                                const u16* __restrict__ wT,
                                                const float* __restrict__ bq,
                                                const float* __restrict__ bk,
                                                const float* __restrict__ bv,
                                                float* __restrict__ qo,
                                                float* __restrict__ ko,
                                                float* __restrict__ vo) {
  const int ct = blockIdx.x, rt = blockIdx.y, z = blockIdx.z;
  const u16* wt = wT + (size_t)z * WSZ;
  const float* bias = (z == 0) ? bq : (z == 1) ? bk : bv;
  float* out = (z == 0) ? qo : (z == 1) ? ko : vo;
  const int tid = threadIdx.x, wv_ = tid >> 6, l = tid & 63;
  const int row = rt * 64 + wv_ * 16 + (l & 15);
  const int kb = (l >> 4) * 8;
  const u16* arow = xtb + (size_t)row * DM + kb;
  const u16* brow = wt + (size_t)(ct * 64 + (l & 15)) * DM + kb;

  f32x4 acc[4] = {};
#pragma unroll 4
  for (int k0 = 0; k0 < DM; k0 += 32) {
    const bf16x8 a = *(const bf16x8*)(arow + k0);
#pragma unroll
    for (int nt = 0; nt < 4; ++nt) {
      const bf16x8 b = *(const bf16x8*)(brow + (size_t)nt * 16 * DM + k0);
      acc[nt] = __builtin_amdgcn_mfma_f32_16x16x32_bf16(a, b, acc[nt], 0, 0, 0);
    }
  }

  const int r0 = rt * 64 + wv_ * 16 + ((l >> 4) << 2);
  const int c  = l & 15;
#pragma unroll
  for (int nt = 0; nt < 4; ++nt) {
    const int col = nt * 16 + c;
    const float bb = bias[ct * 64 + col];
#pragma unroll
    for (int r = 0; r < 4; ++r)
      out[((size_t)ct * LS + r0 + r) * HD + col] = acc[nt][r] + bb;
  }
}

// ---------------------------------------------------------------------------
// K6: y = lerpb @ wo + b via bf16 MFMA, direct-global fragments.
// grid (12, 16), block 256
__global__ __launch_bounds__(256) void out_mfma(const u16* __restrict__ lerpb,
                                                const u16* __restrict__ woT,
                                                const float* __restrict__ bias,
                                                float* __restrict__ out) {
  const int ct = blockIdx.x, rt = blockIdx.y;
  const int tid = threadIdx.x, wv_ = tid >> 6, l = tid & 63;
  const int row = rt * 64 + wv_ * 16 + (l & 15);
  const int kb = (l >> 4) * 8;
  const u16* arow = lerpb + (size_t)row * DM + kb;
  const u16* brow = woT + (size_t)(ct * 64 + (l & 15)) * DM + kb;

  f32x4 acc[4] = {};
#pragma unroll 4
  for (int k0 = 0; k0 < DM; k0 += 32) {
    const bf16x8 a = *(const bf16x8*)(arow + k0);
#pragma unroll
    for (int nt = 0; nt < 4; ++nt) {
      const bf16x8 b = *(const bf16x8*)(brow + (size_t)nt * 16 * DM + k0);
      acc[nt] = __builtin_amdgcn_mfma_f32_16x16x32_bf16(a, b, acc[nt], 0, 0, 0);
    }
  }

  const int r0 = rt * 64 + wv_ * 16 + ((l >> 4) << 2);
  const int c  = l & 15;
#pragma unroll
  for (int nt = 0; nt < 4; ++nt) {
    const int col = ct * 64 + nt * 16 + c;
    const float bb = bias[col];
#pragma unroll
    for (int r = 0; r < 4; ++r)
      out[(size_t)(r0 + r) * DM + col] = acc[nt][r] + bb;
  }
}

// ---------------------------------------------------------------------------
// K3: l2norm + sim + gates. Unchanged (passing).
__global__ void norm_sim_gate(float* __restrict__ q, float* __restrict__ k, float* __restrict__ v,
                              const float* __restrict__ wg, const float* __restrict__ wgb,
                              const float* __restrict__ qk_scale, const float* __restrict__ kv_scale,
                              float* __restrict__ sim, float* __restrict__ gates) {
  const int w = threadIdx.x >> 6, lane = threadIdx.x & 63;
  const int l = blockIdx.x * 4 + w;
  const int head = blockIdx.y;
  const size_t idx = ((size_t)head * LS + l) * HD + lane;
  float qv = q[idx], kv = k[idx], vv = v[idx];

  auto red = [](float x) {
#pragma unroll
    for (int o = 32; o; o >>= 1) x += __shfl_xor(x, o);
    return x;
  };
  const float qn = fmaxf(sqrtf(red(qv * qv)), 1e-12f);
  const float kn = fmaxf(sqrtf(red(kv * kv)), 1e-12f);
  const float vn = fmaxf(sqrtf(red(vv * vv)), 1e-12f);
  qv /= qn; kv /= kn; vv /= vn;
  q[idx] = qv; k[idx] = kv; v[idx] = vv;

  const float s = red(qv * kv) * qk_scale[head];

  __shared__ float vs[4][64];
  vs[w][lane] = vv;
  __syncthreads();
  float t = 0.f;
#pragma unroll 8
  for (int p = 0; p < 64; ++p) t = fmaf(vs[w][p], wg[p * 64 + lane], t);
  float gl = red(t * kv) * kv_scale[head] + wgb[0];
  gl = gl > 0.f ? gl : ALPHAF * gl;
  const float g = gl * gl + EPSF;
  if (lane == 0) {
    sim[head * LS + l] = s;
    gates[head * LS + l] = g;
  }
}

// ---------------------------------------------------------------------------
// K4: per-head scalar prefix scans. Unchanged (passing).
__global__ void scan_kernel(const float* __restrict__ sim, const float* __restrict__ gates,
                            float* __restrict__ m_s, float* __restrict__ Sraw,
                            float* __restrict__ g_s) {
  const int head = blockIdx.x, t = threadIdx.x;
  __shared__ float bm[1024], bs[1024], bg[1024];
  const float sv = sim[head * LS + t];
  float m = sv, S = expf(sv), g = gates[head * LS + t];
  bm[t] = m; bs[t] = S; bg[t] = g;
  __syncthreads();
  for (int off = 1; off < 1024; off <<= 1) {
    float om = -1e30f, os = 0.f, og = 0.f;
    if (t >= off) { om = bm[t - off]; os = bs[t - off]; og = bg[t - off]; }
    __syncthreads();
    m = fmaxf(m, om); S += os; g += og;
    bm[t] = m; bs[t] = S; bg[t] = g;
    __syncthreads();
  }
  m_s[head * LS + t] = m;
  Sraw[head * LS + t] = S;
  g_s[head * LS + t] = g;
}

// ---------------------------------------------------------------------------
// K5a: per-tile states. Unchanged (passing).
__global__ __launch_bounds__(256) void state_kernel(const float* __restrict__ k,
                                                    const float* __restrict__ v,
                                                    const float* __restrict__ sim,
                                                    const float* __restrict__ gates,
                                                    float* __restrict__ states,
                                                    float* __restrict__ nes) {
  const int j = blockIdx.x, head = blockIdx.y;
  const int s0 = j * SG;
  const int tid = threadIdx.x;
  __shared__ alignas(16) float Vs[SG][68];
  __shared__ alignas(16) float Kg[SG][68];
  __shared__ float Es[SG];

  const int r = tid >> 4, c = (tid & 15) * 4;
  const float* kh = k + ((size_t)head * LS + s0) * HD;
  const float* vh = v + ((size_t)head * LS + s0) * HD;
  const float g = gates[head * LS + s0 + r];
  *(float4*)&Vs[r][c] = *(const float4*)(vh + r * HD + c);
  float4 k4 = *(const float4*)(kh + r * HD + c);
  k4.x *= g; k4.y *= g; k4.z *= g; k4.w *= g;
  *(float4*)&Kg[r][c] = k4;
  if (tid < SG) Es[tid] = expf(sim[head * LS + s0 + tid]);
  __syncthreads();

  const int p0 = (tid >> 4) * 4, n0 = (tid & 15) * 4;
  float acc[4][4] = {};
  for (int s = 0; s < SG; ++s) {
    const float4 ra = *(const float4*)&Vs[s][p0];
    const float4 rb = *(const float4*)&Kg[s][n0];
    const float av[4] = {ra.x, ra.y, ra.z, ra.w};
    const float bv[4] = {rb.x, rb.y, rb.z, rb.w};
#pragma unroll
    for (int i = 0; i < 4; ++i)
#pragma unroll
      for (int jj = 0; jj < 4; ++jj)
        acc[i][jj] = fmaf(av[i], bv[jj], acc[i][jj]);
  }
  float* Sout = states + (size_t)(head * NTL + j) * 4096;
#pragma unroll
  for (int i = 0; i < 4; ++i)
    *(float4*)&Sout[(p0 + i) * 64 + n0] =
        make_float4(acc[i][0], acc[i][1], acc[i][2], acc[i][3]);

  if (tid < HD) {
    float ne = 0.f;
    for (int s = 0; s < SG; ++s) ne = fmaf(Es[s], Vs[s][tid], ne);
    nes[(size_t)(head * NTL + j) * HD + tid] = ne;
  }
}

// ---------------------------------------------------------------------------
// K5b: in-place exclusive prefix over tile-states. Unchanged (passing).
__global__ __launch_bounds__(256) void prefix_kernel(float* __restrict__ states,
                                                     float* __restrict__ nes) {
  const int head = blockIdx.x, chunk = blockIdx.y;
  const int tid = threadIdx.x;
  const int off = chunk * 1024 + tid * 4;
  float4 acc = make_float4(0.f, 0.f, 0.f, 0.f);
  float* base = states + (size_t)head * NTL * 4096 + off;
#pragma unroll 4
  for (int j = 0; j < NTL; ++j) {
    float4* p = (float4*)(base + (size_t)j * 4096);
    const float4 sv = *p;
    *p = acc;
    acc.x += sv.x; acc.y += sv.y; acc.z += sv.z; acc.w += sv.w;
  }
  if (chunk == 0 && tid < HD) {
    float a = 0.f;
    float* nb = nes + (size_t)head * NTL * HD + tid;
#pragma unroll 4
    for (int j = 0; j < NTL; ++j) {
      float* p = nb + (size_t)j * HD;
      const float t = *p;
      *p = a;
      a += t;
    }
  }
}

// ---------------------------------------------------------------------------
// K5c: apply + epilogue; now writes lerp in bf16 for the MFMA out-GEMM.
// grid (NTL=64, NH), block 256.
__global__ __launch_bounds__(256) void apply_kernel(const float* __restrict__ q,
                                                    const float* __restrict__ k,
                                                    const float* __restrict__ v,
                                                    const float* __restrict__ sim,
                                                    const float* __restrict__ gates,
                                                    const float* __restrict__ m_s,
                                                    const float* __restrict__ Sraw,
                                                    const float* __restrict__ g_s,
                                                    const float* __restrict__ states,
                                                    const float* __restrict__ nes,
                                                    const float* __restrict__ kv_scale,
                                                    u16* __restrict__ lerpb) {
  const int bt = blockIdx.x, head = blockIdx.y;
  const int t0 = bt * SG;
  const int tid = threadIdx.x;
  __shared__ alignas(16) float Ps[64][68];
  __shared__ alignas(16) float Qs[SG][68];
  __shared__ alignas(16) float Vs[SG][68];
  __shared__ alignas(16) float Ks[SG][68];
  __shared__ alignas(16) float NEp[64];
  __shared__ float Ag[SG][SG + 1];
  __shared__ float Es[SG], Gs[SG];

  const float* Pg = states + (size_t)(head * NTL + bt) * 4096;
#pragma unroll
  for (int rep = 0; rep < 4; ++rep) {
    const int lin = rep * 1024 + tid * 4;
    *(float4*)&Ps[lin >> 6][lin & 63] = *(const float4*)(Pg + lin);
  }
  {
    const int r = tid >> 4, c = (tid & 15) * 4;
    const size_t rowbase = ((size_t)head * LS + t0 + r) * HD;
    *(float4*)&Qs[r][c] = *(const float4*)(q + rowbase + c);
    *(float4*)&Ks[r][c] = *(const float4*)(k + rowbase + c);
    *(float4*)&Vs[r][c] = *(const float4*)(v + rowbase + c);
  }
  if (tid < SG) {
    Es[tid] = expf(sim[head * LS + t0 + tid]);
    Gs[tid] = gates[head * LS + t0 + tid];
  }
  if (tid < HD) NEp[tid] = nes[(size_t)(head * NTL + bt) * HD + tid];
  __syncthreads();

  {
    const int t = tid >> 4, s = tid & 15;
    float a = 0.f;
    if (s <= t) {
#pragma unroll
      for (int p = 0; p < 64; p += 4) {
        const float4 q4 = *(const float4*)&Qs[t][p];
        const float4 v4 = *(const float4*)&Vs[s][p];
        a = fmaf(q4.x, v4.x, a); a = fmaf(q4.y, v4.y, a);
        a = fmaf(q4.z, v4.z, a); a = fmaf(q4.w, v4.w, a);
      }
      a *= Gs[s];
    }
    Ag[t][s] = a;
  }
  __syncthreads();

  const int r = tid >> 4, c0 = (tid & 15) * 4;
  float4 O = make_float4(0.f, 0.f, 0.f, 0.f);
#pragma unroll 8
  for (int p = 0; p < 64; ++p) {
    const float qv = Qs[r][p];
    const float4 p4 = *(const float4*)&Ps[p][c0];
    O.x = fmaf(qv, p4.x, O.x); O.y = fmaf(qv, p4.y, O.y);
    O.z = fmaf(qv, p4.z, O.z); O.w = fmaf(qv, p4.w, O.w);
  }
  float4 Nn = *(const float4*)&NEp[c0];
  for (int s = 0; s <= r; ++s) {
    const float ag = Ag[r][s];
    const float es = Es[s];
    const float4 k4 = *(const float4*)&Ks[s][c0];
    const float4 v4 = *(const float4*)&Vs[s][c0];
    O.x = fmaf(ag, k4.x, O.x); O.y = fmaf(ag, k4.y, O.y);
    O.z = fmaf(ag, k4.z, O.z); O.w = fmaf(ag, k4.w, O.w);
    Nn.x = fmaf(es, v4.x, Nn.x); Nn.y = fmaf(es, v4.y, Nn.y);
    Nn.z = fmaf(es, v4.z, Nn.z); Nn.w = fmaf(es, v4.w, Nn.w);
  }

  const int t = t0 + r;
  const float m  = m_s[head * LS + t];
  const float em = expf(-m);
  const float ss = Sraw[head * LS + t] * em;
  const float inv = 1.f / (ss + EPSF);
  const float sw  = expf(sim[head * LS + t] - m) * inv;
  const float gi  = kv_scale[head] / (g_s[head * LS + t] + EPSF);
  const float ei  = em * inv;
  float rx, ry, rz, rw;
  { const float cx = O.x * gi, la = Nn.x * ei; rx = cx + (la - cx) * sw; }
  { const float cx = O.y * gi, la = Nn.y * ei; ry = cx + (la - cx) * sw; }
  { const float cx = O.z * gi, la = Nn.z * ei; rz = cx + (la - cx) * sw; }
  { const float cx = O.w * gi, la = Nn.w * ei; rw = cx + (la - cx) * sw; }
  ushort4 ob;
  ob.x = f2b(rx); ob.y = f2b(ry); ob.z = f2b(rz); ob.w = f2b(rw);
  *(ushort4*)&lerpb[(size_t)t * DM + head * HD + c0] = ob;
}

// ---------------------------------------------------------------------------
extern "C" void kernel_launch(void* const* d_in, const int* in_sizes, int n_in,
                              void* d_out, int out_size, void* d_ws, size_t ws_size,
                              hipStream_t stream) {
  (void)in_sizes; (void)n_in; (void)out_size; (void)ws_size;
  const float* x        = (const float*)d_in[0];
  const float* filters  = (const float*)d_in[1];
  const float* wq_w     = (const float*)d_in[2];
  const float* wq_b     = (const float*)d_in[3];
  const float* wk_w     = (const float*)d_in[4];
  const float* wk_b     = (const float*)d_in[5];
  const float* wv_w     = (const float*)d_in[6];
  const float* wv_b     = (const float*)d_in[7];
  const float* wo_w     = (const float*)d_in[8];
  const float* wo_b     = (const float*)d_in[9];
  const float* wg_w     = (const float*)d_in[10];
  const float* wg_b     = (const float*)d_in[11];
  const float* qk_scale = (const float*)d_in[12];
  const float* kv_scale = (const float*)d_in[13];

  float* ws = (float*)d_ws;
  const size_t NT = (size_t)LS * DM;  // 786432
  float* xt_a  = ws;
  float* xt_b  = ws + NT;
  float* q     = ws + 2 * NT;
  float* k     = ws + 3 * NT;
  float* v     = ws + 4 * NT;
  float* sim   = ws + 5 * NT;
  float* gates = sim + NH * LS;
  float* m_s   = gates + NH * LS;
  float* Sraw  = m_s + NH * LS;
  float* g_s   = Sraw + NH * LS;
  float* states = g_s + NH * LS;                       // 12*64*4096
  float* nes    = states + (size_t)NH * NTL * 4096;    // 12*64*64
  u16*   xtb    = (u16*)(nes + (size_t)NH * NTL * HD); // NT bf16
  u16*   wT     = xtb + NT;                            // 4 * 589824 bf16
  u16*   lerpb  = (u16*)xt_a;                          // alias: xt dead after pack

  txw_kernel<<<dim3(DM / 64, DM / 64, 4), 256, 0, stream>>>(wq_w, wk_w, wv_w, wo_w, wT);
  conv_kernel<<<dim3(LS / 64, NH, 2), 256, 0, stream>>>(x, filters, xt_a);
  pack_xt<<<dim3(NT / 2048), 256, 0, stream>>>(xt_a, xt_b, xtb);
  qkv_mfma<<<dim3(NH, LS / 64, 3), 256, 0, stream>>>(
      xtb, wT, wq_b, wk_b, wv_b, q, k, v);
  norm_sim_gate<<<dim3(LS / 4, NH), 256, 0, stream>>>(
      q, k, v, wg_w, wg_b, qk_scale, kv_scale, sim, gates);
  scan_kernel<<<dim3(NH), 1024, 0, stream>>>(sim, gates, m_s, Sraw, g_s);
  state_kernel<<<dim3(NTL, NH), 256, 0, stream>>>(k, v, sim, gates, states, nes);
  prefix_kernel<<<dim3(NH, 4), 256, 0, stream>>>(states, nes);
  apply_kernel<<<dim3(NTL, NH), 256, 0, stream>>>(
      q, k, v, sim, gates, m_s, Sraw, g_s, states, nes, kv_scale, lerpb);
  out_mfma<<<dim3(DM / 64, LS / 64), 256, 0, stream>>>(
      lerpb, wT + 3 * (size_t)WSZ, wo_b, (float*)d_out);
}

// Round 6
// 147.779 us; speedup vs baseline: 3.1768x; 1.0530x over previous
//
#include <hip/hip_runtime.h>
#include <hip/hip_bf16.h>

constexpr int LS = 1024;   // sequence length
constexpr int DM = 768;    // model dim
constexpr int NH = 12;     // heads
constexpr int HD = 64;     // head dim
constexpr float EPSF = 1e-5f;
constexpr float ALPHAF = 0.01f;

constexpr int SG = 16;             // state granularity (rows per tile)
constexpr int NTL = LS / SG;       // 64 tiles per head
constexpr int WSZ = DM * DM;       // 589824 elements per weight matrix

typedef unsigned short u16;
typedef __attribute__((ext_vector_type(8))) short bf16x8;
typedef __attribute__((ext_vector_type(8))) unsigned short u16x8;
typedef __attribute__((ext_vector_type(4))) float f32x4;

__device__ __forceinline__ u16 f2b(float f) {
  unsigned u = __float_as_uint(f);
  u += 0x7FFFu + ((u >> 16) & 1u);   // round-to-nearest-even
  return (u16)(u >> 16);
}

// ---------------------------------------------------------------------------
// K0: transpose + bf16-convert the 4 weight matrices: wT[z][n][k] = bf16(w[k][n])
// grid (12, 12, 4), block 256
__global__ __launch_bounds__(256) void txw_kernel(const float* __restrict__ wq,
                                                  const float* __restrict__ wk,
                                                  const float* __restrict__ wv,
                                                  const float* __restrict__ wo,
                                                  u16* __restrict__ wT) {
  const int z = blockIdx.z;
  const float* src = (z == 0) ? wq : (z == 1) ? wk : (z == 2) ? wv : wo;
  u16* dst = wT + (size_t)z * WSZ;
  const int kb = blockIdx.x * 64, nb = blockIdx.y * 64;
  const int t = threadIdx.x;
  __shared__ float T[64][65];
#pragma unroll
  for (int rep = 0; rep < 4; ++rep) {
    const int r = rep * 16 + (t >> 4);
    const int c4 = (t & 15) * 4;
    const float4 v4 = *(const float4*)(src + (size_t)(kb + r) * DM + nb + c4);
    T[r][c4] = v4.x; T[r][c4 + 1] = v4.y; T[r][c4 + 2] = v4.z; T[r][c4 + 3] = v4.w;
  }
  __syncthreads();
#pragma unroll
  for (int rep = 0; rep < 4; ++rep) {
    const int n = rep * 16 + (t >> 4);
    const int k4 = (t & 15) * 4;
    ushort4 o;
    o.x = f2b(T[k4 + 0][n]); o.y = f2b(T[k4 + 1][n]);
    o.z = f2b(T[k4 + 2][n]); o.w = f2b(T[k4 + 3][n]);
    *(ushort4*)(dst + (size_t)(nb + n) * DM + kb + k4) = o;
  }
}

// ---------------------------------------------------------------------------
// K1: causal conv, banded stencil, parity-4 partial split, filters read
// directly from global (L2-hot, shared across heads). LDS = X tile only.
// grid (16 l-tiles, 12 heads, 4 parities), block 256.
__global__ __launch_bounds__(256) void conv_kernel(const float* __restrict__ x,
                                                   const float* __restrict__ f,
                                                   float* __restrict__ p0,
                                                   float* __restrict__ p1,
                                                   float* __restrict__ p2,
                                                   float* __restrict__ p3) {
  const int i    = blockIdx.x;
  const int head = blockIdx.y;
  const int par  = blockIdx.z;
  const int tid  = threadIdx.x;
  const int c    = tid & 63;
  const int sg   = tid >> 6;
  const int tbase = i * 64;
  const int l0w   = tbase + sg * 16;
  float* __restrict__ xt_p = (par == 0) ? p0 : (par == 1) ? p1 : (par == 2) ? p2 : p3;

  // r_pad = (l - d - sbase) + 16 in [0,111] -> groups 0..27 (data groups 4..19)
  __shared__ float4 Xs2[28][64];

  // zero the pad groups (0..3 and 20..27) once
  {
    const float4 z4 = make_float4(0.f, 0.f, 0.f, 0.f);
#pragma unroll
    for (int k = 0; k < 3; ++k) {
      const int lin = k * 256 + tid;
      const int g   = lin >> 6;
      const int cc  = lin & 63;
      const int grp = (g < 4) ? g : (16 + g);
      Xs2[grp][cc] = z4;
    }
  }

  float acc[16];
#pragma unroll
  for (int t = 0; t < 16; ++t) acc[t] = 0.f;

  const float* xg   = x + head * HD + c;
  const float* fcol = f + c;

  for (int j = par; j <= i; j += 4) {
    const int sbase = j * 64;
    const int b0 = (j < i) ? (tbase - sbase - 64) : 0;  // band base, >= 0
    // stage X tile: rows 0..63 -> groups 4..19
#pragma unroll
    for (int k = 0; k < 4; ++k) {
      const int m  = sg + 4 * k;
      const int ss = 4 * m;
      float4 v4;
      v4.x = xg[(sbase + ss + 0) * DM];
      v4.y = xg[(sbase + ss + 1) * DM];
      v4.z = xg[(sbase + ss + 2) * DM];
      v4.w = xg[(sbase + ss + 3) * DM];
      Xs2[4 + m][c] = v4;
    }
    __syncthreads();

    const int dstart = (j < i) ? (b0 + sg * 16) : 0;
    const int nsteps = (j < i) ? 5 : (sg + 1);
    for (int k = 0; k < nsteps; ++k) {
      const int d0    = dstart + 16 * k;
      const int rbase = l0w - d0 - sbase;      // multiple of 16, in [0,64]
      float fr[16];
#pragma unroll
      for (int m = 0; m < 16; ++m) fr[m] = fcol[(d0 + m) * HD];
      float xw[32];
      const int xgb = rbase >> 2;
#pragma unroll
      for (int m = 0; m < 8; ++m) {
        const float4 v4 = Xs2[xgb + m][c];
        xw[4 * m + 0] = v4.x; xw[4 * m + 1] = v4.y;
        xw[4 * m + 2] = v4.z; xw[4 * m + 3] = v4.w;
      }
#pragma unroll
      for (int li = 0; li < 16; ++li)
#pragma unroll
        for (int dd = 0; dd < 16; ++dd)
          acc[li] = fmaf(fr[dd], xw[li - dd + 16], acc[li]);
    }
    __syncthreads();
  }

#pragma unroll
  for (int li = 0; li < 16; ++li)
    xt_p[(size_t)(l0w + li) * DM + head * HD + c] = acc[li];
}

// ---------------------------------------------------------------------------
// K1b: xtb[l][k] = bf16(p0+p1+p2+p3). grid 384, block 256 (8 elems/thread).
__global__ __launch_bounds__(256) void pack_xt(const float* __restrict__ a,
                                               const float* __restrict__ b,
                                               const float* __restrict__ cc,
                                               const float* __restrict__ d,
                                               u16* __restrict__ xtb) {
  const size_t i = ((size_t)blockIdx.x * 256 + threadIdx.x) * 8;
  u16x8 o;
#pragma unroll
  for (int h = 0; h < 2; ++h) {
    const float4 a4 = *(const float4*)(a + i + h * 4);
    const float4 b4 = *(const float4*)(b + i + h * 4);
    const float4 c4 = *(const float4*)(cc + i + h * 4);
    const float4 d4 = *(const float4*)(d + i + h * 4);
    o[h * 4 + 0] = f2b(a4.x + b4.x + c4.x + d4.x);
    o[h * 4 + 1] = f2b(a4.y + b4.y + c4.y + d4.y);
    o[h * 4 + 2] = f2b(a4.z + b4.z + c4.z + d4.z);
    o[h * 4 + 3] = f2b(a4.w + b4.w + c4.w + d4.w);
  }
  *(u16x8*)(xtb + i) = o;
}

// ---------------------------------------------------------------------------
// K2: q/k/v = xtb @ W + b via bf16 MFMA, direct-global fragments (no LDS).
// grid (12 heads, 16 row-tiles, 3), block 256
__global__ __launch_bounds__(256) void qkv_mfma(const u16* __restrict__ xtb,
                                                const u16* __restrict__ wT,
                                                const float* __restrict__ bq,
                                                const float* __restrict__ bk,
                                                const float* __restrict__ bv,
                                                float* __restrict__ qo,
                                                float* __restrict__ ko,
                                                float* __restrict__ vo) {
  const int ct = blockIdx.x, rt = blockIdx.y, z = blockIdx.z;
  const u16* wt = wT + (size_t)z * WSZ;
  const float* bias = (z == 0) ? bq : (z == 1) ? bk : bv;
  float* out = (z == 0) ? qo : (z == 1) ? ko : vo;
  const int tid = threadIdx.x, wv_ = tid >> 6, l = tid & 63;
  const int row = rt * 64 + wv_ * 16 + (l & 15);
  const int kb = (l >> 4) * 8;
  const u16* arow = xtb + (size_t)row * DM + kb;
  const u16* brow = wt + (size_t)(ct * 64 + (l & 15)) * DM + kb;

  f32x4 acc[4] = {};
#pragma unroll 4
  for (int k0 = 0; k0 < DM; k0 += 32) {
    const bf16x8 a = *(const bf16x8*)(arow + k0);
#pragma unroll
    for (int nt = 0; nt < 4; ++nt) {
      const bf16x8 b = *(const bf16x8*)(brow + (size_t)nt * 16 * DM + k0);
      acc[nt] = __builtin_amdgcn_mfma_f32_16x16x32_bf16(a, b, acc[nt], 0, 0, 0);
    }
  }

  const int r0 = rt * 64 + wv_ * 16 + ((l >> 4) << 2);
  const int c  = l & 15;
#pragma unroll
  for (int nt = 0; nt < 4; ++nt) {
    const int col = nt * 16 + c;
    const float bb = bias[ct * 64 + col];
#pragma unroll
    for (int r = 0; r < 4; ++r)
      out[((size_t)ct * LS + r0 + r) * HD + col] = acc[nt][r] + bb;
  }
}

// ---------------------------------------------------------------------------
// K6: y = lerpb @ wo + b via bf16 MFMA, direct-global fragments.
// grid (12, 16), block 256
__global__ __launch_bounds__(256) void out_mfma(const u16* __restrict__ lerpb,
                                                const u16* __restrict__ woT,
                                                const float* __restrict__ bias,
                                                float* __restrict__ out) {
  const int ct = blockIdx.x, rt = blockIdx.y;
  const int tid = threadIdx.x, wv_ = tid >> 6, l = tid & 63;
  const int row = rt * 64 + wv_ * 16 + (l & 15);
  const int kb = (l >> 4) * 8;
  const u16* arow = lerpb + (size_t)row * DM + kb;
  const u16* brow = woT + (size_t)(ct * 64 + (l & 15)) * DM + kb;

  f32x4 acc[4] = {};
#pragma unroll 4
  for (int k0 = 0; k0 < DM; k0 += 32) {
    const bf16x8 a = *(const bf16x8*)(arow + k0);
#pragma unroll
    for (int nt = 0; nt < 4; ++nt) {
      const bf16x8 b = *(const bf16x8*)(brow + (size_t)nt * 16 * DM + k0);
      acc[nt] = __builtin_amdgcn_mfma_f32_16x16x32_bf16(a, b, acc[nt], 0, 0, 0);
    }
  }

  const int r0 = rt * 64 + wv_ * 16 + ((l >> 4) << 2);
  const int c  = l & 15;
#pragma unroll
  for (int nt = 0; nt < 4; ++nt) {
    const int col = ct * 64 + nt * 16 + c;
    const float bb = bias[col];
#pragma unroll
    for (int r = 0; r < 4; ++r)
      out[(size_t)(r0 + r) * DM + col] = acc[nt][r] + bb;
  }
}

// ---------------------------------------------------------------------------
// K3: l2norm + sim + gates. Unchanged (passing).
__global__ void norm_sim_gate(float* __restrict__ q, float* __restrict__ k, float* __restrict__ v,
                              const float* __restrict__ wg, const float* __restrict__ wgb,
                              const float* __restrict__ qk_scale, const float* __restrict__ kv_scale,
                              float* __restrict__ sim, float* __restrict__ gates) {
  const int w = threadIdx.x >> 6, lane = threadIdx.x & 63;
  const int l = blockIdx.x * 4 + w;
  const int head = blockIdx.y;
  const size_t idx = ((size_t)head * LS + l) * HD + lane;
  float qv = q[idx], kv = k[idx], vv = v[idx];

  auto red = [](float x) {
#pragma unroll
    for (int o = 32; o; o >>= 1) x += __shfl_xor(x, o);
    return x;
  };
  const float qn = fmaxf(sqrtf(red(qv * qv)), 1e-12f);
  const float kn = fmaxf(sqrtf(red(kv * kv)), 1e-12f);
  const float vn = fmaxf(sqrtf(red(vv * vv)), 1e-12f);
  qv /= qn; kv /= kn; vv /= vn;
  q[idx] = qv; k[idx] = kv; v[idx] = vv;

  const float s = red(qv * kv) * qk_scale[head];

  __shared__ float vs[4][64];
  vs[w][lane] = vv;
  __syncthreads();
  float t = 0.f;
#pragma unroll 8
  for (int p = 0; p < 64; ++p) t = fmaf(vs[w][p], wg[p * 64 + lane], t);
  float gl = red(t * kv) * kv_scale[head] + wgb[0];
  gl = gl > 0.f ? gl : ALPHAF * gl;
  const float g = gl * gl + EPSF;
  if (lane == 0) {
    sim[head * LS + l] = s;
    gates[head * LS + l] = g;
  }
}

// ---------------------------------------------------------------------------
// K4: per-head scalar prefix scans. Unchanged (passing).
__global__ void scan_kernel(const float* __restrict__ sim, const float* __restrict__ gates,
                            float* __restrict__ m_s, float* __restrict__ Sraw,
                            float* __restrict__ g_s) {
  const int head = blockIdx.x, t = threadIdx.x;
  __shared__ float bm[1024], bs[1024], bg[1024];
  const float sv = sim[head * LS + t];
  float m = sv, S = expf(sv), g = gates[head * LS + t];
  bm[t] = m; bs[t] = S; bg[t] = g;
  __syncthreads();
  for (int off = 1; off < 1024; off <<= 1) {
    float om = -1e30f, os = 0.f, og = 0.f;
    if (t >= off) { om = bm[t - off]; os = bs[t - off]; og = bg[t - off]; }
    __syncthreads();
    m = fmaxf(m, om); S += os; g += og;
    bm[t] = m; bs[t] = S; bg[t] = g;
    __syncthreads();
  }
  m_s[head * LS + t] = m;
  Sraw[head * LS + t] = S;
  g_s[head * LS + t] = g;
}

// ---------------------------------------------------------------------------
// K5a: per-tile states. Unchanged (passing).
__global__ __launch_bounds__(256) void state_kernel(const float* __restrict__ k,
                                                    const float* __restrict__ v,
                                                    const float* __restrict__ sim,
                                                    const float* __restrict__ gates,
                                                    float* __restrict__ states,
                                                    float* __restrict__ nes) {
  const int j = blockIdx.x, head = blockIdx.y;
  const int s0 = j * SG;
  const int tid = threadIdx.x;
  __shared__ alignas(16) float Vs[SG][68];
  __shared__ alignas(16) float Kg[SG][68];
  __shared__ float Es[SG];

  const int r = tid >> 4, c = (tid & 15) * 4;
  const float* kh = k + ((size_t)head * LS + s0) * HD;
  const float* vh = v + ((size_t)head * LS + s0) * HD;
  const float g = gates[head * LS + s0 + r];
  *(float4*)&Vs[r][c] = *(const float4*)(vh + r * HD + c);
  float4 k4 = *(const float4*)(kh + r * HD + c);
  k4.x *= g; k4.y *= g; k4.z *= g; k4.w *= g;
  *(float4*)&Kg[r][c] = k4;
  if (tid < SG) Es[tid] = expf(sim[head * LS + s0 + tid]);
  __syncthreads();

  const int p0 = (tid >> 4) * 4, n0 = (tid & 15) * 4;
  float acc[4][4] = {};
  for (int s = 0; s < SG; ++s) {
    const float4 ra = *(const float4*)&Vs[s][p0];
    const float4 rb = *(const float4*)&Kg[s][n0];
    const float av[4] = {ra.x, ra.y, ra.z, ra.w};
    const float bv[4] = {rb.x, rb.y, rb.z, rb.w};
#pragma unroll
    for (int i = 0; i < 4; ++i)
#pragma unroll
      for (int jj = 0; jj < 4; ++jj)
        acc[i][jj] = fmaf(av[i], bv[jj], acc[i][jj]);
  }
  float* Sout = states + (size_t)(head * NTL + j) * 4096;
#pragma unroll
  for (int i = 0; i < 4; ++i)
    *(float4*)&Sout[(p0 + i) * 64 + n0] =
        make_float4(acc[i][0], acc[i][1], acc[i][2], acc[i][3]);

  if (tid < HD) {
    float ne = 0.f;
    for (int s = 0; s < SG; ++s) ne = fmaf(Es[s], Vs[s][tid], ne);
    nes[(size_t)(head * NTL + j) * HD + tid] = ne;
  }
}

// ---------------------------------------------------------------------------
// K5b: in-place exclusive prefix over tile-states. Unchanged (passing).
__global__ __launch_bounds__(256) void prefix_kernel(float* __restrict__ states,
                                                     float* __restrict__ nes) {
  const int head = blockIdx.x, chunk = blockIdx.y;
  const int tid = threadIdx.x;
  const int off = chunk * 1024 + tid * 4;
  float4 acc = make_float4(0.f, 0.f, 0.f, 0.f);
  float* base = states + (size_t)head * NTL * 4096 + off;
#pragma unroll 4
  for (int j = 0; j < NTL; ++j) {
    float4* p = (float4*)(base + (size_t)j * 4096);
    const float4 sv = *p;
    *p = acc;
    acc.x += sv.x; acc.y += sv.y; acc.z += sv.z; acc.w += sv.w;
  }
  if (chunk == 0 && tid < HD) {
    float a = 0.f;
    float* nb = nes + (size_t)head * NTL * HD + tid;
#pragma unroll 4
    for (int j = 0; j < NTL; ++j) {
      float* p = nb + (size_t)j * HD;
      const float t = *p;
      *p = a;
      a += t;
    }
  }
}

// ---------------------------------------------------------------------------
// K5c: apply + epilogue; writes lerp in bf16 for the MFMA out-GEMM.
// grid (NTL=64, NH), block 256.
__global__ __launch_bounds__(256) void apply_kernel(const float* __restrict__ q,
                                                    const float* __restrict__ k,
                                                    const float* __restrict__ v,
                                                    const float* __restrict__ sim,
                                                    const float* __restrict__ gates,
                                                    const float* __restrict__ m_s,
                                                    const float* __restrict__ Sraw,
                                                    const float* __restrict__ g_s,
                                                    const float* __restrict__ states,
                                                    const float* __restrict__ nes,
                                                    const float* __restrict__ kv_scale,
                                                    u16* __restrict__ lerpb) {
  const int bt = blockIdx.x, head = blockIdx.y;
  const int t0 = bt * SG;
  const int tid = threadIdx.x;
  __shared__ alignas(16) float Ps[64][68];
  __shared__ alignas(16) float Qs[SG][68];
  __shared__ alignas(16) float Vs[SG][68];
  __shared__ alignas(16) float Ks[SG][68];
  __shared__ alignas(16) float NEp[64];
  __shared__ float Ag[SG][SG + 1];
  __shared__ float Es[SG], Gs[SG];

  const float* Pg = states + (size_t)(head * NTL + bt) * 4096;
#pragma unroll
  for (int rep = 0; rep < 4; ++rep) {
    const int lin = rep * 1024 + tid * 4;
    *(float4*)&Ps[lin >> 6][lin & 63] = *(const float4*)(Pg + lin);
  }
  {
    const int r = tid >> 4, c = (tid & 15) * 4;
    const size_t rowbase = ((size_t)head * LS + t0 + r) * HD;
    *(float4*)&Qs[r][c] = *(const float4*)(q + rowbase + c);
    *(float4*)&Ks[r][c] = *(const float4*)(k + rowbase + c);
    *(float4*)&Vs[r][c] = *(const float4*)(v + rowbase + c);
  }
  if (tid < SG) {
    Es[tid] = expf(sim[head * LS + t0 + tid]);
    Gs[tid] = gates[head * LS + t0 + tid];
  }
  if (tid < HD) NEp[tid] = nes[(size_t)(head * NTL + bt) * HD + tid];
  __syncthreads();

  {
    const int t = tid >> 4, s = tid & 15;
    float a = 0.f;
    if (s <= t) {
#pragma unroll
      for (int p = 0; p < 64; p += 4) {
        const float4 q4 = *(const float4*)&Qs[t][p];
        const float4 v4 = *(const float4*)&Vs[s][p];
        a = fmaf(q4.x, v4.x, a); a = fmaf(q4.y, v4.y, a);
        a = fmaf(q4.z, v4.z, a); a = fmaf(q4.w, v4.w, a);
      }
      a *= Gs[s];
    }
    Ag[t][s] = a;
  }
  __syncthreads();

  const int r = tid >> 4, c0 = (tid & 15) * 4;
  float4 O = make_float4(0.f, 0.f, 0.f, 0.f);
#pragma unroll 8
  for (int p = 0; p < 64; ++p) {
    const float qv = Qs[r][p];
    const float4 p4 = *(const float4*)&Ps[p][c0];
    O.x = fmaf(qv, p4.x, O.x); O.y = fmaf(qv, p4.y, O.y);
    O.z = fmaf(qv, p4.z, O.z); O.w = fmaf(qv, p4.w, O.w);
  }
  float4 Nn = *(const float4*)&NEp[c0];
  for (int s = 0; s <= r; ++s) {
    const float ag = Ag[r][s];
    const float es = Es[s];
    const float4 k4 = *(const float4*)&Ks[s][c0];
    const float4 v4 = *(const float4*)&Vs[s][c0];
    O.x = fmaf(ag, k4.x, O.x); O.y = fmaf(ag, k4.y, O.y);
    O.z = fmaf(ag, k4.z, O.z); O.w = fmaf(ag, k4.w, O.w);
    Nn.x = fmaf(es, v4.x, Nn.x); Nn.y = fmaf(es, v4.y, Nn.y);
    Nn.z = fmaf(es, v4.z, Nn.z); Nn.w = fmaf(es, v4.w, Nn.w);
  }

  const int t = t0 + r;
  const float m  = m_s[head * LS + t];
  const float em = expf(-m);
  const float ss = Sraw[head * LS + t] * em;
  const float inv = 1.f / (ss + EPSF);
  const float sw  = expf(sim[head * LS + t] - m) * inv;
  const float gi  = kv_scale[head] / (g_s[head * LS + t] + EPSF);
  const float ei  = em * inv;
  float rx, ry, rz, rw;
  { const float cx = O.x * gi, la = Nn.x * ei; rx = cx + (la - cx) * sw; }
  { const float cx = O.y * gi, la = Nn.y * ei; ry = cx + (la - cx) * sw; }
  { const float cx = O.z * gi, la = Nn.z * ei; rz = cx + (la - cx) * sw; }
  { const float cx = O.w * gi, la = Nn.w * ei; rw = cx + (la - cx) * sw; }
  ushort4 ob;
  ob.x = f2b(rx); ob.y = f2b(ry); ob.z = f2b(rz); ob.w = f2b(rw);
  *(ushort4*)&lerpb[(size_t)t * DM + head * HD + c0] = ob;
}

// ---------------------------------------------------------------------------
extern "C" void kernel_launch(void* const* d_in, const int* in_sizes, int n_in,
                              void* d_out, int out_size, void* d_ws, size_t ws_size,
                              hipStream_t stream) {
  (void)in_sizes; (void)n_in; (void)out_size; (void)ws_size;
  const float* x        = (const float*)d_in[0];
  const float* filters  = (const float*)d_in[1];
  const float* wq_w     = (const float*)d_in[2];
  const float* wq_b     = (const float*)d_in[3];
  const float* wk_w     = (const float*)d_in[4];
  const float* wk_b     = (const float*)d_in[5];
  const float* wv_w     = (const float*)d_in[6];
  const float* wv_b     = (const float*)d_in[7];
  const float* wo_w     = (const float*)d_in[8];
  const float* wo_b     = (const float*)d_in[9];
  const float* wg_w     = (const float*)d_in[10];
  const float* wg_b     = (const float*)d_in[11];
  const float* qk_scale = (const float*)d_in[12];
  const float* kv_scale = (const float*)d_in[13];

  float* ws = (float*)d_ws;
  const size_t NT = (size_t)LS * DM;  // 786432
  float* xt_a  = ws;                  // conv partial parity 0; later reused as lerpb
  float* xt_b  = ws + NT;             // parity 1
  float* q     = ws + 2 * NT;         // parity 2 partial until pack; then q
  float* k     = ws + 3 * NT;         // parity 3 partial until pack; then k
  float* v     = ws + 4 * NT;
  float* sim   = ws + 5 * NT;
  float* gates = sim + NH * LS;
  float* m_s   = gates + NH * LS;
  float* Sraw  = m_s + NH * LS;
  float* g_s   = Sraw + NH * LS;
  float* states = g_s + NH * LS;                       // 12*64*4096
  float* nes    = states + (size_t)NH * NTL * 4096;    // 12*64*64
  u16*   xtb    = (u16*)(nes + (size_t)NH * NTL * HD); // NT bf16
  u16*   wT     = xtb + NT;                            // 4 * 589824 bf16
  u16*   lerpb  = (u16*)xt_a;                          // alias: xt dead after pack

  txw_kernel<<<dim3(DM / 64, DM / 64, 4), 256, 0, stream>>>(wq_w, wk_w, wv_w, wo_w, wT);
  conv_kernel<<<dim3(LS / 64, NH, 4), 256, 0, stream>>>(x, filters, xt_a, xt_b, q, k);
  pack_xt<<<dim3(NT / 2048), 256, 0, stream>>>(xt_a, xt_b, q, k, xtb);
  qkv_mfma<<<dim3(NH, LS / 64, 3), 256, 0, stream>>>(
      xtb, wT, wq_b, wk_b, wv_b, q, k, v);
  norm_sim_gate<<<dim3(LS / 4, NH), 256, 0, stream>>>(
      q, k, v, wg_w, wg_b, qk_scale, kv_scale, sim, gates);
  scan_kernel<<<dim3(NH), 1024, 0, stream>>>(sim, gates, m_s, Sraw, g_s);
  state_kernel<<<dim3(NTL, NH), 256, 0, stream>>>(k, v, sim, gates, states, nes);
  prefix_kernel<<<dim3(NH, 4), 256, 0, stream>>>(states, nes);
  apply_kernel<<<dim3(NTL, NH), 256, 0, stream>>>(
      q, k, v, sim, gates, m_s, Sraw, g_s, states, nes, kv_scale, lerpb);
  out_mfma<<<dim3(DM / 64, LS / 64), 256, 0, stream>>>(
      lerpb, wT + 3 * (size_t)WSZ, wo_b, (float*)d_out);
}

// Round 7
// 145.151 us; speedup vs baseline: 3.2343x; 1.0181x over previous
//
#include <hip/hip_runtime.h>
#include <hip/hip_bf16.h>

constexpr int LS = 1024;   // sequence length
constexpr int DM = 768;    // model dim
constexpr int NH = 12;     // heads
constexpr int HD = 64;     // head dim
constexpr float EPSF = 1e-5f;
constexpr float ALPHAF = 0.01f;

constexpr int SG = 16;             // state granularity (rows per tile)
constexpr int NTL = LS / SG;       // 64 tiles per head
constexpr int WSZ = DM * DM;       // 589824 elements per weight matrix

typedef unsigned short u16;
typedef __attribute__((ext_vector_type(8))) short bf16x8;
typedef __attribute__((ext_vector_type(8))) unsigned short u16x8;
typedef __attribute__((ext_vector_type(4))) float f32x4;

__device__ __forceinline__ u16 f2b(float f) {
  unsigned u = __float_as_uint(f);
  u += 0x7FFFu + ((u >> 16) & 1u);   // round-to-nearest-even
  return (u16)(u >> 16);
}

// ---------------------------------------------------------------------------
// K0: transpose + bf16-convert the 4 weight matrices: wT[z][n][k] = bf16(w[k][n])
// grid (12, 12, 4), block 256
__global__ __launch_bounds__(256) void txw_kernel(const float* __restrict__ wq,
                                                  const float* __restrict__ wk,
                                                  const float* __restrict__ wv,
                                                  const float* __restrict__ wo,
                                                  u16* __restrict__ wT) {
  const int z = blockIdx.z;
  const float* src = (z == 0) ? wq : (z == 1) ? wk : (z == 2) ? wv : wo;
  u16* dst = wT + (size_t)z * WSZ;
  const int kb = blockIdx.x * 64, nb = blockIdx.y * 64;
  const int t = threadIdx.x;
  __shared__ float T[64][65];
#pragma unroll
  for (int rep = 0; rep < 4; ++rep) {
    const int r = rep * 16 + (t >> 4);
    const int c4 = (t & 15) * 4;
    const float4 v4 = *(const float4*)(src + (size_t)(kb + r) * DM + nb + c4);
    T[r][c4] = v4.x; T[r][c4 + 1] = v4.y; T[r][c4 + 2] = v4.z; T[r][c4 + 3] = v4.w;
  }
  __syncthreads();
#pragma unroll
  for (int rep = 0; rep < 4; ++rep) {
    const int n = rep * 16 + (t >> 4);
    const int k4 = (t & 15) * 4;
    ushort4 o;
    o.x = f2b(T[k4 + 0][n]); o.y = f2b(T[k4 + 1][n]);
    o.z = f2b(T[k4 + 2][n]); o.w = f2b(T[k4 + 3][n]);
    *(ushort4*)(dst + (size_t)(nb + n) * DM + kb + k4) = o;
  }
}

// ---------------------------------------------------------------------------
// K1: causal conv, banded stencil, parity-4 partial split, filters read
// directly from global (L2-hot). LDS = X tile only. Unchanged (passing).
__global__ __launch_bounds__(256) void conv_kernel(const float* __restrict__ x,
                                                   const float* __restrict__ f,
                                                   float* __restrict__ p0,
                                                   float* __restrict__ p1,
                                                   float* __restrict__ p2,
                                                   float* __restrict__ p3) {
  const int i    = blockIdx.x;
  const int head = blockIdx.y;
  const int par  = blockIdx.z;
  const int tid  = threadIdx.x;
  const int c    = tid & 63;
  const int sg   = tid >> 6;
  const int tbase = i * 64;
  const int l0w   = tbase + sg * 16;
  float* __restrict__ xt_p = (par == 0) ? p0 : (par == 1) ? p1 : (par == 2) ? p2 : p3;

  __shared__ float4 Xs2[28][64];

  {
    const float4 z4 = make_float4(0.f, 0.f, 0.f, 0.f);
#pragma unroll
    for (int k = 0; k < 3; ++k) {
      const int lin = k * 256 + tid;
      const int g   = lin >> 6;
      const int cc  = lin & 63;
      const int grp = (g < 4) ? g : (16 + g);
      Xs2[grp][cc] = z4;
    }
  }

  float acc[16];
#pragma unroll
  for (int t = 0; t < 16; ++t) acc[t] = 0.f;

  const float* xg   = x + head * HD + c;
  const float* fcol = f + c;

  for (int j = par; j <= i; j += 4) {
    const int sbase = j * 64;
    const int b0 = (j < i) ? (tbase - sbase - 64) : 0;
#pragma unroll
    for (int k = 0; k < 4; ++k) {
      const int m  = sg + 4 * k;
      const int ss = 4 * m;
      float4 v4;
      v4.x = xg[(sbase + ss + 0) * DM];
      v4.y = xg[(sbase + ss + 1) * DM];
      v4.z = xg[(sbase + ss + 2) * DM];
      v4.w = xg[(sbase + ss + 3) * DM];
      Xs2[4 + m][c] = v4;
    }
    __syncthreads();

    const int dstart = (j < i) ? (b0 + sg * 16) : 0;
    const int nsteps = (j < i) ? 5 : (sg + 1);
    for (int k = 0; k < nsteps; ++k) {
      const int d0    = dstart + 16 * k;
      const int rbase = l0w - d0 - sbase;
      float fr[16];
#pragma unroll
      for (int m = 0; m < 16; ++m) fr[m] = fcol[(d0 + m) * HD];
      float xw[32];
      const int xgb = rbase >> 2;
#pragma unroll
      for (int m = 0; m < 8; ++m) {
        const float4 v4 = Xs2[xgb + m][c];
        xw[4 * m + 0] = v4.x; xw[4 * m + 1] = v4.y;
        xw[4 * m + 2] = v4.z; xw[4 * m + 3] = v4.w;
      }
#pragma unroll
      for (int li = 0; li < 16; ++li)
#pragma unroll
        for (int dd = 0; dd < 16; ++dd)
          acc[li] = fmaf(fr[dd], xw[li - dd + 16], acc[li]);
    }
    __syncthreads();
  }

#pragma unroll
  for (int li = 0; li < 16; ++li)
    xt_p[(size_t)(l0w + li) * DM + head * HD + c] = acc[li];
}

// ---------------------------------------------------------------------------
// K1b: xtb[l][k] = bf16(p0+p1+p2+p3). grid 384, block 256 (8 elems/thread).
__global__ __launch_bounds__(256) void pack_xt(const float* __restrict__ a,
                                               const float* __restrict__ b,
                                               const float* __restrict__ cc,
                                               const float* __restrict__ d,
                                               u16* __restrict__ xtb) {
  const size_t i = ((size_t)blockIdx.x * 256 + threadIdx.x) * 8;
  u16x8 o;
#pragma unroll
  for (int h = 0; h < 2; ++h) {
    const float4 a4 = *(const float4*)(a + i + h * 4);
    const float4 b4 = *(const float4*)(b + i + h * 4);
    const float4 c4 = *(const float4*)(cc + i + h * 4);
    const float4 d4 = *(const float4*)(d + i + h * 4);
    o[h * 4 + 0] = f2b(a4.x + b4.x + c4.x + d4.x);
    o[h * 4 + 1] = f2b(a4.y + b4.y + c4.y + d4.y);
    o[h * 4 + 2] = f2b(a4.z + b4.z + c4.z + d4.z);
    o[h * 4 + 3] = f2b(a4.w + b4.w + c4.w + d4.w);
  }
  *(u16x8*)(xtb + i) = o;
}

// ---------------------------------------------------------------------------
// K2: q/k/v = xtb @ W + b via bf16 MFMA, direct-global fragments with a
// PF-deep software-pipelined register ring (fully unrolled -> static idx).
// grid (12 heads, 16 row-tiles, 3), block 256.
constexpr int KS = DM / 32;   // 24 K-steps
constexpr int PF = 6;         // prefetch depth (ring slots)

__global__ __launch_bounds__(256) void qkv_mfma(const u16* __restrict__ xtb,
                                                const u16* __restrict__ wT,
                                                const float* __restrict__ bq,
                                                const float* __restrict__ bk,
                                                const float* __restrict__ bv,
                                                float* __restrict__ qo,
                                                float* __restrict__ ko,
                                                float* __restrict__ vo) {
  const int ct = blockIdx.x, rt = blockIdx.y, z = blockIdx.z;
  const u16* wt = wT + (size_t)z * WSZ;
  const float* bias = (z == 0) ? bq : (z == 1) ? bk : bv;
  float* out = (z == 0) ? qo : (z == 1) ? ko : vo;
  const int tid = threadIdx.x, wv_ = tid >> 6, l = tid & 63;
  const int row = rt * 64 + wv_ * 16 + (l & 15);
  const int kb = (l >> 4) * 8;
  const u16* arow = xtb + (size_t)row * DM + kb;
  const u16* brow = wt + (size_t)(ct * 64 + (l & 15)) * DM + kb;

  bf16x8 af[PF];
  bf16x8 bfr[PF][4];
#pragma unroll
  for (int d = 0; d < PF; ++d) {
    af[d] = *(const bf16x8*)(arow + d * 32);
#pragma unroll
    for (int nt = 0; nt < 4; ++nt)
      bfr[d][nt] = *(const bf16x8*)(brow + (size_t)nt * 16 * DM + d * 32);
  }

  f32x4 acc[4] = {};
#pragma unroll
  for (int s = 0; s < KS; ++s) {
    const int cur = s % PF;
    const bf16x8 a = af[cur];
    const bf16x8 b0 = bfr[cur][0], b1 = bfr[cur][1];
    const bf16x8 b2 = bfr[cur][2], b3 = bfr[cur][3];
    if (s + PF < KS) {
      const int k0 = (s + PF) * 32;
      af[cur] = *(const bf16x8*)(arow + k0);
#pragma unroll
      for (int nt = 0; nt < 4; ++nt)
        bfr[cur][nt] = *(const bf16x8*)(brow + (size_t)nt * 16 * DM + k0);
    }
    acc[0] = __builtin_amdgcn_mfma_f32_16x16x32_bf16(a, b0, acc[0], 0, 0, 0);
    acc[1] = __builtin_amdgcn_mfma_f32_16x16x32_bf16(a, b1, acc[1], 0, 0, 0);
    acc[2] = __builtin_amdgcn_mfma_f32_16x16x32_bf16(a, b2, acc[2], 0, 0, 0);
    acc[3] = __builtin_amdgcn_mfma_f32_16x16x32_bf16(a, b3, acc[3], 0, 0, 0);
  }

  const int r0 = rt * 64 + wv_ * 16 + ((l >> 4) << 2);
  const int c  = l & 15;
#pragma unroll
  for (int nt = 0; nt < 4; ++nt) {
    const int col = nt * 16 + c;
    const float bb = bias[ct * 64 + col];
#pragma unroll
    for (int r = 0; r < 4; ++r)
      out[((size_t)ct * LS + r0 + r) * HD + col] = acc[nt][r] + bb;
  }
}

// ---------------------------------------------------------------------------
// K6: y = lerpb @ wo + b via bf16 MFMA, same pipelined structure.
// grid (12, 16), block 256
__global__ __launch_bounds__(256) void out_mfma(const u16* __restrict__ lerpb,
                                                const u16* __restrict__ woT,
                                                const float* __restrict__ bias,
                                                float* __restrict__ out) {
  const int ct = blockIdx.x, rt = blockIdx.y;
  const int tid = threadIdx.x, wv_ = tid >> 6, l = tid & 63;
  const int row = rt * 64 + wv_ * 16 + (l & 15);
  const int kb = (l >> 4) * 8;
  const u16* arow = lerpb + (size_t)row * DM + kb;
  const u16* brow = woT + (size_t)(ct * 64 + (l & 15)) * DM + kb;

  bf16x8 af[PF];
  bf16x8 bfr[PF][4];
#pragma unroll
  for (int d = 0; d < PF; ++d) {
    af[d] = *(const bf16x8*)(arow + d * 32);
#pragma unroll
    for (int nt = 0; nt < 4; ++nt)
      bfr[d][nt] = *(const bf16x8*)(brow + (size_t)nt * 16 * DM + d * 32);
  }

  f32x4 acc[4] = {};
#pragma unroll
  for (int s = 0; s < KS; ++s) {
    const int cur = s % PF;
    const bf16x8 a = af[cur];
    const bf16x8 b0 = bfr[cur][0], b1 = bfr[cur][1];
    const bf16x8 b2 = bfr[cur][2], b3 = bfr[cur][3];
    if (s + PF < KS) {
      const int k0 = (s + PF) * 32;
      af[cur] = *(const bf16x8*)(arow + k0);
#pragma unroll
      for (int nt = 0; nt < 4; ++nt)
        bfr[cur][nt] = *(const bf16x8*)(brow + (size_t)nt * 16 * DM + k0);
    }
    acc[0] = __builtin_amdgcn_mfma_f32_16x16x32_bf16(a, b0, acc[0], 0, 0, 0);
    acc[1] = __builtin_amdgcn_mfma_f32_16x16x32_bf16(a, b1, acc[1], 0, 0, 0);
    acc[2] = __builtin_amdgcn_mfma_f32_16x16x32_bf16(a, b2, acc[2], 0, 0, 0);
    acc[3] = __builtin_amdgcn_mfma_f32_16x16x32_bf16(a, b3, acc[3], 0, 0, 0);
  }

  const int r0 = rt * 64 + wv_ * 16 + ((l >> 4) << 2);
  const int c  = l & 15;
#pragma unroll
  for (int nt = 0; nt < 4; ++nt) {
    const int col = ct * 64 + nt * 16 + c;
    const float bb = bias[col];
#pragma unroll
    for (int r = 0; r < 4; ++r)
      out[(size_t)(r0 + r) * DM + col] = acc[nt][r] + bb;
  }
}

// ---------------------------------------------------------------------------
// K3: l2norm + sim + gates. Unchanged (passing).
__global__ void norm_sim_gate(float* __restrict__ q, float* __restrict__ k, float* __restrict__ v,
                              const float* __restrict__ wg, const float* __restrict__ wgb,
                              const float* __restrict__ qk_scale, const float* __restrict__ kv_scale,
                              float* __restrict__ sim, float* __restrict__ gates) {
  const int w = threadIdx.x >> 6, lane = threadIdx.x & 63;
  const int l = blockIdx.x * 4 + w;
  const int head = blockIdx.y;
  const size_t idx = ((size_t)head * LS + l) * HD + lane;
  float qv = q[idx], kv = k[idx], vv = v[idx];

  auto red = [](float x) {
#pragma unroll
    for (int o = 32; o; o >>= 1) x += __shfl_xor(x, o);
    return x;
  };
  const float qn = fmaxf(sqrtf(red(qv * qv)), 1e-12f);
  const float kn = fmaxf(sqrtf(red(kv * kv)), 1e-12f);
  const float vn = fmaxf(sqrtf(red(vv * vv)), 1e-12f);
  qv /= qn; kv /= kn; vv /= vn;
  q[idx] = qv; k[idx] = kv; v[idx] = vv;

  const float s = red(qv * kv) * qk_scale[head];

  __shared__ float vs[4][64];
  vs[w][lane] = vv;
  __syncthreads();
  float t = 0.f;
#pragma unroll 8
  for (int p = 0; p < 64; ++p) t = fmaf(vs[w][p], wg[p * 64 + lane], t);
  float gl = red(t * kv) * kv_scale[head] + wgb[0];
  gl = gl > 0.f ? gl : ALPHAF * gl;
  const float g = gl * gl + EPSF;
  if (lane == 0) {
    sim[head * LS + l] = s;
    gates[head * LS + l] = g;
  }
}

// ---------------------------------------------------------------------------
// K4: per-head scalar prefix scans. Unchanged (passing).
__global__ void scan_kernel(const float* __restrict__ sim, const float* __restrict__ gates,
                            float* __restrict__ m_s, float* __restrict__ Sraw,
                            float* __restrict__ g_s) {
  const int head = blockIdx.x, t = threadIdx.x;
  __shared__ float bm[1024], bs[1024], bg[1024];
  const float sv = sim[head * LS + t];
  float m = sv, S = expf(sv), g = gates[head * LS + t];
  bm[t] = m; bs[t] = S; bg[t] = g;
  __syncthreads();
  for (int off = 1; off < 1024; off <<= 1) {
    float om = -1e30f, os = 0.f, og = 0.f;
    if (t >= off) { om = bm[t - off]; os = bs[t - off]; og = bg[t - off]; }
    __syncthreads();
    m = fmaxf(m, om); S += os; g += og;
    bm[t] = m; bs[t] = S; bg[t] = g;
    __syncthreads();
  }
  m_s[head * LS + t] = m;
  Sraw[head * LS + t] = S;
  g_s[head * LS + t] = g;
}

// ---------------------------------------------------------------------------
// K5a: per-tile states. Unchanged (passing).
__global__ __launch_bounds__(256) void state_kernel(const float* __restrict__ k,
                                                    const float* __restrict__ v,
                                                    const float* __restrict__ sim,
                                                    const float* __restrict__ gates,
                                                    float* __restrict__ states,
                                                    float* __restrict__ nes) {
  const int j = blockIdx.x, head = blockIdx.y;
  const int s0 = j * SG;
  const int tid = threadIdx.x;
  __shared__ alignas(16) float Vs[SG][68];
  __shared__ alignas(16) float Kg[SG][68];
  __shared__ float Es[SG];

  const int r = tid >> 4, c = (tid & 15) * 4;
  const float* kh = k + ((size_t)head * LS + s0) * HD;
  const float* vh = v + ((size_t)head * LS + s0) * HD;
  const float g = gates[head * LS + s0 + r];
  *(float4*)&Vs[r][c] = *(const float4*)(vh + r * HD + c);
  float4 k4 = *(const float4*)(kh + r * HD + c);
  k4.x *= g; k4.y *= g; k4.z *= g; k4.w *= g;
  *(float4*)&Kg[r][c] = k4;
  if (tid < SG) Es[tid] = expf(sim[head * LS + s0 + tid]);
  __syncthreads();

  const int p0 = (tid >> 4) * 4, n0 = (tid & 15) * 4;
  float acc[4][4] = {};
  for (int s = 0; s < SG; ++s) {
    const float4 ra = *(const float4*)&Vs[s][p0];
    const float4 rb = *(const float4*)&Kg[s][n0];
    const float av[4] = {ra.x, ra.y, ra.z, ra.w};
    const float bv[4] = {rb.x, rb.y, rb.z, rb.w};
#pragma unroll
    for (int i = 0; i < 4; ++i)
#pragma unroll
      for (int jj = 0; jj < 4; ++jj)
        acc[i][jj] = fmaf(av[i], bv[jj], acc[i][jj]);
  }
  float* Sout = states + (size_t)(head * NTL + j) * 4096;
#pragma unroll
  for (int i = 0; i < 4; ++i)
    *(float4*)&Sout[(p0 + i) * 64 + n0] =
        make_float4(acc[i][0], acc[i][1], acc[i][2], acc[i][3]);

  if (tid < HD) {
    float ne = 0.f;
    for (int s = 0; s < SG; ++s) ne = fmaf(Es[s], Vs[s][tid], ne);
    nes[(size_t)(head * NTL + j) * HD + tid] = ne;
  }
}

// ---------------------------------------------------------------------------
// K5b: in-place exclusive prefix over tile-states. Unchanged (passing).
__global__ __launch_bounds__(256) void prefix_kernel(float* __restrict__ states,
                                                     float* __restrict__ nes) {
  const int head = blockIdx.x, chunk = blockIdx.y;
  const int tid = threadIdx.x;
  const int off = chunk * 1024 + tid * 4;
  float4 acc = make_float4(0.f, 0.f, 0.f, 0.f);
  float* base = states + (size_t)head * NTL * 4096 + off;
#pragma unroll 4
  for (int j = 0; j < NTL; ++j) {
    float4* p = (float4*)(base + (size_t)j * 4096);
    const float4 sv = *p;
    *p = acc;
    acc.x += sv.x; acc.y += sv.y; acc.z += sv.z; acc.w += sv.w;
  }
  if (chunk == 0 && tid < HD) {
    float a = 0.f;
    float* nb = nes + (size_t)head * NTL * HD + tid;
#pragma unroll 4
    for (int j = 0; j < NTL; ++j) {
      float* p = nb + (size_t)j * HD;
      const float t = *p;
      *p = a;
      a += t;
    }
  }
}

// ---------------------------------------------------------------------------
// K5c: apply + epilogue; writes lerp in bf16 for the MFMA out-GEMM.
// grid (NTL=64, NH), block 256.
__global__ __launch_bounds__(256) void apply_kernel(const float* __restrict__ q,
                                                    const float* __restrict__ k,
                                                    const float* __restrict__ v,
                                                    const float* __restrict__ sim,
                                                    const float* __restrict__ gates,
                                                    const float* __restrict__ m_s,
                                                    const float* __restrict__ Sraw,
                                                    const float* __restrict__ g_s,
                                                    const float* __restrict__ states,
                                                    const float* __restrict__ nes,
                                                    const float* __restrict__ kv_scale,
                                                    u16* __restrict__ lerpb) {
  const int bt = blockIdx.x, head = blockIdx.y;
  const int t0 = bt * SG;
  const int tid = threadIdx.x;
  __shared__ alignas(16) float Ps[64][68];
  __shared__ alignas(16) float Qs[SG][68];
  __shared__ alignas(16) float Vs[SG][68];
  __shared__ alignas(16) float Ks[SG][68];
  __shared__ alignas(16) float NEp[64];
  __shared__ float Ag[SG][SG + 1];
  __shared__ float Es[SG], Gs[SG];

  const float* Pg = states + (size_t)(head * NTL + bt) * 4096;
#pragma unroll
  for (int rep = 0; rep < 4; ++rep) {
    const int lin = rep * 1024 + tid * 4;
    *(float4*)&Ps[lin >> 6][lin & 63] = *(const float4*)(Pg + lin);
  }
  {
    const int r = tid >> 4, c = (tid & 15) * 4;
    const size_t rowbase = ((size_t)head * LS + t0 + r) * HD;
    *(float4*)&Qs[r][c] = *(const float4*)(q + rowbase + c);
    *(float4*)&Ks[r][c] = *(const float4*)(k + rowbase + c);
    *(float4*)&Vs[r][c] = *(const float4*)(v + rowbase + c);
  }
  if (tid < SG) {
    Es[tid] = expf(sim[head * LS + t0 + tid]);
    Gs[tid] = gates[head * LS + t0 + tid];
  }
  if (tid < HD) NEp[tid] = nes[(size_t)(head * NTL + bt) * HD + tid];
  __syncthreads();

  {
    const int t = tid >> 4, s = tid & 15;
    float a = 0.f;
    if (s <= t) {
#pragma unroll
      for (int p = 0; p < 64; p += 4) {
        const float4 q4 = *(const float4*)&Qs[t][p];
        const float4 v4 = *(const float4*)&Vs[s][p];
        a = fmaf(q4.x, v4.x, a); a = fmaf(q4.y, v4.y, a);
        a = fmaf(q4.z, v4.z, a); a = fmaf(q4.w, v4.w, a);
      }
      a *= Gs[s];
    }
    Ag[t][s] = a;
  }
  __syncthreads();

  const int r = tid >> 4, c0 = (tid & 15) * 4;
  float4 O = make_float4(0.f, 0.f, 0.f, 0.f);
#pragma unroll 8
  for (int p = 0; p < 64; ++p) {
    const float qv = Qs[r][p];
    const float4 p4 = *(const float4*)&Ps[p][c0];
    O.x = fmaf(qv, p4.x, O.x); O.y = fmaf(qv, p4.y, O.y);
    O.z = fmaf(qv, p4.z, O.z); O.w = fmaf(qv, p4.w, O.w);
  }
  float4 Nn = *(const float4*)&NEp[c0];
  for (int s = 0; s <= r; ++s) {
    const float ag = Ag[r][s];
    const float es = Es[s];
    const float4 k4 = *(const float4*)&Ks[s][c0];
    const float4 v4 = *(const float4*)&Vs[s][c0];
    O.x = fmaf(ag, k4.x, O.x); O.y = fmaf(ag, k4.y, O.y);
    O.z = fmaf(ag, k4.z, O.z); O.w = fmaf(ag, k4.w, O.w);
    Nn.x = fmaf(es, v4.x, Nn.x); Nn.y = fmaf(es, v4.y, Nn.y);
    Nn.z = fmaf(es, v4.z, Nn.z); Nn.w = fmaf(es, v4.w, Nn.w);
  }

  const int t = t0 + r;
  const float m  = m_s[head * LS + t];
  const float em = expf(-m);
  const float ss = Sraw[head * LS + t] * em;
  const float inv = 1.f / (ss + EPSF);
  const float sw  = expf(sim[head * LS + t] - m) * inv;
  const float gi  = kv_scale[head] / (g_s[head * LS + t] + EPSF);
  const float ei  = em * inv;
  float rx, ry, rz, rw;
  { const float cx = O.x * gi, la = Nn.x * ei; rx = cx + (la - cx) * sw; }
  { const float cx = O.y * gi, la = Nn.y * ei; ry = cx + (la - cx) * sw; }
  { const float cx = O.z * gi, la = Nn.z * ei; rz = cx + (la - cx) * sw; }
  { const float cx = O.w * gi, la = Nn.w * ei; rw = cx + (la - cx) * sw; }
  ushort4 ob;
  ob.x = f2b(rx); ob.y = f2b(ry); ob.z = f2b(rz); ob.w = f2b(rw);
  *(ushort4*)&lerpb[(size_t)t * DM + head * HD + c0] = ob;
}

// ---------------------------------------------------------------------------
extern "C" void kernel_launch(void* const* d_in, const int* in_sizes, int n_in,
                              void* d_out, int out_size, void* d_ws, size_t ws_size,
                              hipStream_t stream) {
  (void)in_sizes; (void)n_in; (void)out_size; (void)ws_size;
  const float* x        = (const float*)d_in[0];
  const float* filters  = (const float*)d_in[1];
  const float* wq_w     = (const float*)d_in[2];
  const float* wq_b     = (const float*)d_in[3];
  const float* wk_w     = (const float*)d_in[4];
  const float* wk_b     = (const float*)d_in[5];
  const float* wv_w     = (const float*)d_in[6];
  const float* wv_b     = (const float*)d_in[7];
  const float* wo_w     = (const float*)d_in[8];
  const float* wo_b     = (const float*)d_in[9];
  const float* wg_w     = (const float*)d_in[10];
  const float* wg_b     = (const float*)d_in[11];
  const float* qk_scale = (const float*)d_in[12];
  const float* kv_scale = (const float*)d_in[13];

  float* ws = (float*)d_ws;
  const size_t NT = (size_t)LS * DM;  // 786432
  float* xt_a  = ws;                  // conv partial parity 0; later reused as lerpb
  float* xt_b  = ws + NT;             // parity 1
  float* q     = ws + 2 * NT;         // parity 2 partial until pack; then q
  float* k     = ws + 3 * NT;         // parity 3 partial until pack; then k
  float* v     = ws + 4 * NT;
  float* sim   = ws + 5 * NT;
  float* gates = sim + NH * LS;
  float* m_s   = gates + NH * LS;
  float* Sraw  = m_s + NH * LS;
  float* g_s   = Sraw + NH * LS;
  float* states = g_s + NH * LS;                       // 12*64*4096
  float* nes    = states + (size_t)NH * NTL * 4096;    // 12*64*64
  u16*   xtb    = (u16*)(nes + (size_t)NH * NTL * HD); // NT bf16
  u16*   wT     = xtb + NT;                            // 4 * 589824 bf16
  u16*   lerpb  = (u16*)xt_a;                          // alias: xt dead after pack

  txw_kernel<<<dim3(DM / 64, DM / 64, 4), 256, 0, stream>>>(wq_w, wk_w, wv_w, wo_w, wT);
  conv_kernel<<<dim3(LS / 64, NH, 4), 256, 0, stream>>>(x, filters, xt_a, xt_b, q, k);
  pack_xt<<<dim3(NT / 2048), 256, 0, stream>>>(xt_a, xt_b, q, k, xtb);
  qkv_mfma<<<dim3(NH, LS / 64, 3), 256, 0, stream>>>(
      xtb, wT, wq_b, wk_b, wv_b, q, k, v);
  norm_sim_gate<<<dim3(LS / 4, NH), 256, 0, stream>>>(
      q, k, v, wg_w, wg_b, qk_scale, kv_scale, sim, gates);
  scan_kernel<<<dim3(NH), 1024, 0, stream>>>(sim, gates, m_s, Sraw, g_s);
  state_kernel<<<dim3(NTL, NH), 256, 0, stream>>>(k, v, sim, gates, states, nes);
  prefix_kernel<<<dim3(NH, 4), 256, 0, stream>>>(states, nes);
  apply_kernel<<<dim3(NTL, NH), 256, 0, stream>>>(
      q, k, v, sim, gates, m_s, Sraw, g_s, states, nes, kv_scale, lerpb);
  out_mfma<<<dim3(DM / 64, LS / 64), 256, 0, stream>>>(
      lerpb, wT + 3 * (size_t)WSZ, wo_b, (float*)d_out);
}

// Round 8
// 108.466 us; speedup vs baseline: 4.3282x; 1.3382x over previous
//
#include <hip/hip_runtime.h>
#include <hip/hip_bf16.h>

constexpr int LS = 1024;   // sequence length
constexpr int DM = 768;    // model dim
constexpr int NH = 12;     // heads
constexpr int HD = 64;     // head dim
constexpr float EPSF = 1e-5f;
constexpr float ALPHAF = 0.01f;

constexpr int SG = 16;             // state granularity (rows per tile)
constexpr int NTL = LS / SG;       // 64 tiles per head
constexpr int WSZ = DM * DM;       // 589824 elements per weight matrix

typedef unsigned short u16;
typedef __attribute__((ext_vector_type(8))) short bf16x8;
typedef __attribute__((ext_vector_type(8))) unsigned short u16x8;
typedef __attribute__((ext_vector_type(4))) float f32x4;

__device__ __forceinline__ u16 f2b(float f) {
  unsigned u = __float_as_uint(f);
  u += 0x7FFFu + ((u >> 16) & 1u);   // round-to-nearest-even
  return (u16)(u >> 16);
}

// async global->LDS, 16B per lane; LDS dest is wave-uniform base + lane*16
__device__ __forceinline__ void gld16(const u16* g, void* l) {
  __builtin_amdgcn_global_load_lds(
      (const __attribute__((address_space(1))) void*)g,
      (__attribute__((address_space(3))) void*)l, 16, 0, 0);
}

// ---------------------------------------------------------------------------
// K0: transpose + bf16-convert the 4 weight matrices: wT[z][n][k] = bf16(w[k][n])
// grid (12, 12, 4), block 256
__global__ __launch_bounds__(256) void txw_kernel(const float* __restrict__ wq,
                                                  const float* __restrict__ wk,
                                                  const float* __restrict__ wv,
                                                  const float* __restrict__ wo,
                                                  u16* __restrict__ wT) {
  const int z = blockIdx.z;
  const float* src = (z == 0) ? wq : (z == 1) ? wk : (z == 2) ? wv : wo;
  u16* dst = wT + (size_t)z * WSZ;
  const int kb = blockIdx.x * 64, nb = blockIdx.y * 64;
  const int t = threadIdx.x;
  __shared__ float T[64][65];
#pragma unroll
  for (int rep = 0; rep < 4; ++rep) {
    const int r = rep * 16 + (t >> 4);
    const int c4 = (t & 15) * 4;
    const float4 v4 = *(const float4*)(src + (size_t)(kb + r) * DM + nb + c4);
    T[r][c4] = v4.x; T[r][c4 + 1] = v4.y; T[r][c4 + 2] = v4.z; T[r][c4 + 3] = v4.w;
  }
  __syncthreads();
#pragma unroll
  for (int rep = 0; rep < 4; ++rep) {
    const int n = rep * 16 + (t >> 4);
    const int k4 = (t & 15) * 4;
    ushort4 o;
    o.x = f2b(T[k4 + 0][n]); o.y = f2b(T[k4 + 1][n]);
    o.z = f2b(T[k4 + 2][n]); o.w = f2b(T[k4 + 3][n]);
    *(ushort4*)(dst + (size_t)(nb + n) * DM + kb + k4) = o;
  }
}

// ---------------------------------------------------------------------------
// K1: causal conv, banded stencil, parity-4 partial split. Unchanged (passing).
__global__ __launch_bounds__(256) void conv_kernel(const float* __restrict__ x,
                                                   const float* __restrict__ f,
                                                   float* __restrict__ p0,
                                                   float* __restrict__ p1,
                                                   float* __restrict__ p2,
                                                   float* __restrict__ p3) {
  const int i    = blockIdx.x;
  const int head = blockIdx.y;
  const int par  = blockIdx.z;
  const int tid  = threadIdx.x;
  const int c    = tid & 63;
  const int sg   = tid >> 6;
  const int tbase = i * 64;
  const int l0w   = tbase + sg * 16;
  float* __restrict__ xt_p = (par == 0) ? p0 : (par == 1) ? p1 : (par == 2) ? p2 : p3;

  __shared__ float4 Xs2[28][64];

  {
    const float4 z4 = make_float4(0.f, 0.f, 0.f, 0.f);
#pragma unroll
    for (int k = 0; k < 3; ++k) {
      const int lin = k * 256 + tid;
      const int g   = lin >> 6;
      const int cc  = lin & 63;
      const int grp = (g < 4) ? g : (16 + g);
      Xs2[grp][cc] = z4;
    }
  }

  float acc[16];
#pragma unroll
  for (int t = 0; t < 16; ++t) acc[t] = 0.f;

  const float* xg   = x + head * HD + c;
  const float* fcol = f + c;

  for (int j = par; j <= i; j += 4) {
    const int sbase = j * 64;
    const int b0 = (j < i) ? (tbase - sbase - 64) : 0;
#pragma unroll
    for (int k = 0; k < 4; ++k) {
      const int m  = sg + 4 * k;
      const int ss = 4 * m;
      float4 v4;
      v4.x = xg[(sbase + ss + 0) * DM];
      v4.y = xg[(sbase + ss + 1) * DM];
      v4.z = xg[(sbase + ss + 2) * DM];
      v4.w = xg[(sbase + ss + 3) * DM];
      Xs2[4 + m][c] = v4;
    }
    __syncthreads();

    const int dstart = (j < i) ? (b0 + sg * 16) : 0;
    const int nsteps = (j < i) ? 5 : (sg + 1);
    for (int k = 0; k < nsteps; ++k) {
      const int d0    = dstart + 16 * k;
      const int rbase = l0w - d0 - sbase;
      float fr[16];
#pragma unroll
      for (int m = 0; m < 16; ++m) fr[m] = fcol[(d0 + m) * HD];
      float xw[32];
      const int xgb = rbase >> 2;
#pragma unroll
      for (int m = 0; m < 8; ++m) {
        const float4 v4 = Xs2[xgb + m][c];
        xw[4 * m + 0] = v4.x; xw[4 * m + 1] = v4.y;
        xw[4 * m + 2] = v4.z; xw[4 * m + 3] = v4.w;
      }
#pragma unroll
      for (int li = 0; li < 16; ++li)
#pragma unroll
        for (int dd = 0; dd < 16; ++dd)
          acc[li] = fmaf(fr[dd], xw[li - dd + 16], acc[li]);
    }
    __syncthreads();
  }

#pragma unroll
  for (int li = 0; li < 16; ++li)
    xt_p[(size_t)(l0w + li) * DM + head * HD + c] = acc[li];
}

// ---------------------------------------------------------------------------
// K1b: xtb[l][k] = bf16(p0+p1+p2+p3). grid 384, block 256 (8 elems/thread).
__global__ __launch_bounds__(256) void pack_xt(const float* __restrict__ a,
                                               const float* __restrict__ b,
                                               const float* __restrict__ cc,
                                               const float* __restrict__ d,
                                               u16* __restrict__ xtb) {
  const size_t i = ((size_t)blockIdx.x * 256 + threadIdx.x) * 8;
  u16x8 o;
#pragma unroll
  for (int h = 0; h < 2; ++h) {
    const float4 a4 = *(const float4*)(a + i + h * 4);
    const float4 b4 = *(const float4*)(b + i + h * 4);
    const float4 c4 = *(const float4*)(cc + i + h * 4);
    const float4 d4 = *(const float4*)(d + i + h * 4);
    o[h * 4 + 0] = f2b(a4.x + b4.x + c4.x + d4.x);
    o[h * 4 + 1] = f2b(a4.y + b4.y + c4.y + d4.y);
    o[h * 4 + 2] = f2b(a4.z + b4.z + c4.z + d4.z);
    o[h * 4 + 3] = f2b(a4.w + b4.w + c4.w + d4.w);
  }
  *(u16x8*)(xtb + i) = o;
}

// ---------------------------------------------------------------------------
// K2: q/k/v via bf16 MFMA, 64x64 tile, BK=64, global_load_lds staging with
// st-swizzled LDS (T2) + bijective XCD-locality block mapping (T1).
// grid 576 linear, block 256 (4 waves, each 32x32 output).
__global__ __launch_bounds__(256) void qkv_mfma(const u16* __restrict__ xtb,
                                                const u16* __restrict__ wT,
                                                const float* __restrict__ bq,
                                                const float* __restrict__ bk,
                                                const float* __restrict__ bv,
                                                float* __restrict__ qo,
                                                float* __restrict__ ko,
                                                float* __restrict__ vo) {
  // XCD swizzle: xcd owns 9 contiguous (z,ct,half) units -> L2-resident slice
  const int b = blockIdx.x;
  const int xcd = b & 7, j = b >> 3;
  const int unit = xcd * 9 + (j >> 3), sub = j & 7;
  const int z = unit / 24, rem = unit % 24;
  const int ct = rem >> 1, rt = (rem & 1) * 8 + sub;

  __shared__ u16 As[64 * 64];   // 8 KB, rows x 64k, 128B rows, XOR-swizzled
  __shared__ u16 Bs[64 * 64];

  const int tid = threadIdx.x, w = tid >> 6, l = tid & 63;
  const int wr = w >> 1, wc = w & 1;

  // staging coords: thread fills 16B slot tid*16 (rows 0..31) and +4KB (32..63)
  const int srow1 = tid >> 3, sc16 = tid & 7;
  const int c16L1 = sc16 ^ (srow1 & 7);
  const int srow2 = srow1 + 32;
  const int c16L2 = sc16 ^ (srow2 & 7);

  const u16* wz = wT + (size_t)z * WSZ;
  const u16* Ag1 = xtb + (size_t)(rt * 64 + srow1) * DM + c16L1 * 8;
  const u16* Ag2 = xtb + (size_t)(rt * 64 + srow2) * DM + c16L2 * 8;
  const u16* Bg1 = wz + (size_t)(ct * 64 + srow1) * DM + c16L1 * 8;
  const u16* Bg2 = wz + (size_t)(ct * 64 + srow2) * DM + c16L2 * 8;

  char* lA = (char*)As + w * 1024;
  char* lB = (char*)Bs + w * 1024;

  f32x4 acc[2][2] = {};
  for (int kb = 0; kb < DM; kb += 64) {
    gld16(Ag1 + kb, lA);
    gld16(Ag2 + kb, lA + 4096);
    gld16(Bg1 + kb, lB);
    gld16(Bg2 + kb, lB + 4096);
    __syncthreads();   // drains vmcnt -> staged data visible
#pragma unroll
    for (int kk = 0; kk < 2; ++kk) {
      bf16x8 a[2], bb[2];
#pragma unroll
      for (int ar = 0; ar < 2; ++ar) {
        const int row = wr * 32 + ar * 16 + (l & 15);
        const int c16 = ((kk << 2) + (l >> 4)) ^ (row & 7);
        a[ar] = *(const bf16x8*)((char*)As + row * 128 + c16 * 16);
      }
#pragma unroll
      for (int bc = 0; bc < 2; ++bc) {
        const int col = wc * 32 + bc * 16 + (l & 15);
        const int c16 = ((kk << 2) + (l >> 4)) ^ (col & 7);
        bb[bc] = *(const bf16x8*)((char*)Bs + col * 128 + c16 * 16);
      }
#pragma unroll
      for (int ar = 0; ar < 2; ++ar)
#pragma unroll
        for (int bc = 0; bc < 2; ++bc)
          acc[ar][bc] = __builtin_amdgcn_mfma_f32_16x16x32_bf16(
              a[ar], bb[bc], acc[ar][bc], 0, 0, 0);
    }
    __syncthreads();   // all reads done before next stage overwrites
  }

  const float* bias = (z == 0) ? bq : (z == 1) ? bk : bv;
  float* out = (z == 0) ? qo : (z == 1) ? ko : vo;
  const int rbase = rt * 64 + wr * 32 + ((l >> 4) << 2);
  const int cb = wc * 32 + (l & 15);
#pragma unroll
  for (int ar = 0; ar < 2; ++ar)
#pragma unroll
    for (int bc = 0; bc < 2; ++bc) {
      const int col = cb + bc * 16;
      const float bbv = bias[ct * 64 + col];
#pragma unroll
      for (int r = 0; r < 4; ++r)
        out[((size_t)ct * LS + rbase + ar * 16 + r) * HD + col] =
            acc[ar][bc][r] + bbv;
    }
}

// ---------------------------------------------------------------------------
// K6: y = lerpb @ wo + b, same structure. grid 192 linear, block 256.
__global__ __launch_bounds__(256) void out_mfma(const u16* __restrict__ lerpb,
                                                const u16* __restrict__ woT,
                                                const float* __restrict__ bias,
                                                float* __restrict__ out) {
  const int b = blockIdx.x;
  const int xcd = b & 7, j = b >> 3;
  const int unit = xcd * 3 + (j >> 3), sub = j & 7;
  const int ct = unit >> 1, rt = (unit & 1) * 8 + sub;

  __shared__ u16 As[64 * 64];
  __shared__ u16 Bs[64 * 64];

  const int tid = threadIdx.x, w = tid >> 6, l = tid & 63;
  const int wr = w >> 1, wc = w & 1;

  const int srow1 = tid >> 3, sc16 = tid & 7;
  const int c16L1 = sc16 ^ (srow1 & 7);
  const int srow2 = srow1 + 32;
  const int c16L2 = sc16 ^ (srow2 & 7);

  const u16* Ag1 = lerpb + (size_t)(rt * 64 + srow1) * DM + c16L1 * 8;
  const u16* Ag2 = lerpb + (size_t)(rt * 64 + srow2) * DM + c16L2 * 8;
  const u16* Bg1 = woT + (size_t)(ct * 64 + srow1) * DM + c16L1 * 8;
  const u16* Bg2 = woT + (size_t)(ct * 64 + srow2) * DM + c16L2 * 8;

  char* lA = (char*)As + w * 1024;
  char* lB = (char*)Bs + w * 1024;

  f32x4 acc[2][2] = {};
  for (int kb = 0; kb < DM; kb += 64) {
    gld16(Ag1 + kb, lA);
    gld16(Ag2 + kb, lA + 4096);
    gld16(Bg1 + kb, lB);
    gld16(Bg2 + kb, lB + 4096);
    __syncthreads();
#pragma unroll
    for (int kk = 0; kk < 2; ++kk) {
      bf16x8 a[2], bb[2];
#pragma unroll
      for (int ar = 0; ar < 2; ++ar) {
        const int row = wr * 32 + ar * 16 + (l & 15);
        const int c16 = ((kk << 2) + (l >> 4)) ^ (row & 7);
        a[ar] = *(const bf16x8*)((char*)As + row * 128 + c16 * 16);
      }
#pragma unroll
      for (int bc = 0; bc < 2; ++bc) {
        const int col = wc * 32 + bc * 16 + (l & 15);
        const int c16 = ((kk << 2) + (l >> 4)) ^ (col & 7);
        bb[bc] = *(const bf16x8*)((char*)Bs + col * 128 + c16 * 16);
      }
#pragma unroll
      for (int ar = 0; ar < 2; ++ar)
#pragma unroll
        for (int bc = 0; bc < 2; ++bc)
          acc[ar][bc] = __builtin_amdgcn_mfma_f32_16x16x32_bf16(
              a[ar], bb[bc], acc[ar][bc], 0, 0, 0);
    }
    __syncthreads();
  }

  const int rbase = rt * 64 + wr * 32 + ((l >> 4) << 2);
  const int cb = wc * 32 + (l & 15);
#pragma unroll
  for (int ar = 0; ar < 2; ++ar)
#pragma unroll
    for (int bc = 0; bc < 2; ++bc) {
      const int col = ct * 64 + cb + bc * 16;
      const float bbv = bias[col];
#pragma unroll
      for (int r = 0; r < 4; ++r)
        out[(size_t)(rbase + ar * 16 + r) * DM + col] = acc[ar][bc][r] + bbv;
    }
}

// ---------------------------------------------------------------------------
// K3: l2norm + sim + gates. Unchanged (passing).
__global__ void norm_sim_gate(float* __restrict__ q, float* __restrict__ k, float* __restrict__ v,
                              const float* __restrict__ wg, const float* __restrict__ wgb,
                              const float* __restrict__ qk_scale, const float* __restrict__ kv_scale,
                              float* __restrict__ sim, float* __restrict__ gates) {
  const int w = threadIdx.x >> 6, lane = threadIdx.x & 63;
  const int l = blockIdx.x * 4 + w;
  const int head = blockIdx.y;
  const size_t idx = ((size_t)head * LS + l) * HD + lane;
  float qv = q[idx], kv = k[idx], vv = v[idx];

  auto red = [](float x) {
#pragma unroll
    for (int o = 32; o; o >>= 1) x += __shfl_xor(x, o);
    return x;
  };
  const float qn = fmaxf(sqrtf(red(qv * qv)), 1e-12f);
  const float kn = fmaxf(sqrtf(red(kv * kv)), 1e-12f);
  const float vn = fmaxf(sqrtf(red(vv * vv)), 1e-12f);
  qv /= qn; kv /= kn; vv /= vn;
  q[idx] = qv; k[idx] = kv; v[idx] = vv;

  const float s = red(qv * kv) * qk_scale[head];

  __shared__ float vs[4][64];
  vs[w][lane] = vv;
  __syncthreads();
  float t = 0.f;
#pragma unroll 8
  for (int p = 0; p < 64; ++p) t = fmaf(vs[w][p], wg[p * 64 + lane], t);
  float gl = red(t * kv) * kv_scale[head] + wgb[0];
  gl = gl > 0.f ? gl : ALPHAF * gl;
  const float g = gl * gl + EPSF;
  if (lane == 0) {
    sim[head * LS + l] = s;
    gates[head * LS + l] = g;
  }
}

// ---------------------------------------------------------------------------
// K4: per-head scalar prefix scans. Unchanged (passing).
__global__ void scan_kernel(const float* __restrict__ sim, const float* __restrict__ gates,
                            float* __restrict__ m_s, float* __restrict__ Sraw,
                            float* __restrict__ g_s) {
  const int head = blockIdx.x, t = threadIdx.x;
  __shared__ float bm[1024], bs[1024], bg[1024];
  const float sv = sim[head * LS + t];
  float m = sv, S = expf(sv), g = gates[head * LS + t];
  bm[t] = m; bs[t] = S; bg[t] = g;
  __syncthreads();
  for (int off = 1; off < 1024; off <<= 1) {
    float om = -1e30f, os = 0.f, og = 0.f;
    if (t >= off) { om = bm[t - off]; os = bs[t - off]; og = bg[t - off]; }
    __syncthreads();
    m = fmaxf(m, om); S += os; g += og;
    bm[t] = m; bs[t] = S; bg[t] = g;
    __syncthreads();
  }
  m_s[head * LS + t] = m;
  Sraw[head * LS + t] = S;
  g_s[head * LS + t] = g;
}

// ---------------------------------------------------------------------------
// K5a: per-tile states. Unchanged (passing).
__global__ __launch_bounds__(256) void state_kernel(const float* __restrict__ k,
                                                    const float* __restrict__ v,
                                                    const float* __restrict__ sim,
                                                    const float* __restrict__ gates,
                                                    float* __restrict__ states,
                                                    float* __restrict__ nes) {
  const int j = blockIdx.x, head = blockIdx.y;
  const int s0 = j * SG;
  const int tid = threadIdx.x;
  __shared__ alignas(16) float Vs[SG][68];
  __shared__ alignas(16) float Kg[SG][68];
  __shared__ float Es[SG];

  const int r = tid >> 4, c = (tid & 15) * 4;
  const float* kh = k + ((size_t)head * LS + s0) * HD;
  const float* vh = v + ((size_t)head * LS + s0) * HD;
  const float g = gates[head * LS + s0 + r];
  *(float4*)&Vs[r][c] = *(const float4*)(vh + r * HD + c);
  float4 k4 = *(const float4*)(kh + r * HD + c);
  k4.x *= g; k4.y *= g; k4.z *= g; k4.w *= g;
  *(float4*)&Kg[r][c] = k4;
  if (tid < SG) Es[tid] = expf(sim[head * LS + s0 + tid]);
  __syncthreads();

  const int p0 = (tid >> 4) * 4, n0 = (tid & 15) * 4;
  float acc[4][4] = {};
  for (int s = 0; s < SG; ++s) {
    const float4 ra = *(const float4*)&Vs[s][p0];
    const float4 rb = *(const float4*)&Kg[s][n0];
    const float av[4] = {ra.x, ra.y, ra.z, ra.w};
    const float bv[4] = {rb.x, rb.y, rb.z, rb.w};
#pragma unroll
    for (int i = 0; i < 4; ++i)
#pragma unroll
      for (int jj = 0; jj < 4; ++jj)
        acc[i][jj] = fmaf(av[i], bv[jj], acc[i][jj]);
  }
  float* Sout = states + (size_t)(head * NTL + j) * 4096;
#pragma unroll
  for (int i = 0; i < 4; ++i)
    *(float4*)&Sout[(p0 + i) * 64 + n0] =
        make_float4(acc[i][0], acc[i][1], acc[i][2], acc[i][3]);

  if (tid < HD) {
    float ne = 0.f;
    for (int s = 0; s < SG; ++s) ne = fmaf(Es[s], Vs[s][tid], ne);
    nes[(size_t)(head * NTL + j) * HD + tid] = ne;
  }
}

// ---------------------------------------------------------------------------
// K5b: in-place exclusive prefix over tile-states. Unchanged (passing).
__global__ __launch_bounds__(256) void prefix_kernel(float* __restrict__ states,
                                                     float* __restrict__ nes) {
  const int head = blockIdx.x, chunk = blockIdx.y;
  const int tid = threadIdx.x;
  const int off = chunk * 1024 + tid * 4;
  float4 acc = make_float4(0.f, 0.f, 0.f, 0.f);
  float* base = states + (size_t)head * NTL * 4096 + off;
#pragma unroll 4
  for (int j = 0; j < NTL; ++j) {
    float4* p = (float4*)(base + (size_t)j * 4096);
    const float4 sv = *p;
    *p = acc;
    acc.x += sv.x; acc.y += sv.y; acc.z += sv.z; acc.w += sv.w;
  }
  if (chunk == 0 && tid < HD) {
    float a = 0.f;
    float* nb = nes + (size_t)head * NTL * HD + tid;
#pragma unroll 4
    for (int j = 0; j < NTL; ++j) {
      float* p = nb + (size_t)j * HD;
      const float t = *p;
      *p = a;
      a += t;
    }
  }
}

// ---------------------------------------------------------------------------
// K5c: apply + epilogue; writes lerp in bf16 for the MFMA out-GEMM.
// grid (NTL=64, NH), block 256.
__global__ __launch_bounds__(256) void apply_kernel(const float* __restrict__ q,
                                                    const float* __restrict__ k,
                                                    const float* __restrict__ v,
                                                    const float* __restrict__ sim,
                                                    const float* __restrict__ gates,
                                                    const float* __restrict__ m_s,
                                                    const float* __restrict__ Sraw,
                                                    const float* __restrict__ g_s,
                                                    const float* __restrict__ states,
                                                    const float* __restrict__ nes,
                                                    const float* __restrict__ kv_scale,
                                                    u16* __restrict__ lerpb) {
  const int bt = blockIdx.x, head = blockIdx.y;
  const int t0 = bt * SG;
  const int tid = threadIdx.x;
  __shared__ alignas(16) float Ps[64][68];
  __shared__ alignas(16) float Qs[SG][68];
  __shared__ alignas(16) float Vs[SG][68];
  __shared__ alignas(16) float Ks[SG][68];
  __shared__ alignas(16) float NEp[64];
  __shared__ float Ag[SG][SG + 1];
  __shared__ float Es[SG], Gs[SG];

  const float* Pg = states + (size_t)(head * NTL + bt) * 4096;
#pragma unroll
  for (int rep = 0; rep < 4; ++rep) {
    const int lin = rep * 1024 + tid * 4;
    *(float4*)&Ps[lin >> 6][lin & 63] = *(const float4*)(Pg + lin);
  }
  {
    const int r = tid >> 4, c = (tid & 15) * 4;
    const size_t rowbase = ((size_t)head * LS + t0 + r) * HD;
    *(float4*)&Qs[r][c] = *(const float4*)(q + rowbase + c);
    *(float4*)&Ks[r][c] = *(const float4*)(k + rowbase + c);
    *(float4*)&Vs[r][c] = *(const float4*)(v + rowbase + c);
  }
  if (tid < SG) {
    Es[tid] = expf(sim[head * LS + t0 + tid]);
    Gs[tid] = gates[head * LS + t0 + tid];
  }
  if (tid < HD) NEp[tid] = nes[(size_t)(head * NTL + bt) * HD + tid];
  __syncthreads();

  {
    const int t = tid >> 4, s = tid & 15;
    float a = 0.f;
    if (s <= t) {
#pragma unroll
      for (int p = 0; p < 64; p += 4) {
        const float4 q4 = *(const float4*)&Qs[t][p];
        const float4 v4 = *(const float4*)&Vs[s][p];
        a = fmaf(q4.x, v4.x, a); a = fmaf(q4.y, v4.y, a);
        a = fmaf(q4.z, v4.z, a); a = fmaf(q4.w, v4.w, a);
      }
      a *= Gs[s];
    }
    Ag[t][s] = a;
  }
  __syncthreads();

  const int r = tid >> 4, c0 = (tid & 15) * 4;
  float4 O = make_float4(0.f, 0.f, 0.f, 0.f);
#pragma unroll 8
  for (int p = 0; p < 64; ++p) {
    const float qv = Qs[r][p];
    const float4 p4 = *(const float4*)&Ps[p][c0];
    O.x = fmaf(qv, p4.x, O.x); O.y = fmaf(qv, p4.y, O.y);
    O.z = fmaf(qv, p4.z, O.z); O.w = fmaf(qv, p4.w, O.w);
  }
  float4 Nn = *(const float4*)&NEp[c0];
  for (int s = 0; s <= r; ++s) {
    const float ag = Ag[r][s];
    const float es = Es[s];
    const float4 k4 = *(const float4*)&Ks[s][c0];
    const float4 v4 = *(const float4*)&Vs[s][c0];
    O.x = fmaf(ag, k4.x, O.x); O.y = fmaf(ag, k4.y, O.y);
    O.z = fmaf(ag, k4.z, O.z); O.w = fmaf(ag, k4.w, O.w);
    Nn.x = fmaf(es, v4.x, Nn.x); Nn.y = fmaf(es, v4.y, Nn.y);
    Nn.z = fmaf(es, v4.z, Nn.z); Nn.w = fmaf(es, v4.w, Nn.w);
  }

  const int t = t0 + r;
  const float m  = m_s[head * LS + t];
  const float em = expf(-m);
  const float ss = Sraw[head * LS + t] * em;
  const float inv = 1.f / (ss + EPSF);
  const float sw  = expf(sim[head * LS + t] - m) * inv;
  const float gi  = kv_scale[head] / (g_s[head * LS + t] + EPSF);
  const float ei  = em * inv;
  float rx, ry, rz, rw;
  { const float cx = O.x * gi, la = Nn.x * ei; rx = cx + (la - cx) * sw; }
  { const float cx = O.y * gi, la = Nn.y * ei; ry = cx + (la - cx) * sw; }
  { const float cx = O.z * gi, la = Nn.z * ei; rz = cx + (la - cx) * sw; }
  { const float cx = O.w * gi, la = Nn.w * ei; rw = cx + (la - cx) * sw; }
  ushort4 ob;
  ob.x = f2b(rx); ob.y = f2b(ry); ob.z = f2b(rz); ob.w = f2b(rw);
  *(ushort4*)&lerpb[(size_t)t * DM + head * HD + c0] = ob;
}

// ---------------------------------------------------------------------------
extern "C" void kernel_launch(void* const* d_in, const int* in_sizes, int n_in,
                              void* d_out, int out_size, void* d_ws, size_t ws_size,
                              hipStream_t stream) {
  (void)in_sizes; (void)n_in; (void)out_size; (void)ws_size;
  const float* x        = (const float*)d_in[0];
  const float* filters  = (const float*)d_in[1];
  const float* wq_w     = (const float*)d_in[2];
  const float* wq_b     = (const float*)d_in[3];
  const float* wk_w     = (const float*)d_in[4];
  const float* wk_b     = (const float*)d_in[5];
  const float* wv_w     = (const float*)d_in[6];
  const float* wv_b     = (const float*)d_in[7];
  const float* wo_w     = (const float*)d_in[8];
  const float* wo_b     = (const float*)d_in[9];
  const float* wg_w     = (const float*)d_in[10];
  const float* wg_b     = (const float*)d_in[11];
  const float* qk_scale = (const float*)d_in[12];
  const float* kv_scale = (const float*)d_in[13];

  float* ws = (float*)d_ws;
  const size_t NT = (size_t)LS * DM;  // 786432
  float* xt_a  = ws;                  // conv partial parity 0; later reused as lerpb
  float* xt_b  = ws + NT;             // parity 1
  float* q     = ws + 2 * NT;         // parity 2 partial until pack; then q
  float* k     = ws + 3 * NT;         // parity 3 partial until pack; then k
  float* v     = ws + 4 * NT;
  float* sim   = ws + 5 * NT;
  float* gates = sim + NH * LS;
  float* m_s   = gates + NH * LS;
  float* Sraw  = m_s + NH * LS;
  float* g_s   = Sraw + NH * LS;
  float* states = g_s + NH * LS;                       // 12*64*4096
  float* nes    = states + (size_t)NH * NTL * 4096;    // 12*64*64
  u16*   xtb    = (u16*)(nes + (size_t)NH * NTL * HD); // NT bf16
  u16*   wT     = xtb + NT;                            // 4 * 589824 bf16
  u16*   lerpb  = (u16*)xt_a;                          // alias: xt dead after pack

  txw_kernel<<<dim3(DM / 64, DM / 64, 4), 256, 0, stream>>>(wq_w, wk_w, wv_w, wo_w, wT);
  conv_kernel<<<dim3(LS / 64, NH, 4), 256, 0, stream>>>(x, filters, xt_a, xt_b, q, k);
  pack_xt<<<dim3(NT / 2048), 256, 0, stream>>>(xt_a, xt_b, q, k, xtb);
  qkv_mfma<<<dim3(576), 256, 0, stream>>>(xtb, wT, wq_b, wk_b, wv_b, q, k, v);
  norm_sim_gate<<<dim3(LS / 4, NH), 256, 0, stream>>>(
      q, k, v, wg_w, wg_b, qk_scale, kv_scale, sim, gates);
  scan_kernel<<<dim3(NH), 1024, 0, stream>>>(sim, gates, m_s, Sraw, g_s);
  state_kernel<<<dim3(NTL, NH), 256, 0, stream>>>(k, v, sim, gates, states, nes);
  prefix_kernel<<<dim3(NH, 4), 256, 0, stream>>>(states, nes);
  apply_kernel<<<dim3(NTL, NH), 256, 0, stream>>>(
      q, k, v, sim, gates, m_s, Sraw, g_s, states, nes, kv_scale, lerpb);
  out_mfma<<<dim3(192), 256, 0, stream>>>(
      lerpb, wT + 3 * (size_t)WSZ, wo_b, (float*)d_out);
}

// Round 9
// 102.490 us; speedup vs baseline: 4.5806x; 1.0583x over previous
//
#include <hip/hip_runtime.h>
#include <hip/hip_bf16.h>

constexpr int LS = 1024;   // sequence length
constexpr int DM = 768;    // model dim
constexpr int NH = 12;     // heads
constexpr int HD = 64;     // head dim
constexpr float EPSF = 1e-5f;
constexpr float ALPHAF = 0.01f;

constexpr int SG = 16;             // state granularity (rows per tile)
constexpr int NTL = LS / SG;       // 64 tiles per head
constexpr int WSZ = DM * DM;       // 589824 elements per weight matrix
constexpr int NPAR = 8;            // conv parity split

typedef unsigned short u16;
typedef __attribute__((ext_vector_type(8))) short bf16x8;
typedef __attribute__((ext_vector_type(8))) unsigned short u16x8;
typedef __attribute__((ext_vector_type(4))) float f32x4;

__device__ __forceinline__ u16 f2b(float f) {
  unsigned u = __float_as_uint(f);
  u += 0x7FFFu + ((u >> 16) & 1u);   // round-to-nearest-even
  return (u16)(u >> 16);
}

// async global->LDS, 16B per lane; LDS dest is wave-uniform base + lane*16
__device__ __forceinline__ void gld16(const u16* g, void* l) {
  __builtin_amdgcn_global_load_lds(
      (const __attribute__((address_space(1))) void*)g,
      (__attribute__((address_space(3))) void*)l, 16, 0, 0);
}

// ---------------------------------------------------------------------------
// K1: FUSED causal-conv (parity-8 banded stencil) + weight transpose/bf16 pack.
// grid 1536+576 = 2112 linear blocks, block 256, dynamic LDS 28672 B.
//  b < 1536 : conv block (i = b%16, head = (b/16)%12, par = b/192)
//  b >= 1536: txw block  (kb = b2%12, nb = (b2/12)%12, z = b2/144)
__global__ __launch_bounds__(256) void conv_txw_kernel(
    const float* __restrict__ x, const float* __restrict__ f,
    const float* __restrict__ wq, const float* __restrict__ wk,
    const float* __restrict__ wv, const float* __restrict__ wo,
    u16* __restrict__ wT, float* __restrict__ pbase) {
  extern __shared__ char smem[];
  const int b = blockIdx.x;
  const int tid = threadIdx.x;

  if (b >= 1536) {
    // ---- txw: wT[z][n][k] = bf16(w[k][n]) ----
    const int b2 = b - 1536;
    const int kb = (b2 % 12) * 64, nb = ((b2 / 12) % 12) * 64, z = b2 / 144;
    const float* src = (z == 0) ? wq : (z == 1) ? wk : (z == 2) ? wv : wo;
    u16* dst = wT + (size_t)z * WSZ;
    float (*T)[65] = (float(*)[65])smem;
#pragma unroll
    for (int rep = 0; rep < 4; ++rep) {
      const int r = rep * 16 + (tid >> 4);
      const int c4 = (tid & 15) * 4;
      const float4 v4 = *(const float4*)(src + (size_t)(kb + r) * DM + nb + c4);
      T[r][c4] = v4.x; T[r][c4 + 1] = v4.y; T[r][c4 + 2] = v4.z; T[r][c4 + 3] = v4.w;
    }
    __syncthreads();
#pragma unroll
    for (int rep = 0; rep < 4; ++rep) {
      const int n = rep * 16 + (tid >> 4);
      const int k4 = (tid & 15) * 4;
      ushort4 o;
      o.x = f2b(T[k4 + 0][n]); o.y = f2b(T[k4 + 1][n]);
      o.z = f2b(T[k4 + 2][n]); o.w = f2b(T[k4 + 3][n]);
      *(ushort4*)(dst + (size_t)(nb + n) * DM + kb + k4) = o;
    }
    return;
  }

  // ---- conv ----
  const int i    = b & 15;
  const int head = (b >> 4) % 12;
  const int par  = b / 192;
  const int c    = tid & 63;
  const int sg   = tid >> 6;
  const int tbase = i * 64;
  const int l0w   = tbase + sg * 16;
  float* __restrict__ xt_p = pbase + (size_t)par * LS * DM;

  // r_pad groups 0..27 (pad 0..3 and 20..27 zeroed), data groups 4..19
  float4 (*Xs2)[64] = (float4(*)[64])smem;

  {
    const float4 z4 = make_float4(0.f, 0.f, 0.f, 0.f);
#pragma unroll
    for (int k = 0; k < 3; ++k) {
      const int lin = k * 256 + tid;
      const int g   = lin >> 6;
      const int cc  = lin & 63;
      const int grp = (g < 4) ? g : (16 + g);
      Xs2[grp][cc] = z4;
    }
  }

  float acc[16];
#pragma unroll
  for (int t = 0; t < 16; ++t) acc[t] = 0.f;

  const float* xg   = x + head * HD + c;
  const float* fcol = f + c;

  for (int j = par; j <= i; j += NPAR) {
    const int sbase = j * 64;
    const int b0 = (j < i) ? (tbase - sbase - 64) : 0;
#pragma unroll
    for (int k = 0; k < 4; ++k) {
      const int m  = sg + 4 * k;
      const int ss = 4 * m;
      float4 v4;
      v4.x = xg[(sbase + ss + 0) * DM];
      v4.y = xg[(sbase + ss + 1) * DM];
      v4.z = xg[(sbase + ss + 2) * DM];
      v4.w = xg[(sbase + ss + 3) * DM];
      Xs2[4 + m][c] = v4;
    }
    __syncthreads();

    const int dstart = (j < i) ? (b0 + sg * 16) : 0;
    const int nsteps = (j < i) ? 5 : (sg + 1);
    for (int k = 0; k < nsteps; ++k) {
      const int d0    = dstart + 16 * k;
      const int rbase = l0w - d0 - sbase;
      float fr[16];
#pragma unroll
      for (int m = 0; m < 16; ++m) fr[m] = fcol[(d0 + m) * HD];
      float xw[32];
      const int xgb = rbase >> 2;
#pragma unroll
      for (int m = 0; m < 8; ++m) {
        const float4 v4 = Xs2[xgb + m][c];
        xw[4 * m + 0] = v4.x; xw[4 * m + 1] = v4.y;
        xw[4 * m + 2] = v4.z; xw[4 * m + 3] = v4.w;
      }
#pragma unroll
      for (int li = 0; li < 16; ++li)
#pragma unroll
        for (int dd = 0; dd < 16; ++dd)
          acc[li] = fmaf(fr[dd], xw[li - dd + 16], acc[li]);
    }
    __syncthreads();
  }

#pragma unroll
  for (int li = 0; li < 16; ++li)
    xt_p[(size_t)(l0w + li) * DM + head * HD + c] = acc[li];
}

// ---------------------------------------------------------------------------
// K1b: xtb = bf16(sum of 8 partials). grid 384, block 256 (8 elems/thread).
__global__ __launch_bounds__(256) void pack_xt(const float* __restrict__ pbase,
                                               u16* __restrict__ xtb) {
  const size_t NT = (size_t)LS * DM;
  const size_t i = ((size_t)blockIdx.x * 256 + threadIdx.x) * 8;
  u16x8 o;
#pragma unroll
  for (int h = 0; h < 2; ++h) {
    float4 s = make_float4(0.f, 0.f, 0.f, 0.f);
#pragma unroll
    for (int p = 0; p < NPAR; ++p) {
      const float4 v4 = *(const float4*)(pbase + p * NT + i + h * 4);
      s.x += v4.x; s.y += v4.y; s.z += v4.z; s.w += v4.w;
    }
    o[h * 4 + 0] = f2b(s.x); o[h * 4 + 1] = f2b(s.y);
    o[h * 4 + 2] = f2b(s.z); o[h * 4 + 3] = f2b(s.w);
  }
  *(u16x8*)(xtb + i) = o;
}

// ---------------------------------------------------------------------------
// K2: q/k/v via bf16 MFMA, 64x64 tile, BK=64, global_load_lds staging with
// XOR-swizzled LDS (T2) + bijective XCD-locality block mapping (T1).
// grid 576 linear, block 256 (4 waves, each 32x32 output). Unchanged (passing).
__global__ __launch_bounds__(256) void qkv_mfma(const u16* __restrict__ xtb,
                                                const u16* __restrict__ wT,
                                                const float* __restrict__ bq,
                                                const float* __restrict__ bk,
                                                const float* __restrict__ bv,
                                                float* __restrict__ qo,
                                                float* __restrict__ ko,
                                                float* __restrict__ vo) {
  const int b = blockIdx.x;
  const int xcd = b & 7, j = b >> 3;
  const int unit = xcd * 9 + (j >> 3), sub = j & 7;
  const int z = unit / 24, rem = unit % 24;
  const int ct = rem >> 1, rt = (rem & 1) * 8 + sub;

  __shared__ u16 As[64 * 64];
  __shared__ u16 Bs[64 * 64];

  const int tid = threadIdx.x, w = tid >> 6, l = tid & 63;
  const int wr = w >> 1, wc = w & 1;

  const int srow1 = tid >> 3, sc16 = tid & 7;
  const int c16L1 = sc16 ^ (srow1 & 7);
  const int srow2 = srow1 + 32;
  const int c16L2 = sc16 ^ (srow2 & 7);

  const u16* wz = wT + (size_t)z * WSZ;
  const u16* Ag1 = xtb + (size_t)(rt * 64 + srow1) * DM + c16L1 * 8;
  const u16* Ag2 = xtb + (size_t)(rt * 64 + srow2) * DM + c16L2 * 8;
  const u16* Bg1 = wz + (size_t)(ct * 64 + srow1) * DM + c16L1 * 8;
  const u16* Bg2 = wz + (size_t)(ct * 64 + srow2) * DM + c16L2 * 8;

  char* lA = (char*)As + w * 1024;
  char* lB = (char*)Bs + w * 1024;

  f32x4 acc[2][2] = {};
  for (int kb = 0; kb < DM; kb += 64) {
    gld16(Ag1 + kb, lA);
    gld16(Ag2 + kb, lA + 4096);
    gld16(Bg1 + kb, lB);
    gld16(Bg2 + kb, lB + 4096);
    __syncthreads();
#pragma unroll
    for (int kk = 0; kk < 2; ++kk) {
      bf16x8 a[2], bb[2];
#pragma unroll
      for (int ar = 0; ar < 2; ++ar) {
        const int row = wr * 32 + ar * 16 + (l & 15);
        const int c16 = ((kk << 2) + (l >> 4)) ^ (row & 7);
        a[ar] = *(const bf16x8*)((char*)As + row * 128 + c16 * 16);
      }
#pragma unroll
      for (int bc = 0; bc < 2; ++bc) {
        const int col = wc * 32 + bc * 16 + (l & 15);
        const int c16 = ((kk << 2) + (l >> 4)) ^ (col & 7);
        bb[bc] = *(const bf16x8*)((char*)Bs + col * 128 + c16 * 16);
      }
#pragma unroll
      for (int ar = 0; ar < 2; ++ar)
#pragma unroll
        for (int bc = 0; bc < 2; ++bc)
          acc[ar][bc] = __builtin_amdgcn_mfma_f32_16x16x32_bf16(
              a[ar], bb[bc], acc[ar][bc], 0, 0, 0);
    }
    __syncthreads();
  }

  const float* bias = (z == 0) ? bq : (z == 1) ? bk : bv;
  float* out = (z == 0) ? qo : (z == 1) ? ko : vo;
  const int rbase = rt * 64 + wr * 32 + ((l >> 4) << 2);
  const int cb = wc * 32 + (l & 15);
#pragma unroll
  for (int ar = 0; ar < 2; ++ar)
#pragma unroll
    for (int bc = 0; bc < 2; ++bc) {
      const int col = cb + bc * 16;
      const float bbv = bias[ct * 64 + col];
#pragma unroll
      for (int r = 0; r < 4; ++r)
        out[((size_t)ct * LS + rbase + ar * 16 + r) * HD + col] =
            acc[ar][bc][r] + bbv;
    }
}

// ---------------------------------------------------------------------------
// K6: y = lerpb @ wo + b, same structure. grid 192 linear. Unchanged (passing).
__global__ __launch_bounds__(256) void out_mfma(const u16* __restrict__ lerpb,
                                                const u16* __restrict__ woT,
                                                const float* __restrict__ bias,
                                                float* __restrict__ out) {
  const int b = blockIdx.x;
  const int xcd = b & 7, j = b >> 3;
  const int unit = xcd * 3 + (j >> 3), sub = j & 7;
  const int ct = unit >> 1, rt = (unit & 1) * 8 + sub;

  __shared__ u16 As[64 * 64];
  __shared__ u16 Bs[64 * 64];

  const int tid = threadIdx.x, w = tid >> 6, l = tid & 63;
  const int wr = w >> 1, wc = w & 1;

  const int srow1 = tid >> 3, sc16 = tid & 7;
  const int c16L1 = sc16 ^ (srow1 & 7);
  const int srow2 = srow1 + 32;
  const int c16L2 = sc16 ^ (srow2 & 7);

  const u16* Ag1 = lerpb + (size_t)(rt * 64 + srow1) * DM + c16L1 * 8;
  const u16* Ag2 = lerpb + (size_t)(rt * 64 + srow2) * DM + c16L2 * 8;
  const u16* Bg1 = woT + (size_t)(ct * 64 + srow1) * DM + c16L1 * 8;
  const u16* Bg2 = woT + (size_t)(ct * 64 + srow2) * DM + c16L2 * 8;

  char* lA = (char*)As + w * 1024;
  char* lB = (char*)Bs + w * 1024;

  f32x4 acc[2][2] = {};
  for (int kb = 0; kb < DM; kb += 64) {
    gld16(Ag1 + kb, lA);
    gld16(Ag2 + kb, lA + 4096);
    gld16(Bg1 + kb, lB);
    gld16(Bg2 + kb, lB + 4096);
    __syncthreads();
#pragma unroll
    for (int kk = 0; kk < 2; ++kk) {
      bf16x8 a[2], bb[2];
#pragma unroll
      for (int ar = 0; ar < 2; ++ar) {
        const int row = wr * 32 + ar * 16 + (l & 15);
        const int c16 = ((kk << 2) + (l >> 4)) ^ (row & 7);
        a[ar] = *(const bf16x8*)((char*)As + row * 128 + c16 * 16);
      }
#pragma unroll
      for (int bc = 0; bc < 2; ++bc) {
        const int col = wc * 32 + bc * 16 + (l & 15);
        const int c16 = ((kk << 2) + (l >> 4)) ^ (col & 7);
        bb[bc] = *(const bf16x8*)((char*)Bs + col * 128 + c16 * 16);
      }
#pragma unroll
      for (int ar = 0; ar < 2; ++ar)
#pragma unroll
        for (int bc = 0; bc < 2; ++bc)
          acc[ar][bc] = __builtin_amdgcn_mfma_f32_16x16x32_bf16(
              a[ar], bb[bc], acc[ar][bc], 0, 0, 0);
    }
    __syncthreads();
  }

  const int rbase = rt * 64 + wr * 32 + ((l >> 4) << 2);
  const int cb = wc * 32 + (l & 15);
#pragma unroll
  for (int ar = 0; ar < 2; ++ar)
#pragma unroll
    for (int bc = 0; bc < 2; ++bc) {
      const int col = ct * 64 + cb + bc * 16;
      const float bbv = bias[col];
#pragma unroll
      for (int r = 0; r < 4; ++r)
        out[(size_t)(rbase + ar * 16 + r) * DM + col] = acc[ar][bc][r] + bbv;
    }
}

// ---------------------------------------------------------------------------
// K3: l2norm + sim + gates. Unchanged (passing).
__global__ void norm_sim_gate(float* __restrict__ q, float* __restrict__ k, float* __restrict__ v,
                              const float* __restrict__ wg, const float* __restrict__ wgb,
                              const float* __restrict__ qk_scale, const float* __restrict__ kv_scale,
                              float* __restrict__ sim, float* __restrict__ gates) {
  const int w = threadIdx.x >> 6, lane = threadIdx.x & 63;
  const int l = blockIdx.x * 4 + w;
  const int head = blockIdx.y;
  const size_t idx = ((size_t)head * LS + l) * HD + lane;
  float qv = q[idx], kv = k[idx], vv = v[idx];

  auto red = [](float x) {
#pragma unroll
    for (int o = 32; o; o >>= 1) x += __shfl_xor(x, o);
    return x;
  };
  const float qn = fmaxf(sqrtf(red(qv * qv)), 1e-12f);
  const float kn = fmaxf(sqrtf(red(kv * kv)), 1e-12f);
  const float vn = fmaxf(sqrtf(red(vv * vv)), 1e-12f);
  qv /= qn; kv /= kn; vv /= vn;
  q[idx] = qv; k[idx] = kv; v[idx] = vv;

  const float s = red(qv * kv) * qk_scale[head];

  __shared__ float vs[4][64];
  vs[w][lane] = vv;
  __syncthreads();
  float t = 0.f;
#pragma unroll 8
  for (int p = 0; p < 64; ++p) t = fmaf(vs[w][p], wg[p * 64 + lane], t);
  float gl = red(t * kv) * kv_scale[head] + wgb[0];
  gl = gl > 0.f ? gl : ALPHAF * gl;
  const float g = gl * gl + EPSF;
  if (lane == 0) {
    sim[head * LS + l] = s;
    gates[head * LS + l] = g;
  }
}

// ---------------------------------------------------------------------------
// K4: per-head scalar prefix scans. Unchanged (passing).
__global__ void scan_kernel(const float* __restrict__ sim, const float* __restrict__ gates,
                            float* __restrict__ m_s, float* __restrict__ Sraw,
                            float* __restrict__ g_s) {
  const int head = blockIdx.x, t = threadIdx.x;
  __shared__ float bm[1024], bs[1024], bg[1024];
  const float sv = sim[head * LS + t];
  float m = sv, S = expf(sv), g = gates[head * LS + t];
  bm[t] = m; bs[t] = S; bg[t] = g;
  __syncthreads();
  for (int off = 1; off < 1024; off <<= 1) {
    float om = -1e30f, os = 0.f, og = 0.f;
    if (t >= off) { om = bm[t - off]; os = bs[t - off]; og = bg[t - off]; }
    __syncthreads();
    m = fmaxf(m, om); S += os; g += og;
    bm[t] = m; bs[t] = S; bg[t] = g;
    __syncthreads();
  }
  m_s[head * LS + t] = m;
  Sraw[head * LS + t] = S;
  g_s[head * LS + t] = g;
}

// ---------------------------------------------------------------------------
// K5a: per-tile states. Unchanged (passing).
__global__ __launch_bounds__(256) void state_kernel(const float* __restrict__ k,
                                                    const float* __restrict__ v,
                                                    const float* __restrict__ sim,
                                                    const float* __restrict__ gates,
                                                    float* __restrict__ states,
                                                    float* __restrict__ nes) {
  const int j = blockIdx.x, head = blockIdx.y;
  const int s0 = j * SG;
  const int tid = threadIdx.x;
  __shared__ alignas(16) float Vs[SG][68];
  __shared__ alignas(16) float Kg[SG][68];
  __shared__ float Es[SG];

  const int r = tid >> 4, c = (tid & 15) * 4;
  const float* kh = k + ((size_t)head * LS + s0) * HD;
  const float* vh = v + ((size_t)head * LS + s0) * HD;
  const float g = gates[head * LS + s0 + r];
  *(float4*)&Vs[r][c] = *(const float4*)(vh + r * HD + c);
  float4 k4 = *(const float4*)(kh + r * HD + c);
  k4.x *= g; k4.y *= g; k4.z *= g; k4.w *= g;
  *(float4*)&Kg[r][c] = k4;
  if (tid < SG) Es[tid] = expf(sim[head * LS + s0 + tid]);
  __syncthreads();

  const int p0 = (tid >> 4) * 4, n0 = (tid & 15) * 4;
  float acc[4][4] = {};
  for (int s = 0; s < SG; ++s) {
    const float4 ra = *(const float4*)&Vs[s][p0];
    const float4 rb = *(const float4*)&Kg[s][n0];
    const float av[4] = {ra.x, ra.y, ra.z, ra.w};
    const float bv[4] = {rb.x, rb.y, rb.z, rb.w};
#pragma unroll
    for (int i = 0; i < 4; ++i)
#pragma unroll
      for (int jj = 0; jj < 4; ++jj)
        acc[i][jj] = fmaf(av[i], bv[jj], acc[i][jj]);
  }
  float* Sout = states + (size_t)(head * NTL + j) * 4096;
#pragma unroll
  for (int i = 0; i < 4; ++i)
    *(float4*)&Sout[(p0 + i) * 64 + n0] =
        make_float4(acc[i][0], acc[i][1], acc[i][2], acc[i][3]);

  if (tid < HD) {
    float ne = 0.f;
    for (int s = 0; s < SG; ++s) ne = fmaf(Es[s], Vs[s][tid], ne);
    nes[(size_t)(head * NTL + j) * HD + tid] = ne;
  }
}

// ---------------------------------------------------------------------------
// K5b: in-place exclusive prefix over tile-states. Unchanged (passing).
__global__ __launch_bounds__(256) void prefix_kernel(float* __restrict__ states,
                                                     float* __restrict__ nes) {
  const int head = blockIdx.x, chunk = blockIdx.y;
  const int tid = threadIdx.x;
  const int off = chunk * 1024 + tid * 4;
  float4 acc = make_float4(0.f, 0.f, 0.f, 0.f);
  float* base = states + (size_t)head * NTL * 4096 + off;
#pragma unroll 4
  for (int j = 0; j < NTL; ++j) {
    float4* p = (float4*)(base + (size_t)j * 4096);
    const float4 sv = *p;
    *p = acc;
    acc.x += sv.x; acc.y += sv.y; acc.z += sv.z; acc.w += sv.w;
  }
  if (chunk == 0 && tid < HD) {
    float a = 0.f;
    float* nb = nes + (size_t)head * NTL * HD + tid;
#pragma unroll 4
    for (int j = 0; j < NTL; ++j) {
      float* p = nb + (size_t)j * HD;
      const float t = *p;
      *p = a;
      a += t;
    }
  }
}

// ---------------------------------------------------------------------------
// K5c: apply + epilogue; writes lerp in bf16 for the MFMA out-GEMM.
// grid (NTL=64, NH), block 256. Unchanged (passing).
__global__ __launch_bounds__(256) void apply_kernel(const float* __restrict__ q,
                                                    const float* __restrict__ k,
                                                    const float* __restrict__ v,
                                                    const float* __restrict__ sim,
                                                    const float* __restrict__ gates,
                                                    const float* __restrict__ m_s,
                                                    const float* __restrict__ Sraw,
                                                    const float* __restrict__ g_s,
                                                    const float* __restrict__ states,
                                                    const float* __restrict__ nes,
                                                    const float* __restrict__ kv_scale,
                                                    u16* __restrict__ lerpb) {
  const int bt = blockIdx.x, head = blockIdx.y;
  const int t0 = bt * SG;
  const int tid = threadIdx.x;
  __shared__ alignas(16) float Ps[64][68];
  __shared__ alignas(16) float Qs[SG][68];
  __shared__ alignas(16) float Vs[SG][68];
  __shared__ alignas(16) float Ks[SG][68];
  __shared__ alignas(16) float NEp[64];
  __shared__ float Ag[SG][SG + 1];
  __shared__ float Es[SG], Gs[SG];

  const float* Pg = states + (size_t)(head * NTL + bt) * 4096;
#pragma unroll
  for (int rep = 0; rep < 4; ++rep) {
    const int lin = rep * 1024 + tid * 4;
    *(float4*)&Ps[lin >> 6][lin & 63] = *(const float4*)(Pg + lin);
  }
  {
    const int r = tid >> 4, c = (tid & 15) * 4;
    const size_t rowbase = ((size_t)head * LS + t0 + r) * HD;
    *(float4*)&Qs[r][c] = *(const float4*)(q + rowbase + c);
    *(float4*)&Ks[r][c] = *(const float4*)(k + rowbase + c);
    *(float4*)&Vs[r][c] = *(const float4*)(v + rowbase + c);
  }
  if (tid < SG) {
    Es[tid] = expf(sim[head * LS + t0 + tid]);
    Gs[tid] = gates[head * LS + t0 + tid];
  }
  if (tid < HD) NEp[tid] = nes[(size_t)(head * NTL + bt) * HD + tid];
  __syncthreads();

  {
    const int t = tid >> 4, s = tid & 15;
    float a = 0.f;
    if (s <= t) {
#pragma unroll
      for (int p = 0; p < 64; p += 4) {
        const float4 q4 = *(const float4*)&Qs[t][p];
        const float4 v4 = *(const float4*)&Vs[s][p];
        a = fmaf(q4.x, v4.x, a); a = fmaf(q4.y, v4.y, a);
        a = fmaf(q4.z, v4.z, a); a = fmaf(q4.w, v4.w, a);
      }
      a *= Gs[s];
    }
    Ag[t][s] = a;
  }
  __syncthreads();

  const int r = tid >> 4, c0 = (tid & 15) * 4;
  float4 O = make_float4(0.f, 0.f, 0.f, 0.f);
#pragma unroll 8
  for (int p = 0; p < 64; ++p) {
    const float qv = Qs[r][p];
    const float4 p4 = *(const float4*)&Ps[p][c0];
    O.x = fmaf(qv, p4.x, O.x); O.y = fmaf(qv, p4.y, O.y);
    O.z = fmaf(qv, p4.z, O.z); O.w = fmaf(qv, p4.w, O.w);
  }
  float4 Nn = *(const float4*)&NEp[c0];
  for (int s = 0; s <= r; ++s) {
    const float ag = Ag[r][s];
    const float es = Es[s];
    const float4 k4 = *(const float4*)&Ks[s][c0];
    const float4 v4 = *(const float4*)&Vs[s][c0];
    O.x = fmaf(ag, k4.x, O.x); O.y = fmaf(ag, k4.y, O.y);
    O.z = fmaf(ag, k4.z, O.z); O.w = fmaf(ag, k4.w, O.w);
    Nn.x = fmaf(es, v4.x, Nn.x); Nn.y = fmaf(es, v4.y, Nn.y);
    Nn.z = fmaf(es, v4.z, Nn.z); Nn.w = fmaf(es, v4.w, Nn.w);
  }

  const int t = t0 + r;
  const float m  = m_s[head * LS + t];
  const float em = expf(-m);
  const float ss = Sraw[head * LS + t] * em;
  const float inv = 1.f / (ss + EPSF);
  const float sw  = expf(sim[head * LS + t] - m) * inv;
  const float gi  = kv_scale[head] / (g_s[head * LS + t] + EPSF);
  const float ei  = em * inv;
  float rx, ry, rz, rw;
  { const float cx = O.x * gi, la = Nn.x * ei; rx = cx + (la - cx) * sw; }
  { const float cx = O.y * gi, la = Nn.y * ei; ry = cx + (la - cx) * sw; }
  { const float cx = O.z * gi, la = Nn.z * ei; rz = cx + (la - cx) * sw; }
  { const float cx = O.w * gi, la = Nn.w * ei; rw = cx + (la - cx) * sw; }
  ushort4 ob;
  ob.x = f2b(rx); ob.y = f2b(ry); ob.z = f2b(rz); ob.w = f2b(rw);
  *(ushort4*)&lerpb[(size_t)t * DM + head * HD + c0] = ob;
}

// ---------------------------------------------------------------------------
extern "C" void kernel_launch(void* const* d_in, const int* in_sizes, int n_in,
                              void* d_out, int out_size, void* d_ws, size_t ws_size,
                              hipStream_t stream) {
  (void)in_sizes; (void)n_in; (void)out_size; (void)ws_size;
  const float* x        = (const float*)d_in[0];
  const float* filters  = (const float*)d_in[1];
  const float* wq_w     = (const float*)d_in[2];
  const float* wq_b     = (const float*)d_in[3];
  const float* wk_w     = (const float*)d_in[4];
  const float* wk_b     = (const float*)d_in[5];
  const float* wv_w     = (const float*)d_in[6];
  const float* wv_b     = (const float*)d_in[7];
  const float* wo_w     = (const float*)d_in[8];
  const float* wo_b     = (const float*)d_in[9];
  const float* wg_w     = (const float*)d_in[10];
  const float* wg_b     = (const float*)d_in[11];
  const float* qk_scale = (const float*)d_in[12];
  const float* kv_scale = (const float*)d_in[13];

  float* ws = (float*)d_ws;
  const size_t NT = (size_t)LS * DM;  // 786432
  float* q     = ws;
  float* k     = ws + NT;
  float* v     = ws + 2 * NT;
  float* sim   = ws + 3 * NT;
  float* gates = sim + NH * LS;
  float* m_s   = gates + NH * LS;
  float* Sraw  = m_s + NH * LS;
  float* g_s   = Sraw + NH * LS;
  float* states = g_s + NH * LS;                       // 12*64*4096
  float* nes    = states + (size_t)NH * NTL * 4096;    // 12*64*64
  u16*   xtb    = (u16*)(nes + (size_t)NH * NTL * HD); // NT bf16
  u16*   wT     = xtb + NT;                            // 4 * 589824 bf16
  u16*   lerpb  = wT + 4 * (size_t)WSZ;                // NT bf16
  float* pbase  = (float*)(lerpb + NT);                // 8 * NT conv partials

  conv_txw_kernel<<<dim3(2112), 256, 28672, stream>>>(
      x, filters, wq_w, wk_w, wv_w, wo_w, wT, pbase);
  pack_xt<<<dim3(NT / 2048), 256, 0, stream>>>(pbase, xtb);
  qkv_mfma<<<dim3(576), 256, 0, stream>>>(xtb, wT, wq_b, wk_b, wv_b, q, k, v);
  norm_sim_gate<<<dim3(LS / 4, NH), 256, 0, stream>>>(
      q, k, v, wg_w, wg_b, qk_scale, kv_scale, sim, gates);
  scan_kernel<<<dim3(NH), 1024, 0, stream>>>(sim, gates, m_s, Sraw, g_s);
  state_kernel<<<dim3(NTL, NH), 256, 0, stream>>>(k, v, sim, gates, states, nes);
  prefix_kernel<<<dim3(NH, 4), 256, 0, stream>>>(states, nes);
  apply_kernel<<<dim3(NTL, NH), 256, 0, stream>>>(
      q, k, v, sim, gates, m_s, Sraw, g_s, states, nes, kv_scale, lerpb);
  out_mfma<<<dim3(192), 256, 0, stream>>>(
      lerpb, wT + 3 * (size_t)WSZ, wo_b, (float*)d_out);
}